// Round 15
// baseline (800.918 us; speedup 1.0000x reference)
//
#include <hip/hip_runtime.h>
#include <math.h>

#define NN 8192
#define NE 131072
#define CIN 128
#define C 64
#define NL 4
#define COUT 21
#define EPSV 1e-5f
#define ALPHA 0.18033688011112043f  // 0.125 * log2(e)

typedef unsigned short u16;
typedef __attribute__((ext_vector_type(8))) short short8;
typedef __attribute__((ext_vector_type(4))) float f32x4;
typedef __attribute__((ext_vector_type(4))) unsigned int u32x4;
typedef __attribute__((ext_vector_type(2))) unsigned int u32x2;

__device__ __forceinline__ u16 f2bf(float x) {
  unsigned int u = __float_as_uint(x);
  u += 0x7FFF + ((u >> 16) & 1);
  return (u16)(u >> 16);
}

__device__ __forceinline__ unsigned cvtpk(float a, float b) {
  unsigned r;
  asm("v_cvt_pk_bf16_f32 %0, %1, %2" : "=v"(r) : "v"(a), "v"(b));
  return r;
}

__device__ __forceinline__ int pcmap(int c) {  // k-dim permutation (within 32), c<64
  return (c & 32) | (c & 3) | (((c >> 2) & 3) << 3) | (((c >> 4) & 1) << 2);
}

__device__ __forceinline__ int pc128(int c) {  // same, for c<128
  return (c & 96) | (c & 3) | (((c >> 2) & 3) << 3) | (((c >> 4) & 1) << 2);
}

// ---------------------------------------------------------------- setup
__global__ void zero_setup(float* __restrict__ stats, int* __restrict__ degi) {
  int i = blockIdx.x * 256 + threadIdx.x;
  if (i < 1536) stats[i] = 0.f;
  if (i < NN) degi[i] = 0;
}

__global__ void deg_kernel(const int* __restrict__ dst, int* __restrict__ degi) {
  int e = blockIdx.x * 256 + threadIdx.x;
  if (e < NE) atomicAdd(&degi[dst[e]], 1);
}

__global__ __launch_bounds__(256) void prefix_kernel(const int* __restrict__ degi,
                                                     int* __restrict__ rowptr,
                                                     int* __restrict__ cursor) {
  __shared__ int part[256];
  int t = threadIdx.x;
  int base = t * 32;
  int loc[32];
  int s = 0;
#pragma unroll
  for (int i = 0; i < 32; ++i) { loc[i] = s; s += degi[base + i]; }
  part[t] = s;
  __syncthreads();
  for (int off = 1; off < 256; off <<= 1) {
    int v = (t >= off) ? part[t - off] : 0;
    __syncthreads();
    part[t] += v;
    __syncthreads();
  }
  int chunkbase = (t == 0) ? 0 : part[t - 1];
#pragma unroll
  for (int i = 0; i < 32; ++i) {
    int v = chunkbase + loc[i];
    rowptr[base + i] = v;
    cursor[base + i] = v;
  }
  if (t == 255) rowptr[NN] = part[255];
}

__global__ void dinv_kernel(const int* __restrict__ degi, float* __restrict__ dinv) {
  int i = blockIdx.x * 256 + threadIdx.x;
  if (i < NN) dinv[i] = rsqrtf((float)degi[i] + 1.0f);
}

__global__ void fill_kernel(const int* __restrict__ src, const int* __restrict__ dst,
                            const float* __restrict__ dinv,
                            int* __restrict__ cursor, int* __restrict__ esrc,
                            float* __restrict__ ewt) {
  int e = blockIdx.x * 256 + threadIdx.x;
  if (e < NE) {
    int d = dst[e];
    int s = src[e];
    int pos = atomicAdd(&cursor[d], 1);
    esrc[pos] = s;
    ewt[pos] = dinv[s];
  }
}

// ------------------------------------- weight prep: bf16 + pc-permute k-dim
__global__ void prep_weights(const float* __restrict__ Wqkv, const float* __restrict__ Wo,
                             const float* __restrict__ Wg,
                             const float* __restrict__ W1, const float* __restrict__ W2,
                             u16* __restrict__ Wqp, u16* __restrict__ Wop,
                             u16* __restrict__ Wgp,
                             u16* __restrict__ W1p, u16* __restrict__ W2p) {
  int idx = blockIdx.x * 256 + threadIdx.x;   // 147456 total
  if (idx < NL * 192 * 64) {
    int l = idx / 12288, rem = idx % 12288;
    int j = rem >> 6, c = rem & 63;
    Wqp[l * 12288 + j * 64 + pcmap(c)] = f2bf(Wqkv[idx]);
  } else if (idx < NL * 192 * 64 + NL * 64 * 64) {
    int i2 = idx - NL * 192 * 64;
    int l = i2 >> 12, m = (i2 >> 6) & 63, k = i2 & 63;
    Wop[l * 4096 + m * 64 + pcmap(k)] = f2bf(Wo[i2]);
  } else if (idx < NL * 192 * 64 + 2 * NL * 64 * 64) {
    int i3 = idx - NL * 192 * 64 - NL * 64 * 64;
    int l = i3 >> 12, k = (i3 >> 6) & 63, c = i3 & 63;
    Wgp[l * 4096 + c * 64 + pcmap(k)] = f2bf(Wg[i3]);  // transpose: row=out ch
  } else if (idx < NL * 192 * 64 + 2 * NL * 64 * 64 + NL * 64 * 128) {
    int i4 = idx - (NL * 192 * 64 + 2 * NL * 64 * 64);  // W1: [L][64k][128m]
    int l = i4 >> 13, i3 = i4 & 8191;
    int k = i3 >> 7, m = i3 & 127;
    W1p[l * 8192 + m * 64 + pcmap(k)] = f2bf(W1[i4]);
  } else if (idx < NL * 192 * 64 + 2 * NL * 64 * 64 + 2 * NL * 64 * 128) {
    int i5 = idx - (NL * 192 * 64 + 2 * NL * 64 * 64 + NL * 64 * 128);  // W2: [L][128k][64m]
    int l = i5 >> 13, i3 = i5 & 8191;
    int k = i3 >> 6, m = i3 & 63;
    W2p[l * 8192 + m * 128 + pc128(k)] = f2bf(W2[i5]);
  }
}

// ------------------------------------------------------------- input GEMM
__global__ __launch_bounds__(256) void gemm_in_kernel(const float* __restrict__ X,
                                                      const float* __restrict__ W,
                                                      const float* __restrict__ b,
                                                      float* __restrict__ Y,
                                                      u16* __restrict__ hb) {
  int idx = blockIdx.x * 256 + threadIdx.x;
  int n = idx >> 6, c = idx & 63;
  const float* xr = X + n * CIN;
  float acc = b[c];
#pragma unroll 16
  for (int k = 0; k < CIN; ++k) acc = fmaf(xr[k], W[k * C + c], acc);
  Y[idx] = acc;
  hb[n * 64 + pcmap(c)] = f2bf(acc);
}

// ---------------- fused projection: GCN gemm + t1 init + QKV + V transpose
__global__ __launch_bounds__(128) void proj_mfma(const u16* __restrict__ hb,
                                                 const float* __restrict__ h,
                                                 const u16* __restrict__ Wqp,
                                                 const u16* __restrict__ Wgp,
                                                 const float* __restrict__ bq,
                                                 const float* __restrict__ gb,
                                                 const float* __restrict__ dinv,
                                                 u16* __restrict__ Qb,
                                                 u16* __restrict__ Kb,
                                                 u16* __restrict__ Vt,
                                                 float* __restrict__ xw,
                                                 float* __restrict__ t1) {
  __shared__ u16 ldsv[64 * 17];
  const int tid = threadIdx.x;
  const int lane = tid & 63, w = tid >> 6;
  const int r = lane & 15, q = lane >> 4;
  const int n0 = blockIdx.x * 16;
  const int n = n0 + r;

  short8 hf[2];
#pragma unroll
  for (int s = 0; s < 2; ++s)
    hf[s] = *(const short8*)(hb + (size_t)n * 64 + s * 32 + q * 8);

  if (w == 0) {
    float di = dinv[n];
#pragma unroll
    for (int jt = 0; jt < 4; ++jt) {
      f32x4 a = {};
#pragma unroll
      for (int s = 0; s < 2; ++s) {
        short8 wf = *(const short8*)(Wgp + (jt * 16 + r) * 64 + s * 32 + q * 8);
        a = __builtin_amdgcn_mfma_f32_16x16x32_bf16(wf, hf[s], a, 0, 0, 0);
      }
      int j0 = jt * 16 + q * 4;
      f32x4 hres = *(const f32x4*)&h[(size_t)n * 64 + j0];
      f32x4 gbv = *(const f32x4*)&gb[j0];
      *(f32x4*)&xw[(size_t)n * 64 + j0] = a;
      *(f32x4*)&t1[(size_t)n * 64 + j0] = a * di * di + gbv + hres;
    }
#pragma unroll
    for (int jt = 0; jt < 4; ++jt) {
      f32x4 a = {};
#pragma unroll
      for (int s = 0; s < 2; ++s) {
        short8 wf = *(const short8*)(Wqp + (jt * 16 + r) * 64 + s * 32 + q * 8);
        a = __builtin_amdgcn_mfma_f32_16x16x32_bf16(wf, hf[s], a, 0, 0, 0);
      }
      f32x4 v = (a + *(const f32x4*)&bq[jt * 16 + q * 4]) * ALPHA;
      int pb = ((jt & 2) << 4) | (q << 3) | ((jt & 1) << 2);
      *(u32x2*)(Qb + (size_t)n * 64 + pb) = u32x2{cvtpk(v[0], v[1]), cvtpk(v[2], v[3])};
    }
  } else {
#pragma unroll
    for (int jt = 0; jt < 4; ++jt) {
      f32x4 a = {};
#pragma unroll
      for (int s = 0; s < 2; ++s) {
        short8 wf = *(const short8*)(Wqp + (64 + jt * 16 + r) * 64 + s * 32 + q * 8);
        a = __builtin_amdgcn_mfma_f32_16x16x32_bf16(wf, hf[s], a, 0, 0, 0);
      }
      f32x4 v = a + *(const f32x4*)&bq[64 + jt * 16 + q * 4];
      int pb = ((jt & 2) << 4) | (q << 3) | ((jt & 1) << 2);
      *(u32x2*)(Kb + (size_t)n * 64 + pb) = u32x2{cvtpk(v[0], v[1]), cvtpk(v[2], v[3])};
    }
#pragma unroll
    for (int jt = 0; jt < 4; ++jt) {
      f32x4 a = {};
#pragma unroll
      for (int s = 0; s < 2; ++s) {
        short8 wf = *(const short8*)(Wqp + (128 + jt * 16 + r) * 64 + s * 32 + q * 8);
        a = __builtin_amdgcn_mfma_f32_16x16x32_bf16(wf, hf[s], a, 0, 0, 0);
      }
      f32x4 v = a + *(const f32x4*)&bq[128 + jt * 16 + q * 4];
      int j0 = jt * 16 + q * 4;
#pragma unroll
      for (int e = 0; e < 4; ++e) ldsv[(j0 + e) * 17 + r] = f2bf(v[e]);
    }
  }
  __syncthreads();

  const int d = tid >> 1, cp = tid & 1;
  const int grp = n0 & ~31, hh = (n0 >> 4) & 1;
#pragma unroll
  for (int ci = 0; ci < 2; ++ci) {
    int cc = cp * 2 + ci;
    u16 a0 = ldsv[d * 17 + cc * 4 + 0];
    u16 a1 = ldsv[d * 17 + cc * 4 + 1];
    u16 a2 = ldsv[d * 17 + cc * 4 + 2];
    u16 a3 = ldsv[d * 17 + cc * 4 + 3];
    *(u32x2*)(Vt + (size_t)d * NN + grp + cc * 8 + hh * 4) =
        u32x2{(unsigned)a0 | ((unsigned)a1 << 16), (unsigned)a2 | ((unsigned)a3 << 16)};
  }
}

// --------------------------- GCN gather (CSR, ewt) + fused BN stats1
__global__ __launch_bounds__(256) void gcn_gather(const int* __restrict__ rowptr,
                                                  const int* __restrict__ esrc,
                                                  const float* __restrict__ ewt,
                                                  const float* __restrict__ xw,
                                                  const float* __restrict__ dinv,
                                                  float* __restrict__ t1,
                                                  float* __restrict__ stats) {
  __shared__ float gs[4][64], gss[4][64];
  int w = threadIdx.x >> 6, lane = threadIdx.x & 63;
  float s = 0.f, ss = 0.f;
#pragma unroll
  for (int rr = 0; rr < 2; ++rr) {
    int d = blockIdx.x * 8 + w * 2 + rr;
    int beg = rowptr[d], end = rowptr[d + 1];
    float acc = 0.f;
    int i = beg;
    for (; i + 4 <= end; i += 4) {
      int s0 = esrc[i], s1 = esrc[i + 1], s2 = esrc[i + 2], s3 = esrc[i + 3];
      float w0 = ewt[i], w1 = ewt[i + 1], w2 = ewt[i + 2], w3 = ewt[i + 3];
      float x0 = xw[(size_t)s0 * 64 + lane];
      float x1 = xw[(size_t)s1 * 64 + lane];
      float x2 = xw[(size_t)s2 * 64 + lane];
      float x3 = xw[(size_t)s3 * 64 + lane];
      acc = fmaf(x0, w0, acc);
      acc = fmaf(x1, w1, acc);
      acc = fmaf(x2, w2, acc);
      acc = fmaf(x3, w3, acc);
    }
    for (; i < end; ++i) acc = fmaf(xw[(size_t)esrc[i] * 64 + lane], ewt[i], acc);
    size_t idx = (size_t)d * 64 + lane;
    float v = t1[idx] + acc * dinv[d];
    t1[idx] = v;
    s += v; ss += v * v;
  }
  gs[w][lane] = s; gss[w][lane] = ss;
  __syncthreads();
  int t = threadIdx.x;
  if (t < 64) atomicAdd(&stats[t], gs[0][t] + gs[1][t] + gs[2][t] + gs[3][t]);
  else if (t < 128) {
    int c = t - 64;
    atomicAdd(&stats[64 + c], gss[0][c] + gss[1][c] + gss[2][c] + gss[3][c]);
  }
}

// ------------------------------------------------------------ MFMA flash attention
// grid 256 (qt, 32 Q-rows); 1024 thr = 16 waves (guaranteed co-resident, 4/SIMD).
// Wave w: keys [w*512, +512) = 8 tiles of 64 (round-9 loop, it=2 fragments from
// round 10, deferred ll from round 12, 16-wave merge pattern from round 11).
__device__ __forceinline__ void loadK(short8 (&kf)[8], const u16* kb, int koff) {
#pragma unroll
  for (int jt = 0; jt < 4; ++jt)
#pragma unroll
    for (int s = 0; s < 2; ++s)
      kf[jt * 2 + s] = *(const short8*)(kb + koff + jt * 1024 + s * 32);
}

__device__ __forceinline__ void loadV(short8 (&vf)[8], const u16* vb, int voff) {
#pragma unroll
  for (int dt = 0; dt < 4; ++dt)
#pragma unroll
    for (int s = 0; s < 2; ++s)
      vf[dt * 2 + s] = *(const short8*)(vb + voff + dt * 16 * NN + s * 32);
}

__device__ __forceinline__ void computeTile(const short8 (&kf)[8], const short8 (&vf)[8],
                                            const short8 (&qf)[2][2],
                                            f32x4 (&o)[4][2], float (&ll)[2]) {
#pragma unroll
  for (int pair = 0; pair < 2; ++pair) {
    f32x4 st[2][2] = {};
#pragma unroll
    for (int s = 0; s < 2; ++s)
#pragma unroll
      for (int jp = 0; jp < 2; ++jp) {
        short8 kfrag = kf[(pair * 2 + jp) * 2 + s];
#pragma unroll
        for (int it = 0; it < 2; ++it)
          st[jp][it] = __builtin_amdgcn_mfma_f32_16x16x32_bf16(kfrag, qf[it][s], st[jp][it], 0, 0, 0);
      }
    short8 pf[2];
#pragma unroll
    for (int it = 0; it < 2; ++it) {
      float p[8];
#pragma unroll
      for (int jp = 0; jp < 2; ++jp)
#pragma unroll
        for (int r = 0; r < 4; ++r) p[jp * 4 + r] = exp2f(st[jp][it][r]);
      // per-lane partial; cross-lane reduce deferred to after the K loop
      ll[it] += ((p[0] + p[1]) + (p[2] + p[3])) + ((p[4] + p[5]) + (p[6] + p[7]));
      u32x4 a;
      a[0] = cvtpk(p[0], p[1]); a[1] = cvtpk(p[2], p[3]);
      a[2] = cvtpk(p[4], p[5]); a[3] = cvtpk(p[6], p[7]);
      pf[it] = __builtin_bit_cast(short8, a);
    }
#pragma unroll
    for (int dt = 0; dt < 4; ++dt) {
      short8 vfrag = vf[dt * 2 + pair];
#pragma unroll
      for (int it = 0; it < 2; ++it)
        o[dt][it] = __builtin_amdgcn_mfma_f32_16x16x32_bf16(vfrag, pf[it], o[dt][it], 0, 0, 0);
    }
  }
}

__global__ __launch_bounds__(1024, 4)
void attn_mfma(const u16* __restrict__ Qb, const u16* __restrict__ Kb,
               const u16* __restrict__ Vtb, float* __restrict__ Opart,
               float* __restrict__ Lpart) {
  __shared__ float fsm[2 * 32 * 68 + 2 * 32];
  const int tid = threadIdx.x;
  const int lane = tid & 63;
  const int w = tid >> 6;            // 0..15
  const int qt = blockIdx.x;
  const int qbase = qt * 32;
  const int kv0 = w * 512;
  const int r = lane & 15, q = lane >> 4;

  short8 qf[2][2];
#pragma unroll
  for (int it = 0; it < 2; ++it)
#pragma unroll
    for (int s = 0; s < 2; ++s)
      qf[it][s] = *(const short8*)(Qb + (size_t)(qbase + it * 16 + r) * 64 + s * 32 + q * 8);

  f32x4 o[4][2] = {};
  float ll[2] = {0.f, 0.f};

  const u16* kb = Kb + (size_t)(kv0 + r) * 64 + q * 8;
  const u16* vb = Vtb + (size_t)r * NN + kv0 + q * 8;

  short8 kA[8], kB[8], vf[8];
  loadK(kA, kb, 0);
#pragma unroll 1
  for (int t = 0; t < 8; t += 2) {
    loadV(vf, vb, t * 64);
    loadK(kB, kb, (t + 1) * 4096);
    computeTile(kA, vf, qf, o, ll);
    loadV(vf, vb, (t + 1) * 64);
    if (t + 2 < 8) loadK(kA, kb, (t + 2) * 4096);
    computeTile(kB, vf, qf, o, ll);
  }

  // deferred cross-lane reduce of the softmax denominators
#pragma unroll
  for (int it = 0; it < 2; ++it) {
    ll[it] += __shfl_xor(ll[it], 16);
    ll[it] += __shfl_xor(ll[it], 32);
  }

  // ---- 16-wave merge: 2 LDS bufs, 8 rounds (32-row tiles)
  float* buf = fsm + (w & 1) * (32 * 68);
  float* lb = fsm + 2 * 32 * 68 + (w & 1) * 32;
  for (int rr = 0; rr < 8; ++rr) {
    if ((w >> 1) == rr) {
      if (rr == 0) {
#pragma unroll
        for (int dt = 0; dt < 4; ++dt)
#pragma unroll
          for (int it = 0; it < 2; ++it)
            *(f32x4*)&buf[(it * 16 + r) * 68 + dt * 16 + q * 4] = o[dt][it];
        if (lane < 16)
#pragma unroll
          for (int it = 0; it < 2; ++it) lb[it * 16 + lane] = ll[it];
      } else {
#pragma unroll
        for (int dt = 0; dt < 4; ++dt)
#pragma unroll
          for (int it = 0; it < 2; ++it) {
            float* p = &buf[(it * 16 + r) * 68 + dt * 16 + q * 4];
            *(f32x4*)p = *(const f32x4*)p + o[dt][it];
          }
        if (lane < 16)
#pragma unroll
          for (int it = 0; it < 2; ++it) lb[it * 16 + lane] += ll[it];
      }
    }
    __syncthreads();
  }

  // writeout: 32 rows x 64 d = 2048 floats over 1024 threads (2 each)
  int row = tid >> 5, d0 = (tid & 31) * 2;
  float* outp = Opart + (size_t)qt * 2048 + row * 64 + d0;
  const float* b0 = fsm + row * 68 + d0;
  const float* b1 = b0 + 32 * 68;
  outp[0] = b0[0] + b1[0];
  outp[1] = b0[1] + b1[1];
  if (tid < 32)
    Lpart[qt * 32 + tid] = fsm[2 * 32 * 68 + tid] + fsm[2 * 32 * 68 + 32 + tid];
}

// ------ O-projection MFMA (+1/l +bias +res) + fused BN stats2
// 256 blocks x 32 rows; block == one qt tile (single partial now).
__global__ __launch_bounds__(256) void oproj_mfma(const float* __restrict__ Opart,
                                                  const float* __restrict__ Lpart,
                                                  const u16* __restrict__ Wop,
                                                  const float* __restrict__ bo,
                                                  const float* __restrict__ res,
                                                  float* __restrict__ Y,
                                                  float* __restrict__ stats) {
  __shared__ u16 ldso[32 * 72];
  __shared__ float os[2][64], oss[2][64];
  const int tid = threadIdx.x;
  const int n0 = blockIdx.x * 32;
  const int qtile = blockIdx.x;

  {
    int row = tid >> 3, c0 = (tid & 7) * 8;
    float inv = 1.f / Lpart[qtile * 32 + row];
    const float* O0 = Opart + (size_t)qtile * 2048 + row * 64;
#pragma unroll
    for (int j8 = 0; j8 < 2; ++j8) {
      f32x4 a = *(const f32x4*)&O0[c0 + j8 * 4];
      f32x4 vsum = a * inv;
#pragma unroll
      for (int e = 0; e < 4; ++e) ldso[row * 72 + pcmap(c0 + j8 * 4 + e)] = f2bf(vsum[e]);
    }
  }
  __syncthreads();

  const int lane = tid & 63, w = tid >> 6;
  const int r = lane & 15, q = lane >> 4;
  const int ntile = w & 1, mhalf = w >> 1;
  short8 hf[2];
#pragma unroll
  for (int s = 0; s < 2; ++s)
    hf[s] = *(const short8*)&ldso[(ntile * 16 + r) * 72 + s * 32 + q * 8];

  const int n = n0 + ntile * 16 + r;
#pragma unroll
  for (int mi = 0; mi < 2; ++mi) {
    int mt = mhalf * 2 + mi;
    f32x4 a = {};
#pragma unroll
    for (int s = 0; s < 2; ++s) {
      short8 wf = *(const short8*)(Wop + (mt * 16 + r) * 64 + s * 32 + q * 8);
      a = __builtin_amdgcn_mfma_f32_16x16x32_bf16(wf, hf[s], a, 0, 0, 0);
    }
    int m0 = mt * 16 + q * 4;
    f32x4 out = a + *(const f32x4*)&bo[m0] + *(const f32x4*)&res[(size_t)n * 64 + m0];
    *(f32x4*)&Y[(size_t)n * 64 + m0] = out;
    f32x4 s_ = out, q_ = out * out;
#pragma unroll
    for (int off = 1; off < 16; off <<= 1) {
#pragma unroll
      for (int e = 0; e < 4; ++e) {
        s_[e] += __shfl_xor(s_[e], off);
        q_[e] += __shfl_xor(q_[e], off);
      }
    }
    if (r == 0) {
#pragma unroll
      for (int e = 0; e < 4; ++e) {
        os[ntile][m0 + e] = s_[e];
        oss[ntile][m0 + e] = q_[e];
      }
    }
  }
  __syncthreads();
  if (tid < 64) atomicAdd(&stats[tid], os[0][tid] + os[1][tid]);
  else if (tid < 128) {
    int c = tid - 64;
    atomicAdd(&stats[64 + c], oss[0][c] + oss[1][c]);
  }
}

// -------- fused combine(bn1+bn2) + MLP via MFMA (+relu +residual) + BN stats3
__global__ __launch_bounds__(256) void mlp_mfma(const float* __restrict__ t1,
                                                const float* __restrict__ t0,
                                                const float* __restrict__ s1,
                                                const float* __restrict__ s2,
                                                const float* __restrict__ g1,
                                                const float* __restrict__ bb1,
                                                const float* __restrict__ g2,
                                                const float* __restrict__ bb2,
                                                const u16* __restrict__ W1p,
                                                const float* __restrict__ b1,
                                                const u16* __restrict__ W2p,
                                                const float* __restrict__ b2,
                                                float* __restrict__ t4,
                                                float* __restrict__ stats) {
  __shared__ float rows[32][68];
  __shared__ u16 xb[32 * 72];
  __shared__ u16 midb[32 * 136];
  __shared__ float os[2][64], oss[2][64];
  int t = threadIdx.x;
  int r0 = blockIdx.x * 32;

  for (int i = t; i < 2048; i += 256) {
    int rr = i >> 6, c = i & 63;
    int idx = (r0 + rr) * 64 + c;
    float m1 = s1[c] * (1.f / NN);
    float v1 = s1[64 + c] * (1.f / NN) - m1 * m1;
    float m2 = s2[c] * (1.f / NN);
    float v2 = s2[64 + c] * (1.f / NN) - m2 * m2;
    float val = (t1[idx] - m1) * rsqrtf(v1 + EPSV) * g1[c] + bb1[c] +
                (t0[idx] - m2) * rsqrtf(v2 + EPSV) * g2[c] + bb2[c];
    rows[rr][c] = val;
    xb[rr * 72 + pcmap(c)] = f2bf(val);
  }
  __syncthreads();

  const int lane = t & 63, w = t >> 6;
  const int r = lane & 15, q = lane >> 4;
  const int ntile = w & 1, mgrp = w >> 1;

  short8 hf[2];
#pragma unroll
  for (int s = 0; s < 2; ++s)
    hf[s] = *(const short8*)&xb[(ntile * 16 + r) * 72 + s * 32 + q * 8];

#pragma unroll
  for (int mi = 0; mi < 4; ++mi) {
    int mt = mgrp * 4 + mi;
    f32x4 a = {};
#pragma unroll
    for (int s = 0; s < 2; ++s) {
      short8 wf = *(const short8*)(W1p + (mt * 16 + r) * 64 + s * 32 + q * 8);
      a = __builtin_amdgcn_mfma_f32_16x16x32_bf16(wf, hf[s], a, 0, 0, 0);
    }
    int m0 = mt * 16 + q * 4;
    f32x4 v = a + *(const f32x4*)&b1[m0];
#pragma unroll
    for (int e = 0; e < 4; ++e)
      midb[(ntile * 16 + r) * 136 + pc128(m0 + e)] = f2bf(fmaxf(v[e], 0.f));
  }
  __syncthreads();

  short8 mf[4];
#pragma unroll
  for (int s = 0; s < 4; ++s)
    mf[s] = *(const short8*)&midb[(ntile * 16 + r) * 136 + s * 32 + q * 8];

  const int n = r0 + ntile * 16 + r;
#pragma unroll
  for (int mi = 0; mi < 2; ++mi) {
    int mt = mgrp * 2 + mi;
    f32x4 a = {};
#pragma unroll
    for (int s = 0; s < 4; ++s) {
      short8 wf = *(const short8*)(W2p + (mt * 16 + r) * 128 + s * 32 + q * 8);
      a = __builtin_amdgcn_mfma_f32_16x16x32_bf16(wf, mf[s], a, 0, 0, 0);
    }
    int m0 = mt * 16 + q * 4;
    f32x4 out = a + *(const f32x4*)&b2[m0] + *(const f32x4*)&rows[ntile * 16 + r][m0];
    *(f32x4*)&t4[(size_t)n * 64 + m0] = out;
    f32x4 s_ = out, q_ = out * out;
#pragma unroll
    for (int off = 1; off < 16; off <<= 1) {
#pragma unroll
      for (int e = 0; e < 4; ++e) {
        s_[e] += __shfl_xor(s_[e], off);
        q_[e] += __shfl_xor(q_[e], off);
      }
    }
    if (r == 0) {
#pragma unroll
      for (int e = 0; e < 4; ++e) {
        os[ntile][m0 + e] = s_[e];
        oss[ntile][m0 + e] = q_[e];
      }
    }
  }
  __syncthreads();
  if (t < 64) atomicAdd(&stats[t], os[0][t] + os[1][t]);
  else if (t < 128) {
    int c = t - 64;
    atomicAdd(&stats[64 + c], oss[0][c] + oss[1][c]);
  }
}

// ------------------------------------------- BN3 + LayerNorm + ReLU (fused)
__global__ __launch_bounds__(256) void bn3_ln_relu(const float* __restrict__ t4,
                                                   const float* __restrict__ s3,
                                                   const float* __restrict__ g3,
                                                   const float* __restrict__ b3,
                                                   const float* __restrict__ lg,
                                                   const float* __restrict__ lb,
                                                   float* __restrict__ H,
                                                   u16* __restrict__ hb) {
  int wv = threadIdx.x >> 6, lane = threadIdx.x & 63;
  int n = blockIdx.x * 4 + wv;
  float m3 = s3[lane] * (1.f / NN);
  float v3 = s3[64 + lane] * (1.f / NN) - m3 * m3;
  float x = (t4[n * 64 + lane] - m3) * rsqrtf(v3 + EPSV) * g3[lane] + b3[lane];
  float s = x, ss = x * x;
  for (int o = 32; o > 0; o >>= 1) {
    s += __shfl_xor(s, o, 64);
    ss += __shfl_xor(ss, o, 64);
  }
  float m = s * (1.f / 64), v = ss * (1.f / 64) - m * m;
  float y = (x - m) * rsqrtf(v + EPSV) * lg[lane] + lb[lane];
  y = fmaxf(y, 0.f);
  H[n * 64 + lane] = y;
  hb[n * 64 + pcmap(lane)] = f2bf(y);
}

// ------------------------------------------- final GEMM (64x21) + log_softmax
__global__ __launch_bounds__(256) void final_kernel(const float* __restrict__ H,
                                                    const float* __restrict__ Wout,
                                                    const float* __restrict__ bout,
                                                    float* __restrict__ out) {
  int w = threadIdx.x >> 6, lane = threadIdx.x & 63;
  int n = blockIdx.x * 4 + w;
  const float* hr = H + n * 64;
  float acc = (lane < COUT) ? bout[lane] : -INFINITY;
  if (lane < COUT) {
#pragma unroll 16
    for (int k = 0; k < 64; ++k) acc = fmaf(hr[k], Wout[k * COUT + lane], acc);
  }
  float mx = acc;
  for (int o = 32; o > 0; o >>= 1) mx = fmaxf(mx, __shfl_xor(mx, o, 64));
  float e = __expf(acc - mx);
  float se = e;
  for (int o = 32; o > 0; o >>= 1) se += __shfl_xor(se, o, 64);
  float lse = mx + logf(se);
  if (lane < COUT) out[n * COUT + lane] = acc - lse;
}

// ================================================================ launch
extern "C" void kernel_launch(void* const* d_in, const int* in_sizes, int n_in,
                              void* d_out, int out_size, void* d_ws, size_t ws_size,
                              hipStream_t stream) {
  const float* x    = (const float*)d_in[0];
  const int*   ei   = (const int*)d_in[1];
  const float* W_in = (const float*)d_in[2];
  const float* b_in = (const float*)d_in[3];
  const float* gcnW = (const float*)d_in[4];
  const float* gcnB = (const float*)d_in[5];
  const float* Wqkv = (const float*)d_in[6];
  const float* bqkv = (const float*)d_in[7];
  const float* Wo   = (const float*)d_in[8];
  const float* bo   = (const float*)d_in[9];
  const float* bn1g = (const float*)d_in[10];
  const float* bn1b = (const float*)d_in[11];
  const float* bn2g = (const float*)d_in[12];
  const float* bn2b = (const float*)d_in[13];
  const float* bn3g = (const float*)d_in[14];
  const float* bn3b = (const float*)d_in[15];
  const float* W1   = (const float*)d_in[16];
  const float* b1   = (const float*)d_in[17];
  const float* W2   = (const float*)d_in[18];
  const float* b2   = (const float*)d_in[19];
  const float* lng  = (const float*)d_in[20];
  const float* lnb  = (const float*)d_in[21];
  const float* Wout = (const float*)d_in[22];
  const float* bout = (const float*)d_in[23];

  const int* src = ei;
  const int* dst = ei + NE;

  const int NC = NN * C;
  float* ws = (float*)d_ws;
  float* h     = ws + 0 * NC;
  float* t0    = ws + 1 * NC;     // xw (gather input), then oproj output
  float* t1    = ws + 2 * NC;
  float* Opart = ws + 3 * NC;     // 2MB: 256qt x 32 x 64
  float* t4    = ws + 5 * NC;
  u16* Qb  = (u16*)(ws + 6 * NC);
  u16* Kb  = Qb + NC;
  u16* Vtb = Kb + NC;
  u16* hbb = Vtb + NC;
  u16* Wqp = hbb + NC;            // NL x 192 x 64
  u16* Wop = Wqp + NL * 192 * 64; // NL x 64 x 64
  u16* Wgp = Wop + NL * 64 * 64;  // NL x 64 x 64
  u16* W1p = Wgp + NL * 64 * 64;  // NL x 128 x 64
  u16* W2p = W1p + NL * 128 * 64; // NL x 64 x 128
  float* dinv = (float*)(W2p + NL * 64 * 128);
  float* statsAll = dinv + NN;    // 12 x 128
  float* Lpart = statsAll + 1536; // 256qt x 32
  int* degi   = (int*)(Lpart + 16384);
  int* rowptr = degi + NN;        // NN+1
  int* cursor = rowptr + NN + 8;
  int* esrc   = cursor + NN;      // NE
  float* ewt  = (float*)(esrc + NE);  // NE

  dim3 B(256);

  // ---- setup: CSR + dinv + weight prep (deterministic; recomputed per call)
  zero_setup<<<32, B, 0, stream>>>(statsAll, degi);
  deg_kernel<<<NE / 256, B, 0, stream>>>(dst, degi);
  prefix_kernel<<<1, B, 0, stream>>>(degi, rowptr, cursor);
  dinv_kernel<<<NN / 256, B, 0, stream>>>(degi, dinv);
  fill_kernel<<<NE / 256, B, 0, stream>>>(src, dst, dinv, cursor, esrc, ewt);
  prep_weights<<<576, B, 0, stream>>>(Wqkv, Wo, gcnW, W1, W2, Wqp, Wop, Wgp, W1p, W2p);

  gemm_in_kernel<<<NN * C / 256, B, 0, stream>>>(x, W_in, b_in, h, hbb);

  for (int l = 0; l < NL; ++l) {
    float* s1 = statsAll + l * 384;
    float* s2 = s1 + 128;
    float* s3 = s1 + 256;

    // ---- fused projection: gcn gemm + t1 init + QKV + Vt
    proj_mfma<<<NN / 16, 128, 0, stream>>>(hbb, h, Wqp + l * 192 * 64, Wgp + l * 4096,
                                           bqkv + l * 192, gcnB + l * C, dinv,
                                           Qb, Kb, Vtb, t0, t1);
    // ---- gather + fused stats1
    gcn_gather<<<NN / 8, B, 0, stream>>>(rowptr, esrc, ewt, t0, dinv, t1, s1);

    // ---- global attention branch + residual -> t0, fused stats2
    attn_mfma<<<256, 1024, 0, stream>>>(Qb, Kb, Vtb, Opart, Lpart);
    oproj_mfma<<<NN / 32, B, 0, stream>>>(Opart, Lpart, Wop + l * 4096, bo + l * C, h, t0, s2);

    // ---- combine + MLP (MFMA) -> t4 + fused stats3, then BN3 + LN + ReLU -> h (+hb)
    mlp_mfma<<<NN / 32, B, 0, stream>>>(t1, t0, s1, s2, bn1g + l * C, bn1b + l * C,
                                        bn2g + l * C, bn2b + l * C,
                                        W1p + l * 8192, b1 + l * 2 * C,
                                        W2p + l * 8192, b2 + l * C, t4, s3);
    bn3_ln_relu<<<NN / 4, B, 0, stream>>>(t4, s3, bn3g + l * C, bn3b + l * C,
                                          lng + l * C, lnb + l * C, h, hbb);
  }

  final_kernel<<<NN / 4, B, 0, stream>>>(h, Wout, bout, (float*)d_out);
}

// Round 16
// 800.733 us; speedup vs baseline: 1.0002x; 1.0002x over previous
//
#include <hip/hip_runtime.h>
#include <math.h>

#define NN 8192
#define NE 131072
#define CIN 128
#define C 64
#define NL 4
#define COUT 21
#define EPSV 1e-5f
#define ALPHA 0.18033688011112043f  // 0.125 * log2(e)

typedef unsigned short u16;
typedef __attribute__((ext_vector_type(8))) short short8;
typedef __attribute__((ext_vector_type(4))) float f32x4;
typedef __attribute__((ext_vector_type(4))) unsigned int u32x4;
typedef __attribute__((ext_vector_type(2))) unsigned int u32x2;

__device__ __forceinline__ u16 f2bf(float x) {
  unsigned int u = __float_as_uint(x);
  u += 0x7FFF + ((u >> 16) & 1);
  return (u16)(u >> 16);
}

__device__ __forceinline__ unsigned cvtpk(float a, float b) {
  unsigned r;
  asm("v_cvt_pk_bf16_f32 %0, %1, %2" : "=v"(r) : "v"(a), "v"(b));
  return r;
}

__device__ __forceinline__ int pcmap(int c) {  // k-dim permutation (within 32), c<64
  return (c & 32) | (c & 3) | (((c >> 2) & 3) << 3) | (((c >> 4) & 1) << 2);
}

__device__ __forceinline__ int pc128(int c) {  // same, for c<128
  return (c & 96) | (c & 3) | (((c >> 2) & 3) << 3) | (((c >> 4) & 1) << 2);
}

// ---------------------------------------------------------------- setup
__global__ void zero_setup(float* __restrict__ stats, int* __restrict__ degi) {
  int i = blockIdx.x * 256 + threadIdx.x;
  if (i < 1536) stats[i] = 0.f;
  if (i < NN) degi[i] = 0;
}

__global__ void deg_kernel(const int* __restrict__ dst, int* __restrict__ degi) {
  int e = blockIdx.x * 256 + threadIdx.x;
  if (e < NE) atomicAdd(&degi[dst[e]], 1);
}

__global__ __launch_bounds__(256) void prefix_kernel(const int* __restrict__ degi,
                                                     int* __restrict__ rowptr,
                                                     int* __restrict__ cursor) {
  __shared__ int part[256];
  int t = threadIdx.x;
  int base = t * 32;
  int loc[32];
  int s = 0;
#pragma unroll
  for (int i = 0; i < 32; ++i) { loc[i] = s; s += degi[base + i]; }
  part[t] = s;
  __syncthreads();
  for (int off = 1; off < 256; off <<= 1) {
    int v = (t >= off) ? part[t - off] : 0;
    __syncthreads();
    part[t] += v;
    __syncthreads();
  }
  int chunkbase = (t == 0) ? 0 : part[t - 1];
#pragma unroll
  for (int i = 0; i < 32; ++i) {
    int v = chunkbase + loc[i];
    rowptr[base + i] = v;
    cursor[base + i] = v;
  }
  if (t == 255) rowptr[NN] = part[255];
}

__global__ void dinv_kernel(const int* __restrict__ degi, float* __restrict__ dinv) {
  int i = blockIdx.x * 256 + threadIdx.x;
  if (i < NN) dinv[i] = rsqrtf((float)degi[i] + 1.0f);
}

__global__ void fill_kernel(const int* __restrict__ src, const int* __restrict__ dst,
                            const float* __restrict__ dinv,
                            int* __restrict__ cursor, int* __restrict__ esrc,
                            float* __restrict__ ewt) {
  int e = blockIdx.x * 256 + threadIdx.x;
  if (e < NE) {
    int d = dst[e];
    int s = src[e];
    int pos = atomicAdd(&cursor[d], 1);
    esrc[pos] = s;
    ewt[pos] = dinv[s];
  }
}

// ------------------------------------- weight prep: bf16 + pc-permute k-dim
__global__ void prep_weights(const float* __restrict__ Wqkv, const float* __restrict__ Wo,
                             const float* __restrict__ Wg,
                             const float* __restrict__ W1, const float* __restrict__ W2,
                             u16* __restrict__ Wqp, u16* __restrict__ Wop,
                             u16* __restrict__ Wgp,
                             u16* __restrict__ W1p, u16* __restrict__ W2p) {
  int idx = blockIdx.x * 256 + threadIdx.x;   // 147456 total
  if (idx < NL * 192 * 64) {
    int l = idx / 12288, rem = idx % 12288;
    int j = rem >> 6, c = rem & 63;
    Wqp[l * 12288 + j * 64 + pcmap(c)] = f2bf(Wqkv[idx]);
  } else if (idx < NL * 192 * 64 + NL * 64 * 64) {
    int i2 = idx - NL * 192 * 64;
    int l = i2 >> 12, m = (i2 >> 6) & 63, k = i2 & 63;
    Wop[l * 4096 + m * 64 + pcmap(k)] = f2bf(Wo[i2]);
  } else if (idx < NL * 192 * 64 + 2 * NL * 64 * 64) {
    int i3 = idx - NL * 192 * 64 - NL * 64 * 64;
    int l = i3 >> 12, k = (i3 >> 6) & 63, c = i3 & 63;
    Wgp[l * 4096 + c * 64 + pcmap(k)] = f2bf(Wg[i3]);  // transpose: row=out ch
  } else if (idx < NL * 192 * 64 + 2 * NL * 64 * 64 + NL * 64 * 128) {
    int i4 = idx - (NL * 192 * 64 + 2 * NL * 64 * 64);  // W1: [L][64k][128m]
    int l = i4 >> 13, i3 = i4 & 8191;
    int k = i3 >> 7, m = i3 & 127;
    W1p[l * 8192 + m * 64 + pcmap(k)] = f2bf(W1[i4]);
  } else if (idx < NL * 192 * 64 + 2 * NL * 64 * 64 + 2 * NL * 64 * 128) {
    int i5 = idx - (NL * 192 * 64 + 2 * NL * 64 * 64 + NL * 64 * 128);  // W2: [L][128k][64m]
    int l = i5 >> 13, i3 = i5 & 8191;
    int k = i3 >> 6, m = i3 & 63;
    W2p[l * 8192 + m * 128 + pc128(k)] = f2bf(W2[i5]);
  }
}

// ------------------------------------------------------------- input GEMM
__global__ __launch_bounds__(256) void gemm_in_kernel(const float* __restrict__ X,
                                                      const float* __restrict__ W,
                                                      const float* __restrict__ b,
                                                      float* __restrict__ Y,
                                                      u16* __restrict__ hb) {
  int idx = blockIdx.x * 256 + threadIdx.x;
  int n = idx >> 6, c = idx & 63;
  const float* xr = X + n * CIN;
  float acc = b[c];
#pragma unroll 16
  for (int k = 0; k < CIN; ++k) acc = fmaf(xr[k], W[k * C + c], acc);
  Y[idx] = acc;
  hb[n * 64 + pcmap(c)] = f2bf(acc);
}

// ---------------- fused projection: GCN gemm + t1 init + QKV + V transpose
__global__ __launch_bounds__(128) void proj_mfma(const u16* __restrict__ hb,
                                                 const float* __restrict__ h,
                                                 const u16* __restrict__ Wqp,
                                                 const u16* __restrict__ Wgp,
                                                 const float* __restrict__ bq,
                                                 const float* __restrict__ gb,
                                                 const float* __restrict__ dinv,
                                                 u16* __restrict__ Qb,
                                                 u16* __restrict__ Kb,
                                                 u16* __restrict__ Vt,
                                                 float* __restrict__ xw,
                                                 float* __restrict__ t1) {
  __shared__ u16 ldsv[64 * 17];
  const int tid = threadIdx.x;
  const int lane = tid & 63, w = tid >> 6;
  const int r = lane & 15, q = lane >> 4;
  const int n0 = blockIdx.x * 16;
  const int n = n0 + r;

  short8 hf[2];
#pragma unroll
  for (int s = 0; s < 2; ++s)
    hf[s] = *(const short8*)(hb + (size_t)n * 64 + s * 32 + q * 8);

  if (w == 0) {
    float di = dinv[n];
#pragma unroll
    for (int jt = 0; jt < 4; ++jt) {
      f32x4 a = {};
#pragma unroll
      for (int s = 0; s < 2; ++s) {
        short8 wf = *(const short8*)(Wgp + (jt * 16 + r) * 64 + s * 32 + q * 8);
        a = __builtin_amdgcn_mfma_f32_16x16x32_bf16(wf, hf[s], a, 0, 0, 0);
      }
      int j0 = jt * 16 + q * 4;
      f32x4 hres = *(const f32x4*)&h[(size_t)n * 64 + j0];
      f32x4 gbv = *(const f32x4*)&gb[j0];
      *(f32x4*)&xw[(size_t)n * 64 + j0] = a;
      *(f32x4*)&t1[(size_t)n * 64 + j0] = a * di * di + gbv + hres;
    }
#pragma unroll
    for (int jt = 0; jt < 4; ++jt) {
      f32x4 a = {};
#pragma unroll
      for (int s = 0; s < 2; ++s) {
        short8 wf = *(const short8*)(Wqp + (jt * 16 + r) * 64 + s * 32 + q * 8);
        a = __builtin_amdgcn_mfma_f32_16x16x32_bf16(wf, hf[s], a, 0, 0, 0);
      }
      f32x4 v = (a + *(const f32x4*)&bq[jt * 16 + q * 4]) * ALPHA;
      int pb = ((jt & 2) << 4) | (q << 3) | ((jt & 1) << 2);
      *(u32x2*)(Qb + (size_t)n * 64 + pb) = u32x2{cvtpk(v[0], v[1]), cvtpk(v[2], v[3])};
    }
  } else {
#pragma unroll
    for (int jt = 0; jt < 4; ++jt) {
      f32x4 a = {};
#pragma unroll
      for (int s = 0; s < 2; ++s) {
        short8 wf = *(const short8*)(Wqp + (64 + jt * 16 + r) * 64 + s * 32 + q * 8);
        a = __builtin_amdgcn_mfma_f32_16x16x32_bf16(wf, hf[s], a, 0, 0, 0);
      }
      f32x4 v = a + *(const f32x4*)&bq[64 + jt * 16 + q * 4];
      int pb = ((jt & 2) << 4) | (q << 3) | ((jt & 1) << 2);
      *(u32x2*)(Kb + (size_t)n * 64 + pb) = u32x2{cvtpk(v[0], v[1]), cvtpk(v[2], v[3])};
    }
#pragma unroll
    for (int jt = 0; jt < 4; ++jt) {
      f32x4 a = {};
#pragma unroll
      for (int s = 0; s < 2; ++s) {
        short8 wf = *(const short8*)(Wqp + (128 + jt * 16 + r) * 64 + s * 32 + q * 8);
        a = __builtin_amdgcn_mfma_f32_16x16x32_bf16(wf, hf[s], a, 0, 0, 0);
      }
      f32x4 v = a + *(const f32x4*)&bq[128 + jt * 16 + q * 4];
      int j0 = jt * 16 + q * 4;
#pragma unroll
      for (int e = 0; e < 4; ++e) ldsv[(j0 + e) * 17 + r] = f2bf(v[e]);
    }
  }
  __syncthreads();

  const int d = tid >> 1, cp = tid & 1;
  const int grp = n0 & ~31, hh = (n0 >> 4) & 1;
#pragma unroll
  for (int ci = 0; ci < 2; ++ci) {
    int cc = cp * 2 + ci;
    u16 a0 = ldsv[d * 17 + cc * 4 + 0];
    u16 a1 = ldsv[d * 17 + cc * 4 + 1];
    u16 a2 = ldsv[d * 17 + cc * 4 + 2];
    u16 a3 = ldsv[d * 17 + cc * 4 + 3];
    *(u32x2*)(Vt + (size_t)d * NN + grp + cc * 8 + hh * 4) =
        u32x2{(unsigned)a0 | ((unsigned)a1 << 16), (unsigned)a2 | ((unsigned)a3 << 16)};
  }
}

// --------------------------- GCN gather (CSR, ewt) + fused BN stats1
__global__ __launch_bounds__(256) void gcn_gather(const int* __restrict__ rowptr,
                                                  const int* __restrict__ esrc,
                                                  const float* __restrict__ ewt,
                                                  const float* __restrict__ xw,
                                                  const float* __restrict__ dinv,
                                                  float* __restrict__ t1,
                                                  float* __restrict__ stats) {
  __shared__ float gs[4][64], gss[4][64];
  int w = threadIdx.x >> 6, lane = threadIdx.x & 63;
  float s = 0.f, ss = 0.f;
#pragma unroll
  for (int rr = 0; rr < 2; ++rr) {
    int d = blockIdx.x * 8 + w * 2 + rr;
    int beg = rowptr[d], end = rowptr[d + 1];
    float acc = 0.f;
    int i = beg;
    for (; i + 4 <= end; i += 4) {
      int s0 = esrc[i], s1 = esrc[i + 1], s2 = esrc[i + 2], s3 = esrc[i + 3];
      float w0 = ewt[i], w1 = ewt[i + 1], w2 = ewt[i + 2], w3 = ewt[i + 3];
      float x0 = xw[(size_t)s0 * 64 + lane];
      float x1 = xw[(size_t)s1 * 64 + lane];
      float x2 = xw[(size_t)s2 * 64 + lane];
      float x3 = xw[(size_t)s3 * 64 + lane];
      acc = fmaf(x0, w0, acc);
      acc = fmaf(x1, w1, acc);
      acc = fmaf(x2, w2, acc);
      acc = fmaf(x3, w3, acc);
    }
    for (; i < end; ++i) acc = fmaf(xw[(size_t)esrc[i] * 64 + lane], ewt[i], acc);
    size_t idx = (size_t)d * 64 + lane;
    float v = t1[idx] + acc * dinv[d];
    t1[idx] = v;
    s += v; ss += v * v;
  }
  gs[w][lane] = s; gss[w][lane] = ss;
  __syncthreads();
  int t = threadIdx.x;
  if (t < 64) atomicAdd(&stats[t], gs[0][t] + gs[1][t] + gs[2][t] + gs[3][t]);
  else if (t < 128) {
    int c = t - 64;
    atomicAdd(&stats[64 + c], gss[0][c] + gss[1][c] + gss[2][c] + gss[3][c]);
  }
}

// ------------------------------------------------------------ MFMA flash attention
// grid 256 (qt, 32 Q-rows); 1024 thr = 16 waves (4 waves/SIMD in ONE block).
// launch_bounds (1024,1): 1 block/CU -> VGPR cap 128 >= ~108 needed (round-10
// measured). Wave w: keys [w*512, +512) = 8 tiles of 64.
__device__ __forceinline__ void loadK(short8 (&kf)[8], const u16* kb, int koff) {
#pragma unroll
  for (int jt = 0; jt < 4; ++jt)
#pragma unroll
    for (int s = 0; s < 2; ++s)
      kf[jt * 2 + s] = *(const short8*)(kb + koff + jt * 1024 + s * 32);
}

__device__ __forceinline__ void loadV(short8 (&vf)[8], const u16* vb, int voff) {
#pragma unroll
  for (int dt = 0; dt < 4; ++dt)
#pragma unroll
    for (int s = 0; s < 2; ++s)
      vf[dt * 2 + s] = *(const short8*)(vb + voff + dt * 16 * NN + s * 32);
}

__device__ __forceinline__ void computeTile(const short8 (&kf)[8], const short8 (&vf)[8],
                                            const short8 (&qf)[2][2],
                                            f32x4 (&o)[4][2], float (&ll)[2]) {
#pragma unroll
  for (int pair = 0; pair < 2; ++pair) {
    f32x4 st[2][2] = {};
#pragma unroll
    for (int s = 0; s < 2; ++s)
#pragma unroll
      for (int jp = 0; jp < 2; ++jp) {
        short8 kfrag = kf[(pair * 2 + jp) * 2 + s];
#pragma unroll
        for (int it = 0; it < 2; ++it)
          st[jp][it] = __builtin_amdgcn_mfma_f32_16x16x32_bf16(kfrag, qf[it][s], st[jp][it], 0, 0, 0);
      }
    short8 pf[2];
#pragma unroll
    for (int it = 0; it < 2; ++it) {
      float p[8];
#pragma unroll
      for (int jp = 0; jp < 2; ++jp)
#pragma unroll
        for (int r = 0; r < 4; ++r) p[jp * 4 + r] = exp2f(st[jp][it][r]);
      // per-lane partial; cross-lane reduce deferred to after the K loop
      ll[it] += ((p[0] + p[1]) + (p[2] + p[3])) + ((p[4] + p[5]) + (p[6] + p[7]));
      u32x4 a;
      a[0] = cvtpk(p[0], p[1]); a[1] = cvtpk(p[2], p[3]);
      a[2] = cvtpk(p[4], p[5]); a[3] = cvtpk(p[6], p[7]);
      pf[it] = __builtin_bit_cast(short8, a);
    }
#pragma unroll
    for (int dt = 0; dt < 4; ++dt) {
      short8 vfrag = vf[dt * 2 + pair];
#pragma unroll
      for (int it = 0; it < 2; ++it)
        o[dt][it] = __builtin_amdgcn_mfma_f32_16x16x32_bf16(vfrag, pf[it], o[dt][it], 0, 0, 0);
    }
  }
}

__global__ __launch_bounds__(1024, 1)
void attn_mfma(const u16* __restrict__ Qb, const u16* __restrict__ Kb,
               const u16* __restrict__ Vtb, float* __restrict__ Opart,
               float* __restrict__ Lpart) {
  __shared__ float fsm[2 * 32 * 68 + 2 * 32];
  const int tid = threadIdx.x;
  const int lane = tid & 63;
  const int w = tid >> 6;            // 0..15
  const int qt = blockIdx.x;
  const int qbase = qt * 32;
  const int kv0 = w * 512;
  const int r = lane & 15, q = lane >> 4;

  short8 qf[2][2];
#pragma unroll
  for (int it = 0; it < 2; ++it)
#pragma unroll
    for (int s = 0; s < 2; ++s)
      qf[it][s] = *(const short8*)(Qb + (size_t)(qbase + it * 16 + r) * 64 + s * 32 + q * 8);

  f32x4 o[4][2] = {};
  float ll[2] = {0.f, 0.f};

  const u16* kb = Kb + (size_t)(kv0 + r) * 64 + q * 8;
  const u16* vb = Vtb + (size_t)r * NN + kv0 + q * 8;

  short8 kA[8], kB[8], vf[8];
  loadK(kA, kb, 0);
#pragma unroll 1
  for (int t = 0; t < 8; t += 2) {
    loadV(vf, vb, t * 64);
    loadK(kB, kb, (t + 1) * 4096);
    computeTile(kA, vf, qf, o, ll);
    loadV(vf, vb, (t + 1) * 64);
    if (t + 2 < 8) loadK(kA, kb, (t + 2) * 4096);
    computeTile(kB, vf, qf, o, ll);
  }

  // deferred cross-lane reduce of the softmax denominators
#pragma unroll
  for (int it = 0; it < 2; ++it) {
    ll[it] += __shfl_xor(ll[it], 16);
    ll[it] += __shfl_xor(ll[it], 32);
  }

  // ---- 16-wave merge: 2 LDS bufs, 8 rounds (32-row tiles)
  float* buf = fsm + (w & 1) * (32 * 68);
  float* lb = fsm + 2 * 32 * 68 + (w & 1) * 32;
  for (int rr = 0; rr < 8; ++rr) {
    if ((w >> 1) == rr) {
      if (rr == 0) {
#pragma unroll
        for (int dt = 0; dt < 4; ++dt)
#pragma unroll
          for (int it = 0; it < 2; ++it)
            *(f32x4*)&buf[(it * 16 + r) * 68 + dt * 16 + q * 4] = o[dt][it];
        if (lane < 16)
#pragma unroll
          for (int it = 0; it < 2; ++it) lb[it * 16 + lane] = ll[it];
      } else {
#pragma unroll
        for (int dt = 0; dt < 4; ++dt)
#pragma unroll
          for (int it = 0; it < 2; ++it) {
            float* p = &buf[(it * 16 + r) * 68 + dt * 16 + q * 4];
            *(f32x4*)p = *(const f32x4*)p + o[dt][it];
          }
        if (lane < 16)
#pragma unroll
          for (int it = 0; it < 2; ++it) lb[it * 16 + lane] += ll[it];
      }
    }
    __syncthreads();
  }

  // writeout: 32 rows x 64 d = 2048 floats over 1024 threads (2 each)
  int row = tid >> 5, d0 = (tid & 31) * 2;
  float* outp = Opart + (size_t)qt * 2048 + row * 64 + d0;
  const float* b0 = fsm + row * 68 + d0;
  const float* b1 = b0 + 32 * 68;
  outp[0] = b0[0] + b1[0];
  outp[1] = b0[1] + b1[1];
  if (tid < 32)
    Lpart[qt * 32 + tid] = fsm[2 * 32 * 68 + tid] + fsm[2 * 32 * 68 + 32 + tid];
}

// ------ O-projection MFMA (+1/l +bias +res) + fused BN stats2
// 256 blocks x 32 rows; block == one qt tile (single partial).
__global__ __launch_bounds__(256) void oproj_mfma(const float* __restrict__ Opart,
                                                  const float* __restrict__ Lpart,
                                                  const u16* __restrict__ Wop,
                                                  const float* __restrict__ bo,
                                                  const float* __restrict__ res,
                                                  float* __restrict__ Y,
                                                  float* __restrict__ stats) {
  __shared__ u16 ldso[32 * 72];
  __shared__ float os[2][64], oss[2][64];
  const int tid = threadIdx.x;
  const int n0 = blockIdx.x * 32;
  const int qtile = blockIdx.x;

  {
    int row = tid >> 3, c0 = (tid & 7) * 8;
    float inv = 1.f / Lpart[qtile * 32 + row];
    const float* O0 = Opart + (size_t)qtile * 2048 + row * 64;
#pragma unroll
    for (int j8 = 0; j8 < 2; ++j8) {
      f32x4 a = *(const f32x4*)&O0[c0 + j8 * 4];
      f32x4 vsum = a * inv;
#pragma unroll
      for (int e = 0; e < 4; ++e) ldso[row * 72 + pcmap(c0 + j8 * 4 + e)] = f2bf(vsum[e]);
    }
  }
  __syncthreads();

  const int lane = tid & 63, w = tid >> 6;
  const int r = lane & 15, q = lane >> 4;
  const int ntile = w & 1, mhalf = w >> 1;
  short8 hf[2];
#pragma unroll
  for (int s = 0; s < 2; ++s)
    hf[s] = *(const short8*)&ldso[(ntile * 16 + r) * 72 + s * 32 + q * 8];

  const int n = n0 + ntile * 16 + r;
#pragma unroll
  for (int mi = 0; mi < 2; ++mi) {
    int mt = mhalf * 2 + mi;
    f32x4 a = {};
#pragma unroll
    for (int s = 0; s < 2; ++s) {
      short8 wf = *(const short8*)(Wop + (mt * 16 + r) * 64 + s * 32 + q * 8);
      a = __builtin_amdgcn_mfma_f32_16x16x32_bf16(wf, hf[s], a, 0, 0, 0);
    }
    int m0 = mt * 16 + q * 4;
    f32x4 out = a + *(const f32x4*)&bo[m0] + *(const f32x4*)&res[(size_t)n * 64 + m0];
    *(f32x4*)&Y[(size_t)n * 64 + m0] = out;
    f32x4 s_ = out, q_ = out * out;
#pragma unroll
    for (int off = 1; off < 16; off <<= 1) {
#pragma unroll
      for (int e = 0; e < 4; ++e) {
        s_[e] += __shfl_xor(s_[e], off);
        q_[e] += __shfl_xor(q_[e], off);
      }
    }
    if (r == 0) {
#pragma unroll
      for (int e = 0; e < 4; ++e) {
        os[ntile][m0 + e] = s_[e];
        oss[ntile][m0 + e] = q_[e];
      }
    }
  }
  __syncthreads();
  if (tid < 64) atomicAdd(&stats[tid], os[0][tid] + os[1][tid]);
  else if (tid < 128) {
    int c = tid - 64;
    atomicAdd(&stats[64 + c], oss[0][c] + oss[1][c]);
  }
}

// -------- fused combine(bn1+bn2) + MLP via MFMA (+relu +residual) + BN stats3
__global__ __launch_bounds__(256) void mlp_mfma(const float* __restrict__ t1,
                                                const float* __restrict__ t0,
                                                const float* __restrict__ s1,
                                                const float* __restrict__ s2,
                                                const float* __restrict__ g1,
                                                const float* __restrict__ bb1,
                                                const float* __restrict__ g2,
                                                const float* __restrict__ bb2,
                                                const u16* __restrict__ W1p,
                                                const float* __restrict__ b1,
                                                const u16* __restrict__ W2p,
                                                const float* __restrict__ b2,
                                                float* __restrict__ t4,
                                                float* __restrict__ stats) {
  __shared__ float rows[32][68];
  __shared__ u16 xb[32 * 72];
  __shared__ u16 midb[32 * 136];
  __shared__ float os[2][64], oss[2][64];
  int t = threadIdx.x;
  int r0 = blockIdx.x * 32;

  for (int i = t; i < 2048; i += 256) {
    int rr = i >> 6, c = i & 63;
    int idx = (r0 + rr) * 64 + c;
    float m1 = s1[c] * (1.f / NN);
    float v1 = s1[64 + c] * (1.f / NN) - m1 * m1;
    float m2 = s2[c] * (1.f / NN);
    float v2 = s2[64 + c] * (1.f / NN) - m2 * m2;
    float val = (t1[idx] - m1) * rsqrtf(v1 + EPSV) * g1[c] + bb1[c] +
                (t0[idx] - m2) * rsqrtf(v2 + EPSV) * g2[c] + bb2[c];
    rows[rr][c] = val;
    xb[rr * 72 + pcmap(c)] = f2bf(val);
  }
  __syncthreads();

  const int lane = t & 63, w = t >> 6;
  const int r = lane & 15, q = lane >> 4;
  const int ntile = w & 1, mgrp = w >> 1;

  short8 hf[2];
#pragma unroll
  for (int s = 0; s < 2; ++s)
    hf[s] = *(const short8*)&xb[(ntile * 16 + r) * 72 + s * 32 + q * 8];

#pragma unroll
  for (int mi = 0; mi < 4; ++mi) {
    int mt = mgrp * 4 + mi;
    f32x4 a = {};
#pragma unroll
    for (int s = 0; s < 2; ++s) {
      short8 wf = *(const short8*)(W1p + (mt * 16 + r) * 64 + s * 32 + q * 8);
      a = __builtin_amdgcn_mfma_f32_16x16x32_bf16(wf, hf[s], a, 0, 0, 0);
    }
    int m0 = mt * 16 + q * 4;
    f32x4 v = a + *(const f32x4*)&b1[m0];
#pragma unroll
    for (int e = 0; e < 4; ++e)
      midb[(ntile * 16 + r) * 136 + pc128(m0 + e)] = f2bf(fmaxf(v[e], 0.f));
  }
  __syncthreads();

  short8 mf[4];
#pragma unroll
  for (int s = 0; s < 4; ++s)
    mf[s] = *(const short8*)&midb[(ntile * 16 + r) * 136 + s * 32 + q * 8];

  const int n = r0 + ntile * 16 + r;
#pragma unroll
  for (int mi = 0; mi < 2; ++mi) {
    int mt = mgrp * 2 + mi;
    f32x4 a = {};
#pragma unroll
    for (int s = 0; s < 4; ++s) {
      short8 wf = *(const short8*)(W2p + (mt * 16 + r) * 128 + s * 32 + q * 8);
      a = __builtin_amdgcn_mfma_f32_16x16x32_bf16(wf, mf[s], a, 0, 0, 0);
    }
    int m0 = mt * 16 + q * 4;
    f32x4 out = a + *(const f32x4*)&b2[m0] + *(const f32x4*)&rows[ntile * 16 + r][m0];
    *(f32x4*)&t4[(size_t)n * 64 + m0] = out;
    f32x4 s_ = out, q_ = out * out;
#pragma unroll
    for (int off = 1; off < 16; off <<= 1) {
#pragma unroll
      for (int e = 0; e < 4; ++e) {
        s_[e] += __shfl_xor(s_[e], off);
        q_[e] += __shfl_xor(q_[e], off);
      }
    }
    if (r == 0) {
#pragma unroll
      for (int e = 0; e < 4; ++e) {
        os[ntile][m0 + e] = s_[e];
        oss[ntile][m0 + e] = q_[e];
      }
    }
  }
  __syncthreads();
  if (t < 64) atomicAdd(&stats[t], os[0][t] + os[1][t]);
  else if (t < 128) {
    int c = t - 64;
    atomicAdd(&stats[64 + c], oss[0][c] + oss[1][c]);
  }
}

// ------------------------------------------- BN3 + LayerNorm + ReLU (fused)
__global__ __launch_bounds__(256) void bn3_ln_relu(const float* __restrict__ t4,
                                                   const float* __restrict__ s3,
                                                   const float* __restrict__ g3,
                                                   const float* __restrict__ b3,
                                                   const float* __restrict__ lg,
                                                   const float* __restrict__ lb,
                                                   float* __restrict__ H,
                                                   u16* __restrict__ hb) {
  int wv = threadIdx.x >> 6, lane = threadIdx.x & 63;
  int n = blockIdx.x * 4 + wv;
  float m3 = s3[lane] * (1.f / NN);
  float v3 = s3[64 + lane] * (1.f / NN) - m3 * m3;
  float x = (t4[n * 64 + lane] - m3) * rsqrtf(v3 + EPSV) * g3[lane] + b3[lane];
  float s = x, ss = x * x;
  for (int o = 32; o > 0; o >>= 1) {
    s += __shfl_xor(s, o, 64);
    ss += __shfl_xor(ss, o, 64);
  }
  float m = s * (1.f / 64), v = ss * (1.f / 64) - m * m;
  float y = (x - m) * rsqrtf(v + EPSV) * lg[lane] + lb[lane];
  y = fmaxf(y, 0.f);
  H[n * 64 + lane] = y;
  hb[n * 64 + pcmap(lane)] = f2bf(y);
}

// ------------------------------------------- final GEMM (64x21) + log_softmax
__global__ __launch_bounds__(256) void final_kernel(const float* __restrict__ H,
                                                    const float* __restrict__ Wout,
                                                    const float* __restrict__ bout,
                                                    float* __restrict__ out) {
  int w = threadIdx.x >> 6, lane = threadIdx.x & 63;
  int n = blockIdx.x * 4 + w;
  const float* hr = H + n * 64;
  float acc = (lane < COUT) ? bout[lane] : -INFINITY;
  if (lane < COUT) {
#pragma unroll 16
    for (int k = 0; k < 64; ++k) acc = fmaf(hr[k], Wout[k * COUT + lane], acc);
  }
  float mx = acc;
  for (int o = 32; o > 0; o >>= 1) mx = fmaxf(mx, __shfl_xor(mx, o, 64));
  float e = __expf(acc - mx);
  float se = e;
  for (int o = 32; o > 0; o >>= 1) se += __shfl_xor(se, o, 64);
  float lse = mx + logf(se);
  if (lane < COUT) out[n * COUT + lane] = acc - lse;
}

// ================================================================ launch
extern "C" void kernel_launch(void* const* d_in, const int* in_sizes, int n_in,
                              void* d_out, int out_size, void* d_ws, size_t ws_size,
                              hipStream_t stream) {
  const float* x    = (const float*)d_in[0];
  const int*   ei   = (const int*)d_in[1];
  const float* W_in = (const float*)d_in[2];
  const float* b_in = (const float*)d_in[3];
  const float* gcnW = (const float*)d_in[4];
  const float* gcnB = (const float*)d_in[5];
  const float* Wqkv = (const float*)d_in[6];
  const float* bqkv = (const float*)d_in[7];
  const float* Wo   = (const float*)d_in[8];
  const float* bo   = (const float*)d_in[9];
  const float* bn1g = (const float*)d_in[10];
  const float* bn1b = (const float*)d_in[11];
  const float* bn2g = (const float*)d_in[12];
  const float* bn2b = (const float*)d_in[13];
  const float* bn3g = (const float*)d_in[14];
  const float* bn3b = (const float*)d_in[15];
  const float* W1   = (const float*)d_in[16];
  const float* b1   = (const float*)d_in[17];
  const float* W2   = (const float*)d_in[18];
  const float* b2   = (const float*)d_in[19];
  const float* lng  = (const float*)d_in[20];
  const float* lnb  = (const float*)d_in[21];
  const float* Wout = (const float*)d_in[22];
  const float* bout = (const float*)d_in[23];

  const int* src = ei;
  const int* dst = ei + NE;

  const int NC = NN * C;
  float* ws = (float*)d_ws;
  float* h     = ws + 0 * NC;
  float* t0    = ws + 1 * NC;     // xw (gather input), then oproj output
  float* t1    = ws + 2 * NC;
  float* Opart = ws + 3 * NC;     // 2MB: 256qt x 32 x 64
  float* t4    = ws + 5 * NC;
  u16* Qb  = (u16*)(ws + 6 * NC);
  u16* Kb  = Qb + NC;
  u16* Vtb = Kb + NC;
  u16* hbb = Vtb + NC;
  u16* Wqp = hbb + NC;            // NL x 192 x 64
  u16* Wop = Wqp + NL * 192 * 64; // NL x 64 x 64
  u16* Wgp = Wop + NL * 64 * 64;  // NL x 64 x 64
  u16* W1p = Wgp + NL * 64 * 64;  // NL x 128 x 64
  u16* W2p = W1p + NL * 128 * 64; // NL x 64 x 128
  float* dinv = (float*)(W2p + NL * 64 * 128);
  float* statsAll = dinv + NN;    // 12 x 128
  float* Lpart = statsAll + 1536; // 256qt x 32
  int* degi   = (int*)(Lpart + 16384);
  int* rowptr = degi + NN;        // NN+1
  int* cursor = rowptr + NN + 8;
  int* esrc   = cursor + NN;      // NE
  float* ewt  = (float*)(esrc + NE);  // NE

  dim3 B(256);

  // ---- setup: CSR + dinv + weight prep (deterministic; recomputed per call)
  zero_setup<<<32, B, 0, stream>>>(statsAll, degi);
  deg_kernel<<<NE / 256, B, 0, stream>>>(dst, degi);
  prefix_kernel<<<1, B, 0, stream>>>(degi, rowptr, cursor);
  dinv_kernel<<<NN / 256, B, 0, stream>>>(degi, dinv);
  fill_kernel<<<NE / 256, B, 0, stream>>>(src, dst, dinv, cursor, esrc, ewt);
  prep_weights<<<576, B, 0, stream>>>(Wqkv, Wo, gcnW, W1, W2, Wqp, Wop, Wgp, W1p, W2p);

  gemm_in_kernel<<<NN * C / 256, B, 0, stream>>>(x, W_in, b_in, h, hbb);

  for (int l = 0; l < NL; ++l) {
    float* s1 = statsAll + l * 384;
    float* s2 = s1 + 128;
    float* s3 = s1 + 256;

    // ---- fused projection: gcn gemm + t1 init + QKV + Vt
    proj_mfma<<<NN / 16, 128, 0, stream>>>(hbb, h, Wqp + l * 192 * 64, Wgp + l * 4096,
                                           bqkv + l * 192, gcnB + l * C, dinv,
                                           Qb, Kb, Vtb, t0, t1);
    // ---- gather + fused stats1
    gcn_gather<<<NN / 8, B, 0, stream>>>(rowptr, esrc, ewt, t0, dinv, t1, s1);

    // ---- global attention branch + residual -> t0, fused stats2
    attn_mfma<<<256, 1024, 0, stream>>>(Qb, Kb, Vtb, Opart, Lpart);
    oproj_mfma<<<NN / 32, B, 0, stream>>>(Opart, Lpart, Wop + l * 4096, bo + l * C, h, t0, s2);

    // ---- combine + MLP (MFMA) -> t4 + fused stats3, then BN3 + LN + ReLU -> h (+hb)
    mlp_mfma<<<NN / 32, B, 0, stream>>>(t1, t0, s1, s2, bn1g + l * C, bn1b + l * C,
                                        bn2g + l * C, bn2b + l * C,
                                        W1p + l * 8192, b1 + l * 2 * C,
                                        W2p + l * 8192, b2 + l * C, t4, s3);
    bn3_ln_relu<<<NN / 4, B, 0, stream>>>(t4, s3, bn3g + l * C, bn3b + l * C,
                                          lng + l * C, lnb + l * C, h, hbb);
  }

  final_kernel<<<NN / 4, B, 0, stream>>>(h, Wout, bout, (float*)d_out);
}

// Round 17
// 564.162 us; speedup vs baseline: 1.4197x; 1.4193x over previous
//
#include <hip/hip_runtime.h>
#include <math.h>

#define NN 8192
#define NE 131072
#define CIN 128
#define C 64
#define NL 4
#define COUT 21
#define EPSV 1e-5f
#define ALPHA 0.18033688011112043f  // 0.125 * log2(e)

typedef unsigned short u16;
typedef __attribute__((ext_vector_type(8))) short short8;
typedef __attribute__((ext_vector_type(4))) float f32x4;
typedef __attribute__((ext_vector_type(4))) unsigned int u32x4;
typedef __attribute__((ext_vector_type(2))) unsigned int u32x2;

__device__ __forceinline__ u16 f2bf(float x) {
  unsigned int u = __float_as_uint(x);
  u += 0x7FFF + ((u >> 16) & 1);
  return (u16)(u >> 16);
}

__device__ __forceinline__ unsigned cvtpk(float a, float b) {
  unsigned r;
  asm("v_cvt_pk_bf16_f32 %0, %1, %2" : "=v"(r) : "v"(a), "v"(b));
  return r;
}

__device__ __forceinline__ int pcmap(int c) {  // k-dim permutation (within 32), c<64
  return (c & 32) | (c & 3) | (((c >> 2) & 3) << 3) | (((c >> 4) & 1) << 2);
}

__device__ __forceinline__ int pc128(int c) {  // same, for c<128
  return (c & 96) | (c & 3) | (((c >> 2) & 3) << 3) | (((c >> 4) & 1) << 2);
}

// ---------------------------------------------------------------- setup
__global__ void zero_setup(float* __restrict__ stats, int* __restrict__ degi) {
  int i = blockIdx.x * 256 + threadIdx.x;
  if (i < 1536) stats[i] = 0.f;
  if (i < NN) degi[i] = 0;
}

__global__ void deg_kernel(const int* __restrict__ dst, int* __restrict__ degi) {
  int e = blockIdx.x * 256 + threadIdx.x;
  if (e < NE) atomicAdd(&degi[dst[e]], 1);
}

__global__ __launch_bounds__(256) void prefix_kernel(const int* __restrict__ degi,
                                                     int* __restrict__ rowptr,
                                                     int* __restrict__ cursor) {
  __shared__ int part[256];
  int t = threadIdx.x;
  int base = t * 32;
  int loc[32];
  int s = 0;
#pragma unroll
  for (int i = 0; i < 32; ++i) { loc[i] = s; s += degi[base + i]; }
  part[t] = s;
  __syncthreads();
  for (int off = 1; off < 256; off <<= 1) {
    int v = (t >= off) ? part[t - off] : 0;
    __syncthreads();
    part[t] += v;
    __syncthreads();
  }
  int chunkbase = (t == 0) ? 0 : part[t - 1];
#pragma unroll
  for (int i = 0; i < 32; ++i) {
    int v = chunkbase + loc[i];
    rowptr[base + i] = v;
    cursor[base + i] = v;
  }
  if (t == 255) rowptr[NN] = part[255];
}

__global__ void dinv_kernel(const int* __restrict__ degi, float* __restrict__ dinv) {
  int i = blockIdx.x * 256 + threadIdx.x;
  if (i < NN) dinv[i] = rsqrtf((float)degi[i] + 1.0f);
}

__global__ void fill_kernel(const int* __restrict__ src, const int* __restrict__ dst,
                            const float* __restrict__ dinv,
                            int* __restrict__ cursor, int* __restrict__ esrc,
                            float* __restrict__ ewt) {
  int e = blockIdx.x * 256 + threadIdx.x;
  if (e < NE) {
    int d = dst[e];
    int s = src[e];
    int pos = atomicAdd(&cursor[d], 1);
    esrc[pos] = s;
    ewt[pos] = dinv[s];
  }
}

// ------------------------------------- weight prep: bf16 + pc-permute k-dim
__global__ void prep_weights(const float* __restrict__ Wqkv, const float* __restrict__ Wo,
                             const float* __restrict__ Wg,
                             const float* __restrict__ W1, const float* __restrict__ W2,
                             u16* __restrict__ Wqp, u16* __restrict__ Wop,
                             u16* __restrict__ Wgp,
                             u16* __restrict__ W1p, u16* __restrict__ W2p) {
  int idx = blockIdx.x * 256 + threadIdx.x;   // 147456 total
  if (idx < NL * 192 * 64) {
    int l = idx / 12288, rem = idx % 12288;
    int j = rem >> 6, c = rem & 63;
    Wqp[l * 12288 + j * 64 + pcmap(c)] = f2bf(Wqkv[idx]);
  } else if (idx < NL * 192 * 64 + NL * 64 * 64) {
    int i2 = idx - NL * 192 * 64;
    int l = i2 >> 12, m = (i2 >> 6) & 63, k = i2 & 63;
    Wop[l * 4096 + m * 64 + pcmap(k)] = f2bf(Wo[i2]);
  } else if (idx < NL * 192 * 64 + 2 * NL * 64 * 64) {
    int i3 = idx - NL * 192 * 64 - NL * 64 * 64;
    int l = i3 >> 12, k = (i3 >> 6) & 63, c = i3 & 63;
    Wgp[l * 4096 + c * 64 + pcmap(k)] = f2bf(Wg[i3]);  // transpose: row=out ch
  } else if (idx < NL * 192 * 64 + 2 * NL * 64 * 64 + NL * 64 * 128) {
    int i4 = idx - (NL * 192 * 64 + 2 * NL * 64 * 64);  // W1: [L][64k][128m]
    int l = i4 >> 13, i3 = i4 & 8191;
    int k = i3 >> 7, m = i3 & 127;
    W1p[l * 8192 + m * 64 + pcmap(k)] = f2bf(W1[i4]);
  } else if (idx < NL * 192 * 64 + 2 * NL * 64 * 64 + 2 * NL * 64 * 128) {
    int i5 = idx - (NL * 192 * 64 + 2 * NL * 64 * 64 + NL * 64 * 128);  // W2: [L][128k][64m]
    int l = i5 >> 13, i3 = i5 & 8191;
    int k = i3 >> 6, m = i3 & 63;
    W2p[l * 8192 + m * 128 + pc128(k)] = f2bf(W2[i5]);
  }
}

// ------------------------------------------------------------- input GEMM
__global__ __launch_bounds__(256) void gemm_in_kernel(const float* __restrict__ X,
                                                      const float* __restrict__ W,
                                                      const float* __restrict__ b,
                                                      float* __restrict__ Y,
                                                      u16* __restrict__ hb) {
  int idx = blockIdx.x * 256 + threadIdx.x;
  int n = idx >> 6, c = idx & 63;
  const float* xr = X + n * CIN;
  float acc = b[c];
#pragma unroll 16
  for (int k = 0; k < CIN; ++k) acc = fmaf(xr[k], W[k * C + c], acc);
  Y[idx] = acc;
  hb[n * 64 + pcmap(c)] = f2bf(acc);
}

// ---------------- fused projection: GCN gemm + t1 init + QKV + V transpose
__global__ __launch_bounds__(128) void proj_mfma(const u16* __restrict__ hb,
                                                 const float* __restrict__ h,
                                                 const u16* __restrict__ Wqp,
                                                 const u16* __restrict__ Wgp,
                                                 const float* __restrict__ bq,
                                                 const float* __restrict__ gb,
                                                 const float* __restrict__ dinv,
                                                 u16* __restrict__ Qb,
                                                 u16* __restrict__ Kb,
                                                 u16* __restrict__ Vt,
                                                 float* __restrict__ xw,
                                                 float* __restrict__ t1) {
  __shared__ u16 ldsv[64 * 17];
  const int tid = threadIdx.x;
  const int lane = tid & 63, w = tid >> 6;
  const int r = lane & 15, q = lane >> 4;
  const int n0 = blockIdx.x * 16;
  const int n = n0 + r;

  short8 hf[2];
#pragma unroll
  for (int s = 0; s < 2; ++s)
    hf[s] = *(const short8*)(hb + (size_t)n * 64 + s * 32 + q * 8);

  if (w == 0) {
    float di = dinv[n];
#pragma unroll
    for (int jt = 0; jt < 4; ++jt) {
      f32x4 a = {};
#pragma unroll
      for (int s = 0; s < 2; ++s) {
        short8 wf = *(const short8*)(Wgp + (jt * 16 + r) * 64 + s * 32 + q * 8);
        a = __builtin_amdgcn_mfma_f32_16x16x32_bf16(wf, hf[s], a, 0, 0, 0);
      }
      int j0 = jt * 16 + q * 4;
      f32x4 hres = *(const f32x4*)&h[(size_t)n * 64 + j0];
      f32x4 gbv = *(const f32x4*)&gb[j0];
      *(f32x4*)&xw[(size_t)n * 64 + j0] = a;
      *(f32x4*)&t1[(size_t)n * 64 + j0] = a * di * di + gbv + hres;
    }
#pragma unroll
    for (int jt = 0; jt < 4; ++jt) {
      f32x4 a = {};
#pragma unroll
      for (int s = 0; s < 2; ++s) {
        short8 wf = *(const short8*)(Wqp + (jt * 16 + r) * 64 + s * 32 + q * 8);
        a = __builtin_amdgcn_mfma_f32_16x16x32_bf16(wf, hf[s], a, 0, 0, 0);
      }
      f32x4 v = (a + *(const f32x4*)&bq[jt * 16 + q * 4]) * ALPHA;
      int pb = ((jt & 2) << 4) | (q << 3) | ((jt & 1) << 2);
      *(u32x2*)(Qb + (size_t)n * 64 + pb) = u32x2{cvtpk(v[0], v[1]), cvtpk(v[2], v[3])};
    }
  } else {
#pragma unroll
    for (int jt = 0; jt < 4; ++jt) {
      f32x4 a = {};
#pragma unroll
      for (int s = 0; s < 2; ++s) {
        short8 wf = *(const short8*)(Wqp + (64 + jt * 16 + r) * 64 + s * 32 + q * 8);
        a = __builtin_amdgcn_mfma_f32_16x16x32_bf16(wf, hf[s], a, 0, 0, 0);
      }
      f32x4 v = a + *(const f32x4*)&bq[64 + jt * 16 + q * 4];
      int pb = ((jt & 2) << 4) | (q << 3) | ((jt & 1) << 2);
      *(u32x2*)(Kb + (size_t)n * 64 + pb) = u32x2{cvtpk(v[0], v[1]), cvtpk(v[2], v[3])};
    }
#pragma unroll
    for (int jt = 0; jt < 4; ++jt) {
      f32x4 a = {};
#pragma unroll
      for (int s = 0; s < 2; ++s) {
        short8 wf = *(const short8*)(Wqp + (128 + jt * 16 + r) * 64 + s * 32 + q * 8);
        a = __builtin_amdgcn_mfma_f32_16x16x32_bf16(wf, hf[s], a, 0, 0, 0);
      }
      f32x4 v = a + *(const f32x4*)&bq[128 + jt * 16 + q * 4];
      int j0 = jt * 16 + q * 4;
#pragma unroll
      for (int e = 0; e < 4; ++e) ldsv[(j0 + e) * 17 + r] = f2bf(v[e]);
    }
  }
  __syncthreads();

  const int d = tid >> 1, cp = tid & 1;
  const int grp = n0 & ~31, hh = (n0 >> 4) & 1;
#pragma unroll
  for (int ci = 0; ci < 2; ++ci) {
    int cc = cp * 2 + ci;
    u16 a0 = ldsv[d * 17 + cc * 4 + 0];
    u16 a1 = ldsv[d * 17 + cc * 4 + 1];
    u16 a2 = ldsv[d * 17 + cc * 4 + 2];
    u16 a3 = ldsv[d * 17 + cc * 4 + 3];
    *(u32x2*)(Vt + (size_t)d * NN + grp + cc * 8 + hh * 4) =
        u32x2{(unsigned)a0 | ((unsigned)a1 << 16), (unsigned)a2 | ((unsigned)a3 << 16)};
  }
}

// --------------------------- GCN gather (CSR, ewt) + fused BN stats1
__global__ __launch_bounds__(256) void gcn_gather(const int* __restrict__ rowptr,
                                                  const int* __restrict__ esrc,
                                                  const float* __restrict__ ewt,
                                                  const float* __restrict__ xw,
                                                  const float* __restrict__ dinv,
                                                  float* __restrict__ t1,
                                                  float* __restrict__ stats) {
  __shared__ float gs[4][64], gss[4][64];
  int w = threadIdx.x >> 6, lane = threadIdx.x & 63;
  float s = 0.f, ss = 0.f;
#pragma unroll
  for (int rr = 0; rr < 2; ++rr) {
    int d = blockIdx.x * 8 + w * 2 + rr;
    int beg = rowptr[d], end = rowptr[d + 1];
    float acc = 0.f;
    int i = beg;
    for (; i + 4 <= end; i += 4) {
      int s0 = esrc[i], s1 = esrc[i + 1], s2 = esrc[i + 2], s3 = esrc[i + 3];
      float w0 = ewt[i], w1 = ewt[i + 1], w2 = ewt[i + 2], w3 = ewt[i + 3];
      float x0 = xw[(size_t)s0 * 64 + lane];
      float x1 = xw[(size_t)s1 * 64 + lane];
      float x2 = xw[(size_t)s2 * 64 + lane];
      float x3 = xw[(size_t)s3 * 64 + lane];
      acc = fmaf(x0, w0, acc);
      acc = fmaf(x1, w1, acc);
      acc = fmaf(x2, w2, acc);
      acc = fmaf(x3, w3, acc);
    }
    for (; i < end; ++i) acc = fmaf(xw[(size_t)esrc[i] * 64 + lane], ewt[i], acc);
    size_t idx = (size_t)d * 64 + lane;
    float v = t1[idx] + acc * dinv[d];
    t1[idx] = v;
    s += v; ss += v * v;
  }
  gs[w][lane] = s; gss[w][lane] = ss;
  __syncthreads();
  int t = threadIdx.x;
  if (t < 64) atomicAdd(&stats[t], gs[0][t] + gs[1][t] + gs[2][t] + gs[3][t]);
  else if (t < 128) {
    int c = t - 64;
    atomicAdd(&stats[64 + c], gss[0][c] + gss[1][c] + gss[2][c] + gss[3][c]);
  }
}

// ------------------------------------------------------------ MFMA flash attention
// round-14 structure: grid 256 = 128 qt x 2 ks; 512 thr (8 waves). Block: 64 Q
// rows, 4096 keys; wave: 512 keys = 8 tiles of 64. Deferred ll reduce.
// THIS ROUND: s_setprio(1) around MFMA clusters (T5; waves at different phases).
__device__ __forceinline__ void loadK(short8 (&kf)[8], const u16* kb, int koff) {
#pragma unroll
  for (int jt = 0; jt < 4; ++jt)
#pragma unroll
    for (int s = 0; s < 2; ++s)
      kf[jt * 2 + s] = *(const short8*)(kb + koff + jt * 1024 + s * 32);
}

__device__ __forceinline__ void loadV(short8 (&vf)[8], const u16* vb, int voff) {
#pragma unroll
  for (int dt = 0; dt < 4; ++dt)
#pragma unroll
    for (int s = 0; s < 2; ++s)
      vf[dt * 2 + s] = *(const short8*)(vb + voff + dt * 16 * NN + s * 32);
}

__device__ __forceinline__ void computeTile(const short8 (&kf)[8], const short8 (&vf)[8],
                                            const short8 (&qf)[4][2],
                                            f32x4 (&o)[4][4], float (&ll)[4]) {
#pragma unroll
  for (int pair = 0; pair < 2; ++pair) {
    f32x4 st[2][4] = {};
    __builtin_amdgcn_s_setprio(1);
#pragma unroll
    for (int s = 0; s < 2; ++s)
#pragma unroll
      for (int jp = 0; jp < 2; ++jp) {
        short8 kfrag = kf[(pair * 2 + jp) * 2 + s];
#pragma unroll
        for (int it = 0; it < 4; ++it)
          st[jp][it] = __builtin_amdgcn_mfma_f32_16x16x32_bf16(kfrag, qf[it][s], st[jp][it], 0, 0, 0);
      }
    __builtin_amdgcn_s_setprio(0);
    short8 pf[4];
#pragma unroll
    for (int it = 0; it < 4; ++it) {
      float p[8];
#pragma unroll
      for (int jp = 0; jp < 2; ++jp)
#pragma unroll
        for (int r = 0; r < 4; ++r) p[jp * 4 + r] = exp2f(st[jp][it][r]);
      ll[it] += ((p[0] + p[1]) + (p[2] + p[3])) + ((p[4] + p[5]) + (p[6] + p[7]));
      u32x4 a;
      a[0] = cvtpk(p[0], p[1]); a[1] = cvtpk(p[2], p[3]);
      a[2] = cvtpk(p[4], p[5]); a[3] = cvtpk(p[6], p[7]);
      pf[it] = __builtin_bit_cast(short8, a);
    }
    __builtin_amdgcn_s_setprio(1);
#pragma unroll
    for (int dt = 0; dt < 4; ++dt) {
      short8 vfrag = vf[dt * 2 + pair];
#pragma unroll
      for (int it = 0; it < 4; ++it)
        o[dt][it] = __builtin_amdgcn_mfma_f32_16x16x32_bf16(vfrag, pf[it], o[dt][it], 0, 0, 0);
    }
    __builtin_amdgcn_s_setprio(0);
  }
}

__global__ __launch_bounds__(512, 2)
void attn_mfma(const u16* __restrict__ Qb, const u16* __restrict__ Kb,
               const u16* __restrict__ Vtb, float* __restrict__ Opart,
               float* __restrict__ Lpart) {
  __shared__ float fsm[2 * 64 * 68 + 2 * 64];
  const int tid = threadIdx.x;
  const int lane = tid & 63;
  const int w = tid >> 6;
  const int qt = blockIdx.x >> 1, ks = blockIdx.x & 1;
  const int qbase = qt * 64;
  const int kv0 = ks * 4096 + w * 512;
  const int r = lane & 15, q = lane >> 4;

  short8 qf[4][2];
#pragma unroll
  for (int it = 0; it < 4; ++it)
#pragma unroll
    for (int s = 0; s < 2; ++s)
      qf[it][s] = *(const short8*)(Qb + (size_t)(qbase + it * 16 + r) * 64 + s * 32 + q * 8);

  f32x4 o[4][4] = {};
  float ll[4] = {0.f, 0.f, 0.f, 0.f};

  const u16* kb = Kb + (size_t)(kv0 + r) * 64 + q * 8;
  const u16* vb = Vtb + (size_t)r * NN + kv0 + q * 8;

  short8 kA[8], kB[8], vf[8];
  loadK(kA, kb, 0);
#pragma unroll 1
  for (int t = 0; t < 8; t += 2) {
    loadV(vf, vb, t * 64);
    loadK(kB, kb, (t + 1) * 4096);
    computeTile(kA, vf, qf, o, ll);
    loadV(vf, vb, (t + 1) * 64);
    if (t + 2 < 8) loadK(kA, kb, (t + 2) * 4096);
    computeTile(kB, vf, qf, o, ll);
  }

#pragma unroll
  for (int it = 0; it < 4; ++it) {
    ll[it] += __shfl_xor(ll[it], 16);
    ll[it] += __shfl_xor(ll[it], 32);
  }

  // ---- 8-wave merge: 2 LDS bufs, 4 rounds
  float* buf = fsm + (w & 1) * (64 * 68);
  float* lb = fsm + 2 * 64 * 68 + (w & 1) * 64;
  for (int rr = 0; rr < 4; ++rr) {
    if ((w >> 1) == rr) {
      if (rr == 0) {
#pragma unroll
        for (int dt = 0; dt < 4; ++dt)
#pragma unroll
          for (int it = 0; it < 4; ++it)
            *(f32x4*)&buf[(it * 16 + r) * 68 + dt * 16 + q * 4] = o[dt][it];
        if (lane < 16)
#pragma unroll
          for (int it = 0; it < 4; ++it) lb[it * 16 + lane] = ll[it];
      } else {
#pragma unroll
        for (int dt = 0; dt < 4; ++dt)
#pragma unroll
          for (int it = 0; it < 4; ++it) {
            float* p = &buf[(it * 16 + r) * 68 + dt * 16 + q * 4];
            *(f32x4*)p = *(const f32x4*)p + o[dt][it];
          }
        if (lane < 16)
#pragma unroll
          for (int it = 0; it < 4; ++it) lb[it * 16 + lane] += ll[it];
      }
    }
    __syncthreads();
  }

  int row = tid >> 3, d0 = (tid & 7) * 8;
  float* outp = Opart + (size_t)(qt * 2 + ks) * 4096 + row * 64 + d0;
  const float* b0 = fsm + row * 68 + d0;
  const float* b1 = b0 + 64 * 68;
#pragma unroll
  for (int j = 0; j < 8; ++j) outp[j] = b0[j] + b1[j];
  if (tid < 64)
    Lpart[(qt * 2 + ks) * 64 + tid] = fsm[2 * 64 * 68 + tid] + fsm[2 * 64 * 68 + 64 + tid];
}

// ------ O-projection MFMA (+2-way merge +1/l +bias +res) + fused BN stats2
__global__ __launch_bounds__(256) void oproj_mfma(const float* __restrict__ Opart,
                                                  const float* __restrict__ Lpart,
                                                  const u16* __restrict__ Wop,
                                                  const float* __restrict__ bo,
                                                  const float* __restrict__ res,
                                                  float* __restrict__ Y,
                                                  float* __restrict__ stats) {
  __shared__ u16 ldso[32 * 72];
  __shared__ float os[2][64], oss[2][64];
  const int tid = threadIdx.x;
  const int n0 = blockIdx.x * 32;
  const int qtile = n0 >> 6;

  {
    int row = tid >> 3, c0 = (tid & 7) * 8;
    int r64 = (n0 + row) & 63;
    float inv = 1.f / (Lpart[qtile * 128 + r64] + Lpart[qtile * 128 + 64 + r64]);
    const float* O0 = Opart + (size_t)(qtile * 2) * 4096 + r64 * 64;
    const float* O1 = O0 + 4096;
#pragma unroll
    for (int j8 = 0; j8 < 2; ++j8) {
      f32x4 a = *(const f32x4*)&O0[c0 + j8 * 4];
      f32x4 b = *(const f32x4*)&O1[c0 + j8 * 4];
      f32x4 vsum = (a + b) * inv;
#pragma unroll
      for (int e = 0; e < 4; ++e) ldso[row * 72 + pcmap(c0 + j8 * 4 + e)] = f2bf(vsum[e]);
    }
  }
  __syncthreads();

  const int lane = tid & 63, w = tid >> 6;
  const int r = lane & 15, q = lane >> 4;
  const int ntile = w & 1, mhalf = w >> 1;
  short8 hf[2];
#pragma unroll
  for (int s = 0; s < 2; ++s)
    hf[s] = *(const short8*)&ldso[(ntile * 16 + r) * 72 + s * 32 + q * 8];

  const int n = n0 + ntile * 16 + r;
#pragma unroll
  for (int mi = 0; mi < 2; ++mi) {
    int mt = mhalf * 2 + mi;
    f32x4 a = {};
#pragma unroll
    for (int s = 0; s < 2; ++s) {
      short8 wf = *(const short8*)(Wop + (mt * 16 + r) * 64 + s * 32 + q * 8);
      a = __builtin_amdgcn_mfma_f32_16x16x32_bf16(wf, hf[s], a, 0, 0, 0);
    }
    int m0 = mt * 16 + q * 4;
    f32x4 out = a + *(const f32x4*)&bo[m0] + *(const f32x4*)&res[(size_t)n * 64 + m0];
    *(f32x4*)&Y[(size_t)n * 64 + m0] = out;
    f32x4 s_ = out, q_ = out * out;
#pragma unroll
    for (int off = 1; off < 16; off <<= 1) {
#pragma unroll
      for (int e = 0; e < 4; ++e) {
        s_[e] += __shfl_xor(s_[e], off);
        q_[e] += __shfl_xor(q_[e], off);
      }
    }
    if (r == 0) {
#pragma unroll
      for (int e = 0; e < 4; ++e) {
        os[ntile][m0 + e] = s_[e];
        oss[ntile][m0 + e] = q_[e];
      }
    }
  }
  __syncthreads();
  if (tid < 64) atomicAdd(&stats[tid], os[0][tid] + os[1][tid]);
  else if (tid < 128) {
    int c = tid - 64;
    atomicAdd(&stats[64 + c], oss[0][c] + oss[1][c]);
  }
}

// -------- fused combine(bn1+bn2) + MLP via MFMA (+relu +residual) + BN stats3
__global__ __launch_bounds__(256) void mlp_mfma(const float* __restrict__ t1,
                                                const float* __restrict__ t0,
                                                const float* __restrict__ s1,
                                                const float* __restrict__ s2,
                                                const float* __restrict__ g1,
                                                const float* __restrict__ bb1,
                                                const float* __restrict__ g2,
                                                const float* __restrict__ bb2,
                                                const u16* __restrict__ W1p,
                                                const float* __restrict__ b1,
                                                const u16* __restrict__ W2p,
                                                const float* __restrict__ b2,
                                                float* __restrict__ t4,
                                                float* __restrict__ stats) {
  __shared__ float rows[32][68];
  __shared__ u16 xb[32 * 72];
  __shared__ u16 midb[32 * 136];
  __shared__ float os[2][64], oss[2][64];
  int t = threadIdx.x;
  int r0 = blockIdx.x * 32;

  for (int i = t; i < 2048; i += 256) {
    int rr = i >> 6, c = i & 63;
    int idx = (r0 + rr) * 64 + c;
    float m1 = s1[c] * (1.f / NN);
    float v1 = s1[64 + c] * (1.f / NN) - m1 * m1;
    float m2 = s2[c] * (1.f / NN);
    float v2 = s2[64 + c] * (1.f / NN) - m2 * m2;
    float val = (t1[idx] - m1) * rsqrtf(v1 + EPSV) * g1[c] + bb1[c] +
                (t0[idx] - m2) * rsqrtf(v2 + EPSV) * g2[c] + bb2[c];
    rows[rr][c] = val;
    xb[rr * 72 + pcmap(c)] = f2bf(val);
  }
  __syncthreads();

  const int lane = t & 63, w = t >> 6;
  const int r = lane & 15, q = lane >> 4;
  const int ntile = w & 1, mgrp = w >> 1;

  short8 hf[2];
#pragma unroll
  for (int s = 0; s < 2; ++s)
    hf[s] = *(const short8*)&xb[(ntile * 16 + r) * 72 + s * 32 + q * 8];

#pragma unroll
  for (int mi = 0; mi < 4; ++mi) {
    int mt = mgrp * 4 + mi;
    f32x4 a = {};
#pragma unroll
    for (int s = 0; s < 2; ++s) {
      short8 wf = *(const short8*)(W1p + (mt * 16 + r) * 64 + s * 32 + q * 8);
      a = __builtin_amdgcn_mfma_f32_16x16x32_bf16(wf, hf[s], a, 0, 0, 0);
    }
    int m0 = mt * 16 + q * 4;
    f32x4 v = a + *(const f32x4*)&b1[m0];
#pragma unroll
    for (int e = 0; e < 4; ++e)
      midb[(ntile * 16 + r) * 136 + pc128(m0 + e)] = f2bf(fmaxf(v[e], 0.f));
  }
  __syncthreads();

  short8 mf[4];
#pragma unroll
  for (int s = 0; s < 4; ++s)
    mf[s] = *(const short8*)&midb[(ntile * 16 + r) * 136 + s * 32 + q * 8];

  const int n = r0 + ntile * 16 + r;
#pragma unroll
  for (int mi = 0; mi < 2; ++mi) {
    int mt = mgrp * 2 + mi;
    f32x4 a = {};
#pragma unroll
    for (int s = 0; s < 4; ++s) {
      short8 wf = *(const short8*)(W2p + (mt * 16 + r) * 128 + s * 32 + q * 8);
      a = __builtin_amdgcn_mfma_f32_16x16x32_bf16(wf, mf[s], a, 0, 0, 0);
    }
    int m0 = mt * 16 + q * 4;
    f32x4 out = a + *(const f32x4*)&b2[m0] + *(const f32x4*)&rows[ntile * 16 + r][m0];
    *(f32x4*)&t4[(size_t)n * 64 + m0] = out;
    f32x4 s_ = out, q_ = out * out;
#pragma unroll
    for (int off = 1; off < 16; off <<= 1) {
#pragma unroll
      for (int e = 0; e < 4; ++e) {
        s_[e] += __shfl_xor(s_[e], off);
        q_[e] += __shfl_xor(q_[e], off);
      }
    }
    if (r == 0) {
#pragma unroll
      for (int e = 0; e < 4; ++e) {
        os[ntile][m0 + e] = s_[e];
        oss[ntile][m0 + e] = q_[e];
      }
    }
  }
  __syncthreads();
  if (t < 64) atomicAdd(&stats[t], os[0][t] + os[1][t]);
  else if (t < 128) {
    int c = t - 64;
    atomicAdd(&stats[64 + c], oss[0][c] + oss[1][c]);
  }
}

// ------------------------------------------- BN3 + LayerNorm + ReLU (fused)
__global__ __launch_bounds__(256) void bn3_ln_relu(const float* __restrict__ t4,
                                                   const float* __restrict__ s3,
                                                   const float* __restrict__ g3,
                                                   const float* __restrict__ b3,
                                                   const float* __restrict__ lg,
                                                   const float* __restrict__ lb,
                                                   float* __restrict__ H,
                                                   u16* __restrict__ hb) {
  int wv = threadIdx.x >> 6, lane = threadIdx.x & 63;
  int n = blockIdx.x * 4 + wv;
  float m3 = s3[lane] * (1.f / NN);
  float v3 = s3[64 + lane] * (1.f / NN) - m3 * m3;
  float x = (t4[n * 64 + lane] - m3) * rsqrtf(v3 + EPSV) * g3[lane] + b3[lane];
  float s = x, ss = x * x;
  for (int o = 32; o > 0; o >>= 1) {
    s += __shfl_xor(s, o, 64);
    ss += __shfl_xor(ss, o, 64);
  }
  float m = s * (1.f / 64), v = ss * (1.f / 64) - m * m;
  float y = (x - m) * rsqrtf(v + EPSV) * lg[lane] + lb[lane];
  y = fmaxf(y, 0.f);
  H[n * 64 + lane] = y;
  hb[n * 64 + pcmap(lane)] = f2bf(y);
}

// ------------------------------------------- final GEMM (64x21) + log_softmax
__global__ __launch_bounds__(256) void final_kernel(const float* __restrict__ H,
                                                    const float* __restrict__ Wout,
                                                    const float* __restrict__ bout,
                                                    float* __restrict__ out) {
  int w = threadIdx.x >> 6, lane = threadIdx.x & 63;
  int n = blockIdx.x * 4 + w;
  const float* hr = H + n * 64;
  float acc = (lane < COUT) ? bout[lane] : -INFINITY;
  if (lane < COUT) {
#pragma unroll 16
    for (int k = 0; k < 64; ++k) acc = fmaf(hr[k], Wout[k * COUT + lane], acc);
  }
  float mx = acc;
  for (int o = 32; o > 0; o >>= 1) mx = fmaxf(mx, __shfl_xor(mx, o, 64));
  float e = __expf(acc - mx);
  float se = e;
  for (int o = 32; o > 0; o >>= 1) se += __shfl_xor(se, o, 64);
  float lse = mx + logf(se);
  if (lane < COUT) out[n * COUT + lane] = acc - lse;
}

// ================================================================ launch
extern "C" void kernel_launch(void* const* d_in, const int* in_sizes, int n_in,
                              void* d_out, int out_size, void* d_ws, size_t ws_size,
                              hipStream_t stream) {
  const float* x    = (const float*)d_in[0];
  const int*   ei   = (const int*)d_in[1];
  const float* W_in = (const float*)d_in[2];
  const float* b_in = (const float*)d_in[3];
  const float* gcnW = (const float*)d_in[4];
  const float* gcnB = (const float*)d_in[5];
  const float* Wqkv = (const float*)d_in[6];
  const float* bqkv = (const float*)d_in[7];
  const float* Wo   = (const float*)d_in[8];
  const float* bo   = (const float*)d_in[9];
  const float* bn1g = (const float*)d_in[10];
  const float* bn1b = (const float*)d_in[11];
  const float* bn2g = (const float*)d_in[12];
  const float* bn2b = (const float*)d_in[13];
  const float* bn3g = (const float*)d_in[14];
  const float* bn3b = (const float*)d_in[15];
  const float* W1   = (const float*)d_in[16];
  const float* b1   = (const float*)d_in[17];
  const float* W2   = (const float*)d_in[18];
  const float* b2   = (const float*)d_in[19];
  const float* lng  = (const float*)d_in[20];
  const float* lnb  = (const float*)d_in[21];
  const float* Wout = (const float*)d_in[22];
  const float* bout = (const float*)d_in[23];

  const int* src = ei;
  const int* dst = ei + NE;

  const int NC = NN * C;
  float* ws = (float*)d_ws;
  float* h     = ws + 0 * NC;
  float* t0    = ws + 1 * NC;     // xw (gather input), then oproj output
  float* t1    = ws + 2 * NC;
  float* Opart = ws + 3 * NC;     // 4MB: 128qt x 2ks x 64 x 64
  float* t4    = ws + 5 * NC;
  u16* Qb  = (u16*)(ws + 6 * NC);
  u16* Kb  = Qb + NC;
  u16* Vtb = Kb + NC;
  u16* hbb = Vtb + NC;
  u16* Wqp = hbb + NC;            // NL x 192 x 64
  u16* Wop = Wqp + NL * 192 * 64; // NL x 64 x 64
  u16* Wgp = Wop + NL * 64 * 64;  // NL x 64 x 64
  u16* W1p = Wgp + NL * 64 * 64;  // NL x 128 x 64
  u16* W2p = W1p + NL * 128 * 64; // NL x 64 x 128
  float* dinv = (float*)(W2p + NL * 64 * 128);
  float* statsAll = dinv + NN;    // 12 x 128
  float* Lpart = statsAll + 1536; // 128qt x 2ks x 64
  int* degi   = (int*)(Lpart + 16384);
  int* rowptr = degi + NN;        // NN+1
  int* cursor = rowptr + NN + 8;
  int* esrc   = cursor + NN;      // NE
  float* ewt  = (float*)(esrc + NE);  // NE

  dim3 B(256);

  // ---- setup: CSR + dinv + weight prep (deterministic; recomputed per call)
  zero_setup<<<32, B, 0, stream>>>(statsAll, degi);
  deg_kernel<<<NE / 256, B, 0, stream>>>(dst, degi);
  prefix_kernel<<<1, B, 0, stream>>>(degi, rowptr, cursor);
  dinv_kernel<<<NN / 256, B, 0, stream>>>(degi, dinv);
  fill_kernel<<<NE / 256, B, 0, stream>>>(src, dst, dinv, cursor, esrc, ewt);
  prep_weights<<<576, B, 0, stream>>>(Wqkv, Wo, gcnW, W1, W2, Wqp, Wop, Wgp, W1p, W2p);

  gemm_in_kernel<<<NN * C / 256, B, 0, stream>>>(x, W_in, b_in, h, hbb);

  for (int l = 0; l < NL; ++l) {
    float* s1 = statsAll + l * 384;
    float* s2 = s1 + 128;
    float* s3 = s1 + 256;

    // ---- fused projection: gcn gemm + t1 init + QKV + Vt
    proj_mfma<<<NN / 16, 128, 0, stream>>>(hbb, h, Wqp + l * 192 * 64, Wgp + l * 4096,
                                           bqkv + l * 192, gcnB + l * C, dinv,
                                           Qb, Kb, Vtb, t0, t1);
    // ---- gather + fused stats1
    gcn_gather<<<NN / 8, B, 0, stream>>>(rowptr, esrc, ewt, t0, dinv, t1, s1);

    // ---- global attention branch + residual -> t0, fused stats2
    attn_mfma<<<256, 512, 0, stream>>>(Qb, Kb, Vtb, Opart, Lpart);
    oproj_mfma<<<NN / 32, B, 0, stream>>>(Opart, Lpart, Wop + l * 4096, bo + l * C, h, t0, s2);

    // ---- combine + MLP (MFMA) -> t4 + fused stats3, then BN3 + LN + ReLU -> h (+hb)
    mlp_mfma<<<NN / 32, B, 0, stream>>>(t1, t0, s1, s2, bn1g + l * C, bn1b + l * C,
                                        bn2g + l * C, bn2b + l * C,
                                        W1p + l * 8192, b1 + l * 2 * C,
                                        W2p + l * 8192, b2 + l * C, t4, s3);
    bn3_ln_relu<<<NN / 4, B, 0, stream>>>(t4, s3, bn3g + l * C, bn3b + l * C,
                                          lng + l * C, lnb + l * C, h, hbb);
  }

  final_kernel<<<NN / 4, B, 0, stream>>>(h, Wout, bout, (float*)d_out);
}

// Round 18
// 529.942 us; speedup vs baseline: 1.5113x; 1.0646x over previous
//
#include <hip/hip_runtime.h>
#include <math.h>

#define NN 8192
#define NE 131072
#define CIN 128
#define C 64
#define NL 4
#define COUT 21
#define EPSV 1e-5f
#define ALPHA 0.18033688011112043f  // 0.125 * log2(e)

typedef unsigned short u16;
typedef __attribute__((ext_vector_type(8))) short short8;
typedef __attribute__((ext_vector_type(4))) float f32x4;
typedef __attribute__((ext_vector_type(4))) unsigned int u32x4;
typedef __attribute__((ext_vector_type(2))) unsigned int u32x2;

__device__ __forceinline__ u16 f2bf(float x) {
  unsigned int u = __float_as_uint(x);
  u += 0x7FFF + ((u >> 16) & 1);
  return (u16)(u >> 16);
}

__device__ __forceinline__ unsigned cvtpk(float a, float b) {
  unsigned r;
  asm("v_cvt_pk_bf16_f32 %0, %1, %2" : "=v"(r) : "v"(a), "v"(b));
  return r;
}

__device__ __forceinline__ int pcmap(int c) {  // k-dim permutation (within 32), c<64
  return (c & 32) | (c & 3) | (((c >> 2) & 3) << 3) | (((c >> 4) & 1) << 2);
}

__device__ __forceinline__ int pc128(int c) {  // same, for c<128
  return (c & 96) | (c & 3) | (((c >> 2) & 3) << 3) | (((c >> 4) & 1) << 2);
}

// ---------------------------------------------------------------- setup
__global__ void zero_setup(float* __restrict__ stats, int* __restrict__ degi) {
  int i = blockIdx.x * 256 + threadIdx.x;
  if (i < 1536) stats[i] = 0.f;
  if (i < NN) degi[i] = 0;
}

__global__ void deg_kernel(const int* __restrict__ dst, int* __restrict__ degi) {
  int e = blockIdx.x * 256 + threadIdx.x;
  if (e < NE) atomicAdd(&degi[dst[e]], 1);
}

__global__ __launch_bounds__(256) void prefix_kernel(const int* __restrict__ degi,
                                                     int* __restrict__ rowptr,
                                                     int* __restrict__ cursor) {
  __shared__ int part[256];
  int t = threadIdx.x;
  int base = t * 32;
  int loc[32];
  int s = 0;
#pragma unroll
  for (int i = 0; i < 32; ++i) { loc[i] = s; s += degi[base + i]; }
  part[t] = s;
  __syncthreads();
  for (int off = 1; off < 256; off <<= 1) {
    int v = (t >= off) ? part[t - off] : 0;
    __syncthreads();
    part[t] += v;
    __syncthreads();
  }
  int chunkbase = (t == 0) ? 0 : part[t - 1];
#pragma unroll
  for (int i = 0; i < 32; ++i) {
    int v = chunkbase + loc[i];
    rowptr[base + i] = v;
    cursor[base + i] = v;
  }
  if (t == 255) rowptr[NN] = part[255];
}

__global__ void dinv_kernel(const int* __restrict__ degi, float* __restrict__ dinv) {
  int i = blockIdx.x * 256 + threadIdx.x;
  if (i < NN) dinv[i] = rsqrtf((float)degi[i] + 1.0f);
}

__global__ void fill_kernel(const int* __restrict__ src, const int* __restrict__ dst,
                            const float* __restrict__ dinv,
                            int* __restrict__ cursor, int* __restrict__ esrc,
                            float* __restrict__ ewt) {
  int e = blockIdx.x * 256 + threadIdx.x;
  if (e < NE) {
    int d = dst[e];
    int s = src[e];
    int pos = atomicAdd(&cursor[d], 1);
    esrc[pos] = s;
    ewt[pos] = dinv[s];
  }
}

// ------------------------------------- weight prep: bf16 + pc-permute k-dim
__global__ void prep_weights(const float* __restrict__ Wqkv, const float* __restrict__ Wo,
                             const float* __restrict__ Wg,
                             const float* __restrict__ W1, const float* __restrict__ W2,
                             u16* __restrict__ Wqp, u16* __restrict__ Wop,
                             u16* __restrict__ Wgp,
                             u16* __restrict__ W1p, u16* __restrict__ W2p) {
  int idx = blockIdx.x * 256 + threadIdx.x;   // 147456 total
  if (idx < NL * 192 * 64) {
    int l = idx / 12288, rem = idx % 12288;
    int j = rem >> 6, c = rem & 63;
    Wqp[l * 12288 + j * 64 + pcmap(c)] = f2bf(Wqkv[idx]);
  } else if (idx < NL * 192 * 64 + NL * 64 * 64) {
    int i2 = idx - NL * 192 * 64;
    int l = i2 >> 12, m = (i2 >> 6) & 63, k = i2 & 63;
    Wop[l * 4096 + m * 64 + pcmap(k)] = f2bf(Wo[i2]);
  } else if (idx < NL * 192 * 64 + 2 * NL * 64 * 64) {
    int i3 = idx - NL * 192 * 64 - NL * 64 * 64;
    int l = i3 >> 12, k = (i3 >> 6) & 63, c = i3 & 63;
    Wgp[l * 4096 + c * 64 + pcmap(k)] = f2bf(Wg[i3]);  // transpose: row=out ch
  } else if (idx < NL * 192 * 64 + 2 * NL * 64 * 64 + NL * 64 * 128) {
    int i4 = idx - (NL * 192 * 64 + 2 * NL * 64 * 64);  // W1: [L][64k][128m]
    int l = i4 >> 13, i3 = i4 & 8191;
    int k = i3 >> 7, m = i3 & 127;
    W1p[l * 8192 + m * 64 + pcmap(k)] = f2bf(W1[i4]);
  } else if (idx < NL * 192 * 64 + 2 * NL * 64 * 64 + 2 * NL * 64 * 128) {
    int i5 = idx - (NL * 192 * 64 + 2 * NL * 64 * 64 + NL * 64 * 128);  // W2: [L][128k][64m]
    int l = i5 >> 13, i3 = i5 & 8191;
    int k = i3 >> 6, m = i3 & 63;
    W2p[l * 8192 + m * 128 + pc128(k)] = f2bf(W2[i5]);
  }
}

// ------------------------------------------------------------- input GEMM
__global__ __launch_bounds__(256) void gemm_in_kernel(const float* __restrict__ X,
                                                      const float* __restrict__ W,
                                                      const float* __restrict__ b,
                                                      float* __restrict__ Y,
                                                      u16* __restrict__ hb) {
  int idx = blockIdx.x * 256 + threadIdx.x;
  int n = idx >> 6, c = idx & 63;
  const float* xr = X + n * CIN;
  float acc = b[c];
#pragma unroll 16
  for (int k = 0; k < CIN; ++k) acc = fmaf(xr[k], W[k * C + c], acc);
  Y[idx] = acc;
  hb[n * 64 + pcmap(c)] = f2bf(acc);
}

// ---------------- fused projection: GCN gemm + t1 init + QKV + V transpose
__global__ __launch_bounds__(128) void proj_mfma(const u16* __restrict__ hb,
                                                 const float* __restrict__ h,
                                                 const u16* __restrict__ Wqp,
                                                 const u16* __restrict__ Wgp,
                                                 const float* __restrict__ bq,
                                                 const float* __restrict__ gb,
                                                 const float* __restrict__ dinv,
                                                 u16* __restrict__ Qb,
                                                 u16* __restrict__ Kb,
                                                 u16* __restrict__ Vt,
                                                 float* __restrict__ xw,
                                                 float* __restrict__ t1) {
  __shared__ u16 ldsv[64 * 17];
  const int tid = threadIdx.x;
  const int lane = tid & 63, w = tid >> 6;
  const int r = lane & 15, q = lane >> 4;
  const int n0 = blockIdx.x * 16;
  const int n = n0 + r;

  short8 hf[2];
#pragma unroll
  for (int s = 0; s < 2; ++s)
    hf[s] = *(const short8*)(hb + (size_t)n * 64 + s * 32 + q * 8);

  if (w == 0) {
    float di = dinv[n];
#pragma unroll
    for (int jt = 0; jt < 4; ++jt) {
      f32x4 a = {};
#pragma unroll
      for (int s = 0; s < 2; ++s) {
        short8 wf = *(const short8*)(Wgp + (jt * 16 + r) * 64 + s * 32 + q * 8);
        a = __builtin_amdgcn_mfma_f32_16x16x32_bf16(wf, hf[s], a, 0, 0, 0);
      }
      int j0 = jt * 16 + q * 4;
      f32x4 hres = *(const f32x4*)&h[(size_t)n * 64 + j0];
      f32x4 gbv = *(const f32x4*)&gb[j0];
      *(f32x4*)&xw[(size_t)n * 64 + j0] = a;
      *(f32x4*)&t1[(size_t)n * 64 + j0] = a * di * di + gbv + hres;
    }
#pragma unroll
    for (int jt = 0; jt < 4; ++jt) {
      f32x4 a = {};
#pragma unroll
      for (int s = 0; s < 2; ++s) {
        short8 wf = *(const short8*)(Wqp + (jt * 16 + r) * 64 + s * 32 + q * 8);
        a = __builtin_amdgcn_mfma_f32_16x16x32_bf16(wf, hf[s], a, 0, 0, 0);
      }
      f32x4 v = (a + *(const f32x4*)&bq[jt * 16 + q * 4]) * ALPHA;
      int pb = ((jt & 2) << 4) | (q << 3) | ((jt & 1) << 2);
      *(u32x2*)(Qb + (size_t)n * 64 + pb) = u32x2{cvtpk(v[0], v[1]), cvtpk(v[2], v[3])};
    }
  } else {
#pragma unroll
    for (int jt = 0; jt < 4; ++jt) {
      f32x4 a = {};
#pragma unroll
      for (int s = 0; s < 2; ++s) {
        short8 wf = *(const short8*)(Wqp + (64 + jt * 16 + r) * 64 + s * 32 + q * 8);
        a = __builtin_amdgcn_mfma_f32_16x16x32_bf16(wf, hf[s], a, 0, 0, 0);
      }
      f32x4 v = a + *(const f32x4*)&bq[64 + jt * 16 + q * 4];
      int pb = ((jt & 2) << 4) | (q << 3) | ((jt & 1) << 2);
      *(u32x2*)(Kb + (size_t)n * 64 + pb) = u32x2{cvtpk(v[0], v[1]), cvtpk(v[2], v[3])};
    }
#pragma unroll
    for (int jt = 0; jt < 4; ++jt) {
      f32x4 a = {};
#pragma unroll
      for (int s = 0; s < 2; ++s) {
        short8 wf = *(const short8*)(Wqp + (128 + jt * 16 + r) * 64 + s * 32 + q * 8);
        a = __builtin_amdgcn_mfma_f32_16x16x32_bf16(wf, hf[s], a, 0, 0, 0);
      }
      f32x4 v = a + *(const f32x4*)&bq[128 + jt * 16 + q * 4];
      int j0 = jt * 16 + q * 4;
#pragma unroll
      for (int e = 0; e < 4; ++e) ldsv[(j0 + e) * 17 + r] = f2bf(v[e]);
    }
  }
  __syncthreads();

  const int d = tid >> 1, cp = tid & 1;
  const int grp = n0 & ~31, hh = (n0 >> 4) & 1;
#pragma unroll
  for (int ci = 0; ci < 2; ++ci) {
    int cc = cp * 2 + ci;
    u16 a0 = ldsv[d * 17 + cc * 4 + 0];
    u16 a1 = ldsv[d * 17 + cc * 4 + 1];
    u16 a2 = ldsv[d * 17 + cc * 4 + 2];
    u16 a3 = ldsv[d * 17 + cc * 4 + 3];
    *(u32x2*)(Vt + (size_t)d * NN + grp + cc * 8 + hh * 4) =
        u32x2{(unsigned)a0 | ((unsigned)a1 << 16), (unsigned)a2 | ((unsigned)a3 << 16)};
  }
}

// --------------------------- GCN gather (CSR, ewt) + fused BN stats1
__global__ __launch_bounds__(256) void gcn_gather(const int* __restrict__ rowptr,
                                                  const int* __restrict__ esrc,
                                                  const float* __restrict__ ewt,
                                                  const float* __restrict__ xw,
                                                  const float* __restrict__ dinv,
                                                  float* __restrict__ t1,
                                                  float* __restrict__ stats) {
  __shared__ float gs[4][64], gss[4][64];
  int w = threadIdx.x >> 6, lane = threadIdx.x & 63;
  float s = 0.f, ss = 0.f;
#pragma unroll
  for (int rr = 0; rr < 2; ++rr) {
    int d = blockIdx.x * 8 + w * 2 + rr;
    int beg = rowptr[d], end = rowptr[d + 1];
    float acc = 0.f;
    int i = beg;
    for (; i + 4 <= end; i += 4) {
      int s0 = esrc[i], s1 = esrc[i + 1], s2 = esrc[i + 2], s3 = esrc[i + 3];
      float w0 = ewt[i], w1 = ewt[i + 1], w2 = ewt[i + 2], w3 = ewt[i + 3];
      float x0 = xw[(size_t)s0 * 64 + lane];
      float x1 = xw[(size_t)s1 * 64 + lane];
      float x2 = xw[(size_t)s2 * 64 + lane];
      float x3 = xw[(size_t)s3 * 64 + lane];
      acc = fmaf(x0, w0, acc);
      acc = fmaf(x1, w1, acc);
      acc = fmaf(x2, w2, acc);
      acc = fmaf(x3, w3, acc);
    }
    for (; i < end; ++i) acc = fmaf(xw[(size_t)esrc[i] * 64 + lane], ewt[i], acc);
    size_t idx = (size_t)d * 64 + lane;
    float v = t1[idx] + acc * dinv[d];
    t1[idx] = v;
    s += v; ss += v * v;
  }
  gs[w][lane] = s; gss[w][lane] = ss;
  __syncthreads();
  int t = threadIdx.x;
  if (t < 64) atomicAdd(&stats[t], gs[0][t] + gs[1][t] + gs[2][t] + gs[3][t]);
  else if (t < 128) {
    int c = t - 64;
    atomicAdd(&stats[64 + c], gss[0][c] + gss[1][c] + gss[2][c] + gss[3][c]);
  }
}

// ------------------------------------------------------------ MFMA flash attention
// round-14 structure: grid 256 = 128 qt x 2 ks; 512 thr (8 waves). Block: 64 Q
// rows, 4096 keys; wave: 512 keys = 8 tiles of 64. Deferred ll reduce.
__device__ __forceinline__ void loadK(short8 (&kf)[8], const u16* kb, int koff) {
#pragma unroll
  for (int jt = 0; jt < 4; ++jt)
#pragma unroll
    for (int s = 0; s < 2; ++s)
      kf[jt * 2 + s] = *(const short8*)(kb + koff + jt * 1024 + s * 32);
}

__device__ __forceinline__ void loadV(short8 (&vf)[8], const u16* vb, int voff) {
#pragma unroll
  for (int dt = 0; dt < 4; ++dt)
#pragma unroll
    for (int s = 0; s < 2; ++s)
      vf[dt * 2 + s] = *(const short8*)(vb + voff + dt * 16 * NN + s * 32);
}

__device__ __forceinline__ void computeTile(const short8 (&kf)[8], const short8 (&vf)[8],
                                            const short8 (&qf)[4][2],
                                            f32x4 (&o)[4][4], float (&ll)[4]) {
#pragma unroll
  for (int pair = 0; pair < 2; ++pair) {
    f32x4 st[2][4] = {};
#pragma unroll
    for (int s = 0; s < 2; ++s)
#pragma unroll
      for (int jp = 0; jp < 2; ++jp) {
        short8 kfrag = kf[(pair * 2 + jp) * 2 + s];
#pragma unroll
        for (int it = 0; it < 4; ++it)
          st[jp][it] = __builtin_amdgcn_mfma_f32_16x16x32_bf16(kfrag, qf[it][s], st[jp][it], 0, 0, 0);
      }
    short8 pf[4];
#pragma unroll
    for (int it = 0; it < 4; ++it) {
      float p[8];
#pragma unroll
      for (int jp = 0; jp < 2; ++jp)
#pragma unroll
        for (int r = 0; r < 4; ++r) p[jp * 4 + r] = exp2f(st[jp][it][r]);
      ll[it] += ((p[0] + p[1]) + (p[2] + p[3])) + ((p[4] + p[5]) + (p[6] + p[7]));
      u32x4 a;
      a[0] = cvtpk(p[0], p[1]); a[1] = cvtpk(p[2], p[3]);
      a[2] = cvtpk(p[4], p[5]); a[3] = cvtpk(p[6], p[7]);
      pf[it] = __builtin_bit_cast(short8, a);
    }
#pragma unroll
    for (int dt = 0; dt < 4; ++dt) {
      short8 vfrag = vf[dt * 2 + pair];
#pragma unroll
      for (int it = 0; it < 4; ++it)
        o[dt][it] = __builtin_amdgcn_mfma_f32_16x16x32_bf16(vfrag, pf[it], o[dt][it], 0, 0, 0);
    }
  }
}

__global__ __launch_bounds__(512, 2)
void attn_mfma(const u16* __restrict__ Qb, const u16* __restrict__ Kb,
               const u16* __restrict__ Vtb, float* __restrict__ Opart,
               float* __restrict__ Lpart) {
  __shared__ float fsm[2 * 64 * 68 + 2 * 64];
  const int tid = threadIdx.x;
  const int lane = tid & 63;
  const int w = tid >> 6;
  const int qt = blockIdx.x >> 1, ks = blockIdx.x & 1;
  const int qbase = qt * 64;
  const int kv0 = ks * 4096 + w * 512;
  const int r = lane & 15, q = lane >> 4;

  short8 qf[4][2];
#pragma unroll
  for (int it = 0; it < 4; ++it)
#pragma unroll
    for (int s = 0; s < 2; ++s)
      qf[it][s] = *(const short8*)(Qb + (size_t)(qbase + it * 16 + r) * 64 + s * 32 + q * 8);

  f32x4 o[4][4] = {};
  float ll[4] = {0.f, 0.f, 0.f, 0.f};

  const u16* kb = Kb + (size_t)(kv0 + r) * 64 + q * 8;
  const u16* vb = Vtb + (size_t)r * NN + kv0 + q * 8;

  short8 kA[8], kB[8], vf[8];
  loadK(kA, kb, 0);
#pragma unroll 1
  for (int t = 0; t < 8; t += 2) {
    loadV(vf, vb, t * 64);
    loadK(kB, kb, (t + 1) * 4096);
    computeTile(kA, vf, qf, o, ll);
    loadV(vf, vb, (t + 1) * 64);
    if (t + 2 < 8) loadK(kA, kb, (t + 2) * 4096);
    computeTile(kB, vf, qf, o, ll);
  }

#pragma unroll
  for (int it = 0; it < 4; ++it) {
    ll[it] += __shfl_xor(ll[it], 16);
    ll[it] += __shfl_xor(ll[it], 32);
  }

  // ---- 8-wave merge: 2 LDS bufs, 4 rounds
  float* buf = fsm + (w & 1) * (64 * 68);
  float* lb = fsm + 2 * 64 * 68 + (w & 1) * 64;
  for (int rr = 0; rr < 4; ++rr) {
    if ((w >> 1) == rr) {
      if (rr == 0) {
#pragma unroll
        for (int dt = 0; dt < 4; ++dt)
#pragma unroll
          for (int it = 0; it < 4; ++it)
            *(f32x4*)&buf[(it * 16 + r) * 68 + dt * 16 + q * 4] = o[dt][it];
        if (lane < 16)
#pragma unroll
          for (int it = 0; it < 4; ++it) lb[it * 16 + lane] = ll[it];
      } else {
#pragma unroll
        for (int dt = 0; dt < 4; ++dt)
#pragma unroll
          for (int it = 0; it < 4; ++it) {
            float* p = &buf[(it * 16 + r) * 68 + dt * 16 + q * 4];
            *(f32x4*)p = *(const f32x4*)p + o[dt][it];
          }
        if (lane < 16)
#pragma unroll
          for (int it = 0; it < 4; ++it) lb[it * 16 + lane] += ll[it];
      }
    }
    __syncthreads();
  }

  int row = tid >> 3, d0 = (tid & 7) * 8;
  float* outp = Opart + (size_t)(qt * 2 + ks) * 4096 + row * 64 + d0;
  const float* b0 = fsm + row * 68 + d0;
  const float* b1 = b0 + 64 * 68;
#pragma unroll
  for (int j = 0; j < 8; ++j) outp[j] = b0[j] + b1[j];
  if (tid < 64)
    Lpart[(qt * 2 + ks) * 64 + tid] = fsm[2 * 64 * 68 + tid] + fsm[2 * 64 * 68 + 64 + tid];
}

// ------ O-projection MFMA (+2-way merge +1/l +bias +res) + fused BN stats2
__global__ __launch_bounds__(256) void oproj_mfma(const float* __restrict__ Opart,
                                                  const float* __restrict__ Lpart,
                                                  const u16* __restrict__ Wop,
                                                  const float* __restrict__ bo,
                                                  const float* __restrict__ res,
                                                  float* __restrict__ Y,
                                                  float* __restrict__ stats) {
  __shared__ u16 ldso[32 * 72];
  __shared__ float os[2][64], oss[2][64];
  const int tid = threadIdx.x;
  const int n0 = blockIdx.x * 32;
  const int qtile = n0 >> 6;

  {
    int row = tid >> 3, c0 = (tid & 7) * 8;
    int r64 = (n0 + row) & 63;
    float inv = 1.f / (Lpart[qtile * 128 + r64] + Lpart[qtile * 128 + 64 + r64]);
    const float* O0 = Opart + (size_t)(qtile * 2) * 4096 + r64 * 64;
    const float* O1 = O0 + 4096;
#pragma unroll
    for (int j8 = 0; j8 < 2; ++j8) {
      f32x4 a = *(const f32x4*)&O0[c0 + j8 * 4];
      f32x4 b = *(const f32x4*)&O1[c0 + j8 * 4];
      f32x4 vsum = (a + b) * inv;
#pragma unroll
      for (int e = 0; e < 4; ++e) ldso[row * 72 + pcmap(c0 + j8 * 4 + e)] = f2bf(vsum[e]);
    }
  }
  __syncthreads();

  const int lane = tid & 63, w = tid >> 6;
  const int r = lane & 15, q = lane >> 4;
  const int ntile = w & 1, mhalf = w >> 1;
  short8 hf[2];
#pragma unroll
  for (int s = 0; s < 2; ++s)
    hf[s] = *(const short8*)&ldso[(ntile * 16 + r) * 72 + s * 32 + q * 8];

  const int n = n0 + ntile * 16 + r;
#pragma unroll
  for (int mi = 0; mi < 2; ++mi) {
    int mt = mhalf * 2 + mi;
    f32x4 a = {};
#pragma unroll
    for (int s = 0; s < 2; ++s) {
      short8 wf = *(const short8*)(Wop + (mt * 16 + r) * 64 + s * 32 + q * 8);
      a = __builtin_amdgcn_mfma_f32_16x16x32_bf16(wf, hf[s], a, 0, 0, 0);
    }
    int m0 = mt * 16 + q * 4;
    f32x4 out = a + *(const f32x4*)&bo[m0] + *(const f32x4*)&res[(size_t)n * 64 + m0];
    *(f32x4*)&Y[(size_t)n * 64 + m0] = out;
    f32x4 s_ = out, q_ = out * out;
#pragma unroll
    for (int off = 1; off < 16; off <<= 1) {
#pragma unroll
      for (int e = 0; e < 4; ++e) {
        s_[e] += __shfl_xor(s_[e], off);
        q_[e] += __shfl_xor(q_[e], off);
      }
    }
    if (r == 0) {
#pragma unroll
      for (int e = 0; e < 4; ++e) {
        os[ntile][m0 + e] = s_[e];
        oss[ntile][m0 + e] = q_[e];
      }
    }
  }
  __syncthreads();
  if (tid < 64) atomicAdd(&stats[tid], os[0][tid] + os[1][tid]);
  else if (tid < 128) {
    int c = tid - 64;
    atomicAdd(&stats[64 + c], oss[0][c] + oss[1][c]);
  }
}

// -------- fused combine(bn1+bn2) + MLP via MFMA (+relu +residual) + BN stats3
__global__ __launch_bounds__(256) void mlp_mfma(const float* __restrict__ t1,
                                                const float* __restrict__ t0,
                                                const float* __restrict__ s1,
                                                const float* __restrict__ s2,
                                                const float* __restrict__ g1,
                                                const float* __restrict__ bb1,
                                                const float* __restrict__ g2,
                                                const float* __restrict__ bb2,
                                                const u16* __restrict__ W1p,
                                                const float* __restrict__ b1,
                                                const u16* __restrict__ W2p,
                                                const float* __restrict__ b2,
                                                float* __restrict__ t4,
                                                float* __restrict__ stats) {
  __shared__ float rows[32][68];
  __shared__ u16 xb[32 * 72];
  __shared__ u16 midb[32 * 136];
  __shared__ float os[2][64], oss[2][64];
  int t = threadIdx.x;
  int r0 = blockIdx.x * 32;

  for (int i = t; i < 2048; i += 256) {
    int rr = i >> 6, c = i & 63;
    int idx = (r0 + rr) * 64 + c;
    float m1 = s1[c] * (1.f / NN);
    float v1 = s1[64 + c] * (1.f / NN) - m1 * m1;
    float m2 = s2[c] * (1.f / NN);
    float v2 = s2[64 + c] * (1.f / NN) - m2 * m2;
    float val = (t1[idx] - m1) * rsqrtf(v1 + EPSV) * g1[c] + bb1[c] +
                (t0[idx] - m2) * rsqrtf(v2 + EPSV) * g2[c] + bb2[c];
    rows[rr][c] = val;
    xb[rr * 72 + pcmap(c)] = f2bf(val);
  }
  __syncthreads();

  const int lane = t & 63, w = t >> 6;
  const int r = lane & 15, q = lane >> 4;
  const int ntile = w & 1, mgrp = w >> 1;

  short8 hf[2];
#pragma unroll
  for (int s = 0; s < 2; ++s)
    hf[s] = *(const short8*)&xb[(ntile * 16 + r) * 72 + s * 32 + q * 8];

#pragma unroll
  for (int mi = 0; mi < 4; ++mi) {
    int mt = mgrp * 4 + mi;
    f32x4 a = {};
#pragma unroll
    for (int s = 0; s < 2; ++s) {
      short8 wf = *(const short8*)(W1p + (mt * 16 + r) * 64 + s * 32 + q * 8);
      a = __builtin_amdgcn_mfma_f32_16x16x32_bf16(wf, hf[s], a, 0, 0, 0);
    }
    int m0 = mt * 16 + q * 4;
    f32x4 v = a + *(const f32x4*)&b1[m0];
#pragma unroll
    for (int e = 0; e < 4; ++e)
      midb[(ntile * 16 + r) * 136 + pc128(m0 + e)] = f2bf(fmaxf(v[e], 0.f));
  }
  __syncthreads();

  short8 mf[4];
#pragma unroll
  for (int s = 0; s < 4; ++s)
    mf[s] = *(const short8*)&midb[(ntile * 16 + r) * 136 + s * 32 + q * 8];

  const int n = r0 + ntile * 16 + r;
#pragma unroll
  for (int mi = 0; mi < 2; ++mi) {
    int mt = mgrp * 2 + mi;
    f32x4 a = {};
#pragma unroll
    for (int s = 0; s < 4; ++s) {
      short8 wf = *(const short8*)(W2p + (mt * 16 + r) * 128 + s * 32 + q * 8);
      a = __builtin_amdgcn_mfma_f32_16x16x32_bf16(wf, mf[s], a, 0, 0, 0);
    }
    int m0 = mt * 16 + q * 4;
    f32x4 out = a + *(const f32x4*)&b2[m0] + *(const f32x4*)&rows[ntile * 16 + r][m0];
    *(f32x4*)&t4[(size_t)n * 64 + m0] = out;
    f32x4 s_ = out, q_ = out * out;
#pragma unroll
    for (int off = 1; off < 16; off <<= 1) {
#pragma unroll
      for (int e = 0; e < 4; ++e) {
        s_[e] += __shfl_xor(s_[e], off);
        q_[e] += __shfl_xor(q_[e], off);
      }
    }
    if (r == 0) {
#pragma unroll
      for (int e = 0; e < 4; ++e) {
        os[ntile][m0 + e] = s_[e];
        oss[ntile][m0 + e] = q_[e];
      }
    }
  }
  __syncthreads();
  if (t < 64) atomicAdd(&stats[t], os[0][t] + os[1][t]);
  else if (t < 128) {
    int c = t - 64;
    atomicAdd(&stats[64 + c], oss[0][c] + oss[1][c]);
  }
}

// ------------------------------------------- BN3 + LayerNorm + ReLU (fused)
__global__ __launch_bounds__(256) void bn3_ln_relu(const float* __restrict__ t4,
                                                   const float* __restrict__ s3,
                                                   const float* __restrict__ g3,
                                                   const float* __restrict__ b3,
                                                   const float* __restrict__ lg,
                                                   const float* __restrict__ lb,
                                                   float* __restrict__ H,
                                                   u16* __restrict__ hb) {
  int wv = threadIdx.x >> 6, lane = threadIdx.x & 63;
  int n = blockIdx.x * 4 + wv;
  float m3 = s3[lane] * (1.f / NN);
  float v3 = s3[64 + lane] * (1.f / NN) - m3 * m3;
  float x = (t4[n * 64 + lane] - m3) * rsqrtf(v3 + EPSV) * g3[lane] + b3[lane];
  float s = x, ss = x * x;
  for (int o = 32; o > 0; o >>= 1) {
    s += __shfl_xor(s, o, 64);
    ss += __shfl_xor(ss, o, 64);
  }
  float m = s * (1.f / 64), v = ss * (1.f / 64) - m * m;
  float y = (x - m) * rsqrtf(v + EPSV) * lg[lane] + lb[lane];
  y = fmaxf(y, 0.f);
  H[n * 64 + lane] = y;
  hb[n * 64 + pcmap(lane)] = f2bf(y);
}

// ------------------------------------------- final GEMM (64x21) + log_softmax
__global__ __launch_bounds__(256) void final_kernel(const float* __restrict__ H,
                                                    const float* __restrict__ Wout,
                                                    const float* __restrict__ bout,
                                                    float* __restrict__ out) {
  int w = threadIdx.x >> 6, lane = threadIdx.x & 63;
  int n = blockIdx.x * 4 + w;
  const float* hr = H + n * 64;
  float acc = (lane < COUT) ? bout[lane] : -INFINITY;
  if (lane < COUT) {
#pragma unroll 16
    for (int k = 0; k < 64; ++k) acc = fmaf(hr[k], Wout[k * COUT + lane], acc);
  }
  float mx = acc;
  for (int o = 32; o > 0; o >>= 1) mx = fmaxf(mx, __shfl_xor(mx, o, 64));
  float e = __expf(acc - mx);
  float se = e;
  for (int o = 32; o > 0; o >>= 1) se += __shfl_xor(se, o, 64);
  float lse = mx + logf(se);
  if (lane < COUT) out[n * COUT + lane] = acc - lse;
}

// ================================================================ launch
extern "C" void kernel_launch(void* const* d_in, const int* in_sizes, int n_in,
                              void* d_out, int out_size, void* d_ws, size_t ws_size,
                              hipStream_t stream) {
  const float* x    = (const float*)d_in[0];
  const int*   ei   = (const int*)d_in[1];
  const float* W_in = (const float*)d_in[2];
  const float* b_in = (const float*)d_in[3];
  const float* gcnW = (const float*)d_in[4];
  const float* gcnB = (const float*)d_in[5];
  const float* Wqkv = (const float*)d_in[6];
  const float* bqkv = (const float*)d_in[7];
  const float* Wo   = (const float*)d_in[8];
  const float* bo   = (const float*)d_in[9];
  const float* bn1g = (const float*)d_in[10];
  const float* bn1b = (const float*)d_in[11];
  const float* bn2g = (const float*)d_in[12];
  const float* bn2b = (const float*)d_in[13];
  const float* bn3g = (const float*)d_in[14];
  const float* bn3b = (const float*)d_in[15];
  const float* W1   = (const float*)d_in[16];
  const float* b1   = (const float*)d_in[17];
  const float* W2   = (const float*)d_in[18];
  const float* b2   = (const float*)d_in[19];
  const float* lng  = (const float*)d_in[20];
  const float* lnb  = (const float*)d_in[21];
  const float* Wout = (const float*)d_in[22];
  const float* bout = (const float*)d_in[23];

  const int* src = ei;
  const int* dst = ei + NE;

  const int NC = NN * C;
  float* ws = (float*)d_ws;
  float* h     = ws + 0 * NC;
  float* t0    = ws + 1 * NC;     // xw (gather input), then oproj output
  float* t1    = ws + 2 * NC;
  float* Opart = ws + 3 * NC;     // 4MB: 128qt x 2ks x 64 x 64
  float* t4    = ws + 5 * NC;
  u16* Qb  = (u16*)(ws + 6 * NC);
  u16* Kb  = Qb + NC;
  u16* Vtb = Kb + NC;
  u16* hbb = Vtb + NC;
  u16* Wqp = hbb + NC;            // NL x 192 x 64
  u16* Wop = Wqp + NL * 192 * 64; // NL x 64 x 64
  u16* Wgp = Wop + NL * 64 * 64;  // NL x 64 x 64
  u16* W1p = Wgp + NL * 64 * 64;  // NL x 128 x 64
  u16* W2p = W1p + NL * 128 * 64; // NL x 64 x 128
  float* dinv = (float*)(W2p + NL * 64 * 128);
  float* statsAll = dinv + NN;    // 12 x 128
  float* Lpart = statsAll + 1536; // 128qt x 2ks x 64
  int* degi   = (int*)(Lpart + 16384);
  int* rowptr = degi + NN;        // NN+1
  int* cursor = rowptr + NN + 8;
  int* esrc   = cursor + NN;      // NE
  float* ewt  = (float*)(esrc + NE);  // NE

  dim3 B(256);

  // ---- setup: CSR + dinv + weight prep (deterministic; recomputed per call)
  zero_setup<<<32, B, 0, stream>>>(statsAll, degi);
  deg_kernel<<<NE / 256, B, 0, stream>>>(dst, degi);
  prefix_kernel<<<1, B, 0, stream>>>(degi, rowptr, cursor);
  dinv_kernel<<<NN / 256, B, 0, stream>>>(degi, dinv);
  fill_kernel<<<NE / 256, B, 0, stream>>>(src, dst, dinv, cursor, esrc, ewt);
  prep_weights<<<576, B, 0, stream>>>(Wqkv, Wo, gcnW, W1, W2, Wqp, Wop, Wgp, W1p, W2p);

  gemm_in_kernel<<<NN * C / 256, B, 0, stream>>>(x, W_in, b_in, h, hbb);

  for (int l = 0; l < NL; ++l) {
    float* s1 = statsAll + l * 384;
    float* s2 = s1 + 128;
    float* s3 = s1 + 256;

    // ---- fused projection: gcn gemm + t1 init + QKV + Vt
    proj_mfma<<<NN / 16, 128, 0, stream>>>(hbb, h, Wqp + l * 192 * 64, Wgp + l * 4096,
                                           bqkv + l * 192, gcnB + l * C, dinv,
                                           Qb, Kb, Vtb, t0, t1);
    // ---- gather + fused stats1
    gcn_gather<<<NN / 8, B, 0, stream>>>(rowptr, esrc, ewt, t0, dinv, t1, s1);

    // ---- global attention branch + residual -> t0, fused stats2
    attn_mfma<<<256, 512, 0, stream>>>(Qb, Kb, Vtb, Opart, Lpart);
    oproj_mfma<<<NN / 32, B, 0, stream>>>(Opart, Lpart, Wop + l * 4096, bo + l * C, h, t0, s2);

    // ---- combine + MLP (MFMA) -> t4 + fused stats3, then BN3 + LN + ReLU -> h (+hb)
    mlp_mfma<<<NN / 32, B, 0, stream>>>(t1, t0, s1, s2, bn1g + l * C, bn1b + l * C,
                                        bn2g + l * C, bn2b + l * C,
                                        W1p + l * 8192, b1 + l * 2 * C,
                                        W2p + l * 8192, b2 + l * C, t4, s3);
    bn3_ln_relu<<<NN / 4, B, 0, stream>>>(t4, s3, bn3g + l * C, bn3b + l * C,
                                          lng + l * C, lnb + l * C, h, hbb);
  }

  final_kernel<<<NN / 4, B, 0, stream>>>(h, Wout, bout, (float*)d_out);
}

// Round 19
// 470.420 us; speedup vs baseline: 1.7026x; 1.1265x over previous
//
#include <hip/hip_runtime.h>
#include <math.h>

#define NN 8192
#define NE 131072
#define CIN 128
#define C 64
#define NL 4
#define COUT 21
#define EPSV 1e-5f
#define ALPHA 0.18033688011112043f  // 0.125 * log2(e)

typedef unsigned short u16;
typedef __attribute__((ext_vector_type(8))) short short8;
typedef __attribute__((ext_vector_type(4))) float f32x4;
typedef __attribute__((ext_vector_type(4))) unsigned int u32x4;
typedef __attribute__((ext_vector_type(2))) unsigned int u32x2;

__device__ __forceinline__ u16 f2bf(float x) {
  unsigned int u = __float_as_uint(x);
  u += 0x7FFF + ((u >> 16) & 1);
  return (u16)(u >> 16);
}

__device__ __forceinline__ unsigned cvtpk(float a, float b) {
  unsigned r;
  asm("v_cvt_pk_bf16_f32 %0, %1, %2" : "=v"(r) : "v"(a), "v"(b));
  return r;
}

__device__ __forceinline__ int pcmap(int c) {  // k-dim permutation (within 32), c<64
  return (c & 32) | (c & 3) | (((c >> 2) & 3) << 3) | (((c >> 4) & 1) << 2);
}

__device__ __forceinline__ int pc128(int c) {  // same, for c<128
  return (c & 96) | (c & 3) | (((c >> 2) & 3) << 3) | (((c >> 4) & 1) << 2);
}

// ---------------------------------------------------------------- setup
__global__ void zero_setup(float* __restrict__ stats, int* __restrict__ degi) {
  int i = blockIdx.x * 256 + threadIdx.x;
  if (i < 1536) stats[i] = 0.f;
  if (i < NN) degi[i] = 0;
}

__global__ void deg_kernel(const int* __restrict__ dst, int* __restrict__ degi) {
  int e = blockIdx.x * 256 + threadIdx.x;
  if (e < NE) atomicAdd(&degi[dst[e]], 1);
}

__global__ __launch_bounds__(256) void prefix_kernel(const int* __restrict__ degi,
                                                     int* __restrict__ rowptr,
                                                     int* __restrict__ cursor) {
  __shared__ int part[256];
  int t = threadIdx.x;
  int base = t * 32;
  int loc[32];
  int s = 0;
#pragma unroll
  for (int i = 0; i < 32; ++i) { loc[i] = s; s += degi[base + i]; }
  part[t] = s;
  __syncthreads();
  for (int off = 1; off < 256; off <<= 1) {
    int v = (t >= off) ? part[t - off] : 0;
    __syncthreads();
    part[t] += v;
    __syncthreads();
  }
  int chunkbase = (t == 0) ? 0 : part[t - 1];
#pragma unroll
  for (int i = 0; i < 32; ++i) {
    int v = chunkbase + loc[i];
    rowptr[base + i] = v;
    cursor[base + i] = v;
  }
  if (t == 255) rowptr[NN] = part[255];
}

__global__ void dinv_kernel(const int* __restrict__ degi, float* __restrict__ dinv) {
  int i = blockIdx.x * 256 + threadIdx.x;
  if (i < NN) dinv[i] = rsqrtf((float)degi[i] + 1.0f);
}

__global__ void fill_kernel(const int* __restrict__ src, const int* __restrict__ dst,
                            const float* __restrict__ dinv,
                            int* __restrict__ cursor, int* __restrict__ esrc,
                            float* __restrict__ ewt) {
  int e = blockIdx.x * 256 + threadIdx.x;
  if (e < NE) {
    int d = dst[e];
    int s = src[e];
    int pos = atomicAdd(&cursor[d], 1);
    esrc[pos] = s;
    ewt[pos] = dinv[s];
  }
}

// ------------------------------------- weight prep: bf16 + pc-permute k-dim
__global__ void prep_weights(const float* __restrict__ Wqkv, const float* __restrict__ Wo,
                             const float* __restrict__ Wg,
                             const float* __restrict__ W1, const float* __restrict__ W2,
                             u16* __restrict__ Wqp, u16* __restrict__ Wop,
                             u16* __restrict__ Wgp,
                             u16* __restrict__ W1p, u16* __restrict__ W2p) {
  int idx = blockIdx.x * 256 + threadIdx.x;   // 147456 total
  if (idx < NL * 192 * 64) {
    int l = idx / 12288, rem = idx % 12288;
    int j = rem >> 6, c = rem & 63;
    Wqp[l * 12288 + j * 64 + pcmap(c)] = f2bf(Wqkv[idx]);
  } else if (idx < NL * 192 * 64 + NL * 64 * 64) {
    int i2 = idx - NL * 192 * 64;
    int l = i2 >> 12, m = (i2 >> 6) & 63, k = i2 & 63;
    Wop[l * 4096 + m * 64 + pcmap(k)] = f2bf(Wo[i2]);
  } else if (idx < NL * 192 * 64 + 2 * NL * 64 * 64) {
    int i3 = idx - NL * 192 * 64 - NL * 64 * 64;
    int l = i3 >> 12, k = (i3 >> 6) & 63, c = i3 & 63;
    Wgp[l * 4096 + c * 64 + pcmap(k)] = f2bf(Wg[i3]);  // transpose: row=out ch
  } else if (idx < NL * 192 * 64 + 2 * NL * 64 * 64 + NL * 64 * 128) {
    int i4 = idx - (NL * 192 * 64 + 2 * NL * 64 * 64);  // W1: [L][64k][128m]
    int l = i4 >> 13, i3 = i4 & 8191;
    int k = i3 >> 7, m = i3 & 127;
    W1p[l * 8192 + m * 64 + pcmap(k)] = f2bf(W1[i4]);
  } else if (idx < NL * 192 * 64 + 2 * NL * 64 * 64 + 2 * NL * 64 * 128) {
    int i5 = idx - (NL * 192 * 64 + 2 * NL * 64 * 64 + NL * 64 * 128);  // W2: [L][128k][64m]
    int l = i5 >> 13, i3 = i5 & 8191;
    int k = i3 >> 6, m = i3 & 63;
    W2p[l * 8192 + m * 128 + pc128(k)] = f2bf(W2[i5]);
  }
}

// ------------------------------------------------------------- input GEMM
__global__ __launch_bounds__(256) void gemm_in_kernel(const float* __restrict__ X,
                                                      const float* __restrict__ W,
                                                      const float* __restrict__ b,
                                                      float* __restrict__ Y,
                                                      u16* __restrict__ hb) {
  int idx = blockIdx.x * 256 + threadIdx.x;
  int n = idx >> 6, c = idx & 63;
  const float* xr = X + n * CIN;
  float acc = b[c];
#pragma unroll 16
  for (int k = 0; k < CIN; ++k) acc = fmaf(xr[k], W[k * C + c], acc);
  Y[idx] = acc;
  hb[n * 64 + pcmap(c)] = f2bf(acc);
}

// ---------------- fused projection: GCN gemm + t1 init + QKV + V transpose
__global__ __launch_bounds__(128) void proj_mfma(const u16* __restrict__ hb,
                                                 const float* __restrict__ h,
                                                 const u16* __restrict__ Wqp,
                                                 const u16* __restrict__ Wgp,
                                                 const float* __restrict__ bq,
                                                 const float* __restrict__ gb,
                                                 const float* __restrict__ dinv,
                                                 u16* __restrict__ Qb,
                                                 u16* __restrict__ Kb,
                                                 u16* __restrict__ Vt,
                                                 float* __restrict__ xw,
                                                 float* __restrict__ t1) {
  __shared__ u16 ldsv[64 * 17];
  const int tid = threadIdx.x;
  const int lane = tid & 63, w = tid >> 6;
  const int r = lane & 15, q = lane >> 4;
  const int n0 = blockIdx.x * 16;
  const int n = n0 + r;

  short8 hf[2];
#pragma unroll
  for (int s = 0; s < 2; ++s)
    hf[s] = *(const short8*)(hb + (size_t)n * 64 + s * 32 + q * 8);

  if (w == 0) {
    float di = dinv[n];
#pragma unroll
    for (int jt = 0; jt < 4; ++jt) {
      f32x4 a = {};
#pragma unroll
      for (int s = 0; s < 2; ++s) {
        short8 wf = *(const short8*)(Wgp + (jt * 16 + r) * 64 + s * 32 + q * 8);
        a = __builtin_amdgcn_mfma_f32_16x16x32_bf16(wf, hf[s], a, 0, 0, 0);
      }
      int j0 = jt * 16 + q * 4;
      f32x4 hres = *(const f32x4*)&h[(size_t)n * 64 + j0];
      f32x4 gbv = *(const f32x4*)&gb[j0];
      *(f32x4*)&xw[(size_t)n * 64 + j0] = a;
      *(f32x4*)&t1[(size_t)n * 64 + j0] = a * di * di + gbv + hres;
    }
#pragma unroll
    for (int jt = 0; jt < 4; ++jt) {
      f32x4 a = {};
#pragma unroll
      for (int s = 0; s < 2; ++s) {
        short8 wf = *(const short8*)(Wqp + (jt * 16 + r) * 64 + s * 32 + q * 8);
        a = __builtin_amdgcn_mfma_f32_16x16x32_bf16(wf, hf[s], a, 0, 0, 0);
      }
      f32x4 v = (a + *(const f32x4*)&bq[jt * 16 + q * 4]) * ALPHA;
      int pb = ((jt & 2) << 4) | (q << 3) | ((jt & 1) << 2);
      *(u32x2*)(Qb + (size_t)n * 64 + pb) = u32x2{cvtpk(v[0], v[1]), cvtpk(v[2], v[3])};
    }
  } else {
#pragma unroll
    for (int jt = 0; jt < 4; ++jt) {
      f32x4 a = {};
#pragma unroll
      for (int s = 0; s < 2; ++s) {
        short8 wf = *(const short8*)(Wqp + (64 + jt * 16 + r) * 64 + s * 32 + q * 8);
        a = __builtin_amdgcn_mfma_f32_16x16x32_bf16(wf, hf[s], a, 0, 0, 0);
      }
      f32x4 v = a + *(const f32x4*)&bq[64 + jt * 16 + q * 4];
      int pb = ((jt & 2) << 4) | (q << 3) | ((jt & 1) << 2);
      *(u32x2*)(Kb + (size_t)n * 64 + pb) = u32x2{cvtpk(v[0], v[1]), cvtpk(v[2], v[3])};
    }
#pragma unroll
    for (int jt = 0; jt < 4; ++jt) {
      f32x4 a = {};
#pragma unroll
      for (int s = 0; s < 2; ++s) {
        short8 wf = *(const short8*)(Wqp + (128 + jt * 16 + r) * 64 + s * 32 + q * 8);
        a = __builtin_amdgcn_mfma_f32_16x16x32_bf16(wf, hf[s], a, 0, 0, 0);
      }
      f32x4 v = a + *(const f32x4*)&bq[128 + jt * 16 + q * 4];
      int j0 = jt * 16 + q * 4;
#pragma unroll
      for (int e = 0; e < 4; ++e) ldsv[(j0 + e) * 17 + r] = f2bf(v[e]);
    }
  }
  __syncthreads();

  const int d = tid >> 1, cp = tid & 1;
  const int grp = n0 & ~31, hh = (n0 >> 4) & 1;
#pragma unroll
  for (int ci = 0; ci < 2; ++ci) {
    int cc = cp * 2 + ci;
    u16 a0 = ldsv[d * 17 + cc * 4 + 0];
    u16 a1 = ldsv[d * 17 + cc * 4 + 1];
    u16 a2 = ldsv[d * 17 + cc * 4 + 2];
    u16 a3 = ldsv[d * 17 + cc * 4 + 3];
    *(u32x2*)(Vt + (size_t)d * NN + grp + cc * 8 + hh * 4) =
        u32x2{(unsigned)a0 | ((unsigned)a1 << 16), (unsigned)a2 | ((unsigned)a3 << 16)};
  }
}

// ------------------------------------------------------------ MFMA flash attention
// fused with GCN gather: grid 768 x 512 thr. Blocks 0..255: attn (round-14
// verbatim: 128 qt x 2 ks, 8 waves, 512 keys/wave). Blocks 256..767: gather
// (16 rows/block, 8 waves x 2 rows) — fills the idle wave slots on each CU.
__device__ __forceinline__ void loadK(short8 (&kf)[8], const u16* kb, int koff) {
#pragma unroll
  for (int jt = 0; jt < 4; ++jt)
#pragma unroll
    for (int s = 0; s < 2; ++s)
      kf[jt * 2 + s] = *(const short8*)(kb + koff + jt * 1024 + s * 32);
}

__device__ __forceinline__ void loadV(short8 (&vf)[8], const u16* vb, int voff) {
#pragma unroll
  for (int dt = 0; dt < 4; ++dt)
#pragma unroll
    for (int s = 0; s < 2; ++s)
      vf[dt * 2 + s] = *(const short8*)(vb + voff + dt * 16 * NN + s * 32);
}

__device__ __forceinline__ void computeTile(const short8 (&kf)[8], const short8 (&vf)[8],
                                            const short8 (&qf)[4][2],
                                            f32x4 (&o)[4][4], float (&ll)[4]) {
#pragma unroll
  for (int pair = 0; pair < 2; ++pair) {
    f32x4 st[2][4] = {};
#pragma unroll
    for (int s = 0; s < 2; ++s)
#pragma unroll
      for (int jp = 0; jp < 2; ++jp) {
        short8 kfrag = kf[(pair * 2 + jp) * 2 + s];
#pragma unroll
        for (int it = 0; it < 4; ++it)
          st[jp][it] = __builtin_amdgcn_mfma_f32_16x16x32_bf16(kfrag, qf[it][s], st[jp][it], 0, 0, 0);
      }
    short8 pf[4];
#pragma unroll
    for (int it = 0; it < 4; ++it) {
      float p[8];
#pragma unroll
      for (int jp = 0; jp < 2; ++jp)
#pragma unroll
        for (int r = 0; r < 4; ++r) p[jp * 4 + r] = exp2f(st[jp][it][r]);
      ll[it] += ((p[0] + p[1]) + (p[2] + p[3])) + ((p[4] + p[5]) + (p[6] + p[7]));
      u32x4 a;
      a[0] = cvtpk(p[0], p[1]); a[1] = cvtpk(p[2], p[3]);
      a[2] = cvtpk(p[4], p[5]); a[3] = cvtpk(p[6], p[7]);
      pf[it] = __builtin_bit_cast(short8, a);
    }
#pragma unroll
    for (int dt = 0; dt < 4; ++dt) {
      short8 vfrag = vf[dt * 2 + pair];
#pragma unroll
      for (int it = 0; it < 4; ++it)
        o[dt][it] = __builtin_amdgcn_mfma_f32_16x16x32_bf16(vfrag, pf[it], o[dt][it], 0, 0, 0);
    }
  }
}

__global__ __launch_bounds__(512, 2)
void attn_gather(const u16* __restrict__ Qb, const u16* __restrict__ Kb,
                 const u16* __restrict__ Vtb, float* __restrict__ Opart,
                 float* __restrict__ Lpart,
                 const int* __restrict__ rowptr, const int* __restrict__ esrc,
                 const float* __restrict__ ewt, const float* __restrict__ xw,
                 const float* __restrict__ dinv, float* __restrict__ t1,
                 float* __restrict__ stats) {
  __shared__ float fsm[2 * 64 * 68 + 2 * 64];
  const int tid = threadIdx.x;
  const int lane = tid & 63;
  const int w = tid >> 6;

  if (blockIdx.x >= 256) {
    // ================= gather branch: 16 rows/block =================
    const int bid2 = blockIdx.x - 256;
    float* gs = fsm;          // [8][64]
    float* gss = fsm + 512;   // [8][64]
    float s = 0.f, ss = 0.f;
#pragma unroll
    for (int rr = 0; rr < 2; ++rr) {
      int d = bid2 * 16 + w * 2 + rr;
      int beg = rowptr[d], end = rowptr[d + 1];
      float acc = 0.f;
      int i = beg;
      for (; i + 4 <= end; i += 4) {
        int s0 = esrc[i], s1 = esrc[i + 1], s2 = esrc[i + 2], s3 = esrc[i + 3];
        float w0 = ewt[i], w1 = ewt[i + 1], w2 = ewt[i + 2], w3 = ewt[i + 3];
        float x0 = xw[(size_t)s0 * 64 + lane];
        float x1 = xw[(size_t)s1 * 64 + lane];
        float x2 = xw[(size_t)s2 * 64 + lane];
        float x3 = xw[(size_t)s3 * 64 + lane];
        acc = fmaf(x0, w0, acc);
        acc = fmaf(x1, w1, acc);
        acc = fmaf(x2, w2, acc);
        acc = fmaf(x3, w3, acc);
      }
      for (; i < end; ++i) acc = fmaf(xw[(size_t)esrc[i] * 64 + lane], ewt[i], acc);
      size_t idx = (size_t)d * 64 + lane;
      float v = t1[idx] + acc * dinv[d];
      t1[idx] = v;
      s += v; ss += v * v;
    }
    gs[w * 64 + lane] = s; gss[w * 64 + lane] = ss;
    __syncthreads();
    if (tid < 64) {
      float a = 0.f;
#pragma unroll
      for (int j = 0; j < 8; ++j) a += gs[j * 64 + tid];
      atomicAdd(&stats[tid], a);
    } else if (tid < 128) {
      int c = tid - 64;
      float a = 0.f;
#pragma unroll
      for (int j = 0; j < 8; ++j) a += gss[j * 64 + c];
      atomicAdd(&stats[64 + c], a);
    }
    return;
  }

  // ================= attn branch (round-14 verbatim) =================
  const int qt = blockIdx.x >> 1, ks = blockIdx.x & 1;
  const int qbase = qt * 64;
  const int kv0 = ks * 4096 + w * 512;
  const int r = lane & 15, q = lane >> 4;

  short8 qf[4][2];
#pragma unroll
  for (int it = 0; it < 4; ++it)
#pragma unroll
    for (int s = 0; s < 2; ++s)
      qf[it][s] = *(const short8*)(Qb + (size_t)(qbase + it * 16 + r) * 64 + s * 32 + q * 8);

  f32x4 o[4][4] = {};
  float ll[4] = {0.f, 0.f, 0.f, 0.f};

  const u16* kb = Kb + (size_t)(kv0 + r) * 64 + q * 8;
  const u16* vb = Vtb + (size_t)r * NN + kv0 + q * 8;

  short8 kA[8], kB[8], vf[8];
  loadK(kA, kb, 0);
#pragma unroll 1
  for (int t = 0; t < 8; t += 2) {
    loadV(vf, vb, t * 64);
    loadK(kB, kb, (t + 1) * 4096);
    computeTile(kA, vf, qf, o, ll);
    loadV(vf, vb, (t + 1) * 64);
    if (t + 2 < 8) loadK(kA, kb, (t + 2) * 4096);
    computeTile(kB, vf, qf, o, ll);
  }

#pragma unroll
  for (int it = 0; it < 4; ++it) {
    ll[it] += __shfl_xor(ll[it], 16);
    ll[it] += __shfl_xor(ll[it], 32);
  }

  // ---- 8-wave merge: 2 LDS bufs, 4 rounds
  float* buf = fsm + (w & 1) * (64 * 68);
  float* lb = fsm + 2 * 64 * 68 + (w & 1) * 64;
  for (int rr = 0; rr < 4; ++rr) {
    if ((w >> 1) == rr) {
      if (rr == 0) {
#pragma unroll
        for (int dt = 0; dt < 4; ++dt)
#pragma unroll
          for (int it = 0; it < 4; ++it)
            *(f32x4*)&buf[(it * 16 + r) * 68 + dt * 16 + q * 4] = o[dt][it];
        if (lane < 16)
#pragma unroll
          for (int it = 0; it < 4; ++it) lb[it * 16 + lane] = ll[it];
      } else {
#pragma unroll
        for (int dt = 0; dt < 4; ++dt)
#pragma unroll
          for (int it = 0; it < 4; ++it) {
            float* p = &buf[(it * 16 + r) * 68 + dt * 16 + q * 4];
            *(f32x4*)p = *(const f32x4*)p + o[dt][it];
          }
        if (lane < 16)
#pragma unroll
          for (int it = 0; it < 4; ++it) lb[it * 16 + lane] += ll[it];
      }
    }
    __syncthreads();
  }

  int row = tid >> 3, d0 = (tid & 7) * 8;
  float* outp = Opart + (size_t)(qt * 2 + ks) * 4096 + row * 64 + d0;
  const float* b0 = fsm + row * 68 + d0;
  const float* b1 = b0 + 64 * 68;
#pragma unroll
  for (int j = 0; j < 8; ++j) outp[j] = b0[j] + b1[j];
  if (tid < 64)
    Lpart[(qt * 2 + ks) * 64 + tid] = fsm[2 * 64 * 68 + tid] + fsm[2 * 64 * 68 + 64 + tid];
}

// ------ O-projection MFMA (+2-way merge +1/l +bias +res) + fused BN stats2
__global__ __launch_bounds__(256) void oproj_mfma(const float* __restrict__ Opart,
                                                  const float* __restrict__ Lpart,
                                                  const u16* __restrict__ Wop,
                                                  const float* __restrict__ bo,
                                                  const float* __restrict__ res,
                                                  float* __restrict__ Y,
                                                  float* __restrict__ stats) {
  __shared__ u16 ldso[32 * 72];
  __shared__ float os[2][64], oss[2][64];
  const int tid = threadIdx.x;
  const int n0 = blockIdx.x * 32;
  const int qtile = n0 >> 6;

  {
    int row = tid >> 3, c0 = (tid & 7) * 8;
    int r64 = (n0 + row) & 63;
    float inv = 1.f / (Lpart[qtile * 128 + r64] + Lpart[qtile * 128 + 64 + r64]);
    const float* O0 = Opart + (size_t)(qtile * 2) * 4096 + r64 * 64;
    const float* O1 = O0 + 4096;
#pragma unroll
    for (int j8 = 0; j8 < 2; ++j8) {
      f32x4 a = *(const f32x4*)&O0[c0 + j8 * 4];
      f32x4 b = *(const f32x4*)&O1[c0 + j8 * 4];
      f32x4 vsum = (a + b) * inv;
#pragma unroll
      for (int e = 0; e < 4; ++e) ldso[row * 72 + pcmap(c0 + j8 * 4 + e)] = f2bf(vsum[e]);
    }
  }
  __syncthreads();

  const int lane = tid & 63, w = tid >> 6;
  const int r = lane & 15, q = lane >> 4;
  const int ntile = w & 1, mhalf = w >> 1;
  short8 hf[2];
#pragma unroll
  for (int s = 0; s < 2; ++s)
    hf[s] = *(const short8*)&ldso[(ntile * 16 + r) * 72 + s * 32 + q * 8];

  const int n = n0 + ntile * 16 + r;
#pragma unroll
  for (int mi = 0; mi < 2; ++mi) {
    int mt = mhalf * 2 + mi;
    f32x4 a = {};
#pragma unroll
    for (int s = 0; s < 2; ++s) {
      short8 wf = *(const short8*)(Wop + (mt * 16 + r) * 64 + s * 32 + q * 8);
      a = __builtin_amdgcn_mfma_f32_16x16x32_bf16(wf, hf[s], a, 0, 0, 0);
    }
    int m0 = mt * 16 + q * 4;
    f32x4 out = a + *(const f32x4*)&bo[m0] + *(const f32x4*)&res[(size_t)n * 64 + m0];
    *(f32x4*)&Y[(size_t)n * 64 + m0] = out;
    f32x4 s_ = out, q_ = out * out;
#pragma unroll
    for (int off = 1; off < 16; off <<= 1) {
#pragma unroll
      for (int e = 0; e < 4; ++e) {
        s_[e] += __shfl_xor(s_[e], off);
        q_[e] += __shfl_xor(q_[e], off);
      }
    }
    if (r == 0) {
#pragma unroll
      for (int e = 0; e < 4; ++e) {
        os[ntile][m0 + e] = s_[e];
        oss[ntile][m0 + e] = q_[e];
      }
    }
  }
  __syncthreads();
  if (tid < 64) atomicAdd(&stats[tid], os[0][tid] + os[1][tid]);
  else if (tid < 128) {
    int c = tid - 64;
    atomicAdd(&stats[64 + c], oss[0][c] + oss[1][c]);
  }
}

// -------- fused combine(bn1+bn2) + MLP via MFMA (+relu +residual) + BN stats3
__global__ __launch_bounds__(256) void mlp_mfma(const float* __restrict__ t1,
                                                const float* __restrict__ t0,
                                                const float* __restrict__ s1,
                                                const float* __restrict__ s2,
                                                const float* __restrict__ g1,
                                                const float* __restrict__ bb1,
                                                const float* __restrict__ g2,
                                                const float* __restrict__ bb2,
                                                const u16* __restrict__ W1p,
                                                const float* __restrict__ b1,
                                                const u16* __restrict__ W2p,
                                                const float* __restrict__ b2,
                                                float* __restrict__ t4,
                                                float* __restrict__ stats) {
  __shared__ float rows[32][68];
  __shared__ u16 xb[32 * 72];
  __shared__ u16 midb[32 * 136];
  __shared__ float os[2][64], oss[2][64];
  int t = threadIdx.x;
  int r0 = blockIdx.x * 32;

  for (int i = t; i < 2048; i += 256) {
    int rr = i >> 6, c = i & 63;
    int idx = (r0 + rr) * 64 + c;
    float m1 = s1[c] * (1.f / NN);
    float v1 = s1[64 + c] * (1.f / NN) - m1 * m1;
    float m2 = s2[c] * (1.f / NN);
    float v2 = s2[64 + c] * (1.f / NN) - m2 * m2;
    float val = (t1[idx] - m1) * rsqrtf(v1 + EPSV) * g1[c] + bb1[c] +
                (t0[idx] - m2) * rsqrtf(v2 + EPSV) * g2[c] + bb2[c];
    rows[rr][c] = val;
    xb[rr * 72 + pcmap(c)] = f2bf(val);
  }
  __syncthreads();

  const int lane = t & 63, w = t >> 6;
  const int r = lane & 15, q = lane >> 4;
  const int ntile = w & 1, mgrp = w >> 1;

  short8 hf[2];
#pragma unroll
  for (int s = 0; s < 2; ++s)
    hf[s] = *(const short8*)&xb[(ntile * 16 + r) * 72 + s * 32 + q * 8];

#pragma unroll
  for (int mi = 0; mi < 4; ++mi) {
    int mt = mgrp * 4 + mi;
    f32x4 a = {};
#pragma unroll
    for (int s = 0; s < 2; ++s) {
      short8 wf = *(const short8*)(W1p + (mt * 16 + r) * 64 + s * 32 + q * 8);
      a = __builtin_amdgcn_mfma_f32_16x16x32_bf16(wf, hf[s], a, 0, 0, 0);
    }
    int m0 = mt * 16 + q * 4;
    f32x4 v = a + *(const f32x4*)&b1[m0];
#pragma unroll
    for (int e = 0; e < 4; ++e)
      midb[(ntile * 16 + r) * 136 + pc128(m0 + e)] = f2bf(fmaxf(v[e], 0.f));
  }
  __syncthreads();

  short8 mf[4];
#pragma unroll
  for (int s = 0; s < 4; ++s)
    mf[s] = *(const short8*)&midb[(ntile * 16 + r) * 136 + s * 32 + q * 8];

  const int n = r0 + ntile * 16 + r;
#pragma unroll
  for (int mi = 0; mi < 2; ++mi) {
    int mt = mgrp * 2 + mi;
    f32x4 a = {};
#pragma unroll
    for (int s = 0; s < 4; ++s) {
      short8 wf = *(const short8*)(W2p + (mt * 16 + r) * 128 + s * 32 + q * 8);
      a = __builtin_amdgcn_mfma_f32_16x16x32_bf16(wf, mf[s], a, 0, 0, 0);
    }
    int m0 = mt * 16 + q * 4;
    f32x4 out = a + *(const f32x4*)&b2[m0] + *(const f32x4*)&rows[ntile * 16 + r][m0];
    *(f32x4*)&t4[(size_t)n * 64 + m0] = out;
    f32x4 s_ = out, q_ = out * out;
#pragma unroll
    for (int off = 1; off < 16; off <<= 1) {
#pragma unroll
      for (int e = 0; e < 4; ++e) {
        s_[e] += __shfl_xor(s_[e], off);
        q_[e] += __shfl_xor(q_[e], off);
      }
    }
    if (r == 0) {
#pragma unroll
      for (int e = 0; e < 4; ++e) {
        os[ntile][m0 + e] = s_[e];
        oss[ntile][m0 + e] = q_[e];
      }
    }
  }
  __syncthreads();
  if (t < 64) atomicAdd(&stats[t], os[0][t] + os[1][t]);
  else if (t < 128) {
    int c = t - 64;
    atomicAdd(&stats[64 + c], oss[0][c] + oss[1][c]);
  }
}

// ------------------------------------------- BN3 + LayerNorm + ReLU (fused)
__global__ __launch_bounds__(256) void bn3_ln_relu(const float* __restrict__ t4,
                                                   const float* __restrict__ s3,
                                                   const float* __restrict__ g3,
                                                   const float* __restrict__ b3,
                                                   const float* __restrict__ lg,
                                                   const float* __restrict__ lb,
                                                   float* __restrict__ H,
                                                   u16* __restrict__ hb) {
  int wv = threadIdx.x >> 6, lane = threadIdx.x & 63;
  int n = blockIdx.x * 4 + wv;
  float m3 = s3[lane] * (1.f / NN);
  float v3 = s3[64 + lane] * (1.f / NN) - m3 * m3;
  float x = (t4[n * 64 + lane] - m3) * rsqrtf(v3 + EPSV) * g3[lane] + b3[lane];
  float s = x, ss = x * x;
  for (int o = 32; o > 0; o >>= 1) {
    s += __shfl_xor(s, o, 64);
    ss += __shfl_xor(ss, o, 64);
  }
  float m = s * (1.f / 64), v = ss * (1.f / 64) - m * m;
  float y = (x - m) * rsqrtf(v + EPSV) * lg[lane] + lb[lane];
  y = fmaxf(y, 0.f);
  H[n * 64 + lane] = y;
  hb[n * 64 + pcmap(lane)] = f2bf(y);
}

// ------------------------------------------- final GEMM (64x21) + log_softmax
__global__ __launch_bounds__(256) void final_kernel(const float* __restrict__ H,
                                                    const float* __restrict__ Wout,
                                                    const float* __restrict__ bout,
                                                    float* __restrict__ out) {
  int w = threadIdx.x >> 6, lane = threadIdx.x & 63;
  int n = blockIdx.x * 4 + w;
  const float* hr = H + n * 64;
  float acc = (lane < COUT) ? bout[lane] : -INFINITY;
  if (lane < COUT) {
#pragma unroll 16
    for (int k = 0; k < 64; ++k) acc = fmaf(hr[k], Wout[k * COUT + lane], acc);
  }
  float mx = acc;
  for (int o = 32; o > 0; o >>= 1) mx = fmaxf(mx, __shfl_xor(mx, o, 64));
  float e = __expf(acc - mx);
  float se = e;
  for (int o = 32; o > 0; o >>= 1) se += __shfl_xor(se, o, 64);
  float lse = mx + logf(se);
  if (lane < COUT) out[n * COUT + lane] = acc - lse;
}

// ================================================================ launch
extern "C" void kernel_launch(void* const* d_in, const int* in_sizes, int n_in,
                              void* d_out, int out_size, void* d_ws, size_t ws_size,
                              hipStream_t stream) {
  const float* x    = (const float*)d_in[0];
  const int*   ei   = (const int*)d_in[1];
  const float* W_in = (const float*)d_in[2];
  const float* b_in = (const float*)d_in[3];
  const float* gcnW = (const float*)d_in[4];
  const float* gcnB = (const float*)d_in[5];
  const float* Wqkv = (const float*)d_in[6];
  const float* bqkv = (const float*)d_in[7];
  const float* Wo   = (const float*)d_in[8];
  const float* bo   = (const float*)d_in[9];
  const float* bn1g = (const float*)d_in[10];
  const float* bn1b = (const float*)d_in[11];
  const float* bn2g = (const float*)d_in[12];
  const float* bn2b = (const float*)d_in[13];
  const float* bn3g = (const float*)d_in[14];
  const float* bn3b = (const float*)d_in[15];
  const float* W1   = (const float*)d_in[16];
  const float* b1   = (const float*)d_in[17];
  const float* W2   = (const float*)d_in[18];
  const float* b2   = (const float*)d_in[19];
  const float* lng  = (const float*)d_in[20];
  const float* lnb  = (const float*)d_in[21];
  const float* Wout = (const float*)d_in[22];
  const float* bout = (const float*)d_in[23];

  const int* src = ei;
  const int* dst = ei + NE;

  const int NC = NN * C;
  float* ws = (float*)d_ws;
  float* h     = ws + 0 * NC;
  float* t0    = ws + 1 * NC;     // xw (gather input), then oproj output
  float* t1    = ws + 2 * NC;
  float* Opart = ws + 3 * NC;     // 4MB: 128qt x 2ks x 64 x 64
  float* t4    = ws + 5 * NC;
  u16* Qb  = (u16*)(ws + 6 * NC);
  u16* Kb  = Qb + NC;
  u16* Vtb = Kb + NC;
  u16* hbb = Vtb + NC;
  u16* Wqp = hbb + NC;            // NL x 192 x 64
  u16* Wop = Wqp + NL * 192 * 64; // NL x 64 x 64
  u16* Wgp = Wop + NL * 64 * 64;  // NL x 64 x 64
  u16* W1p = Wgp + NL * 64 * 64;  // NL x 128 x 64
  u16* W2p = W1p + NL * 128 * 64; // NL x 64 x 128
  float* dinv = (float*)(W2p + NL * 64 * 128);
  float* statsAll = dinv + NN;    // 12 x 128
  float* Lpart = statsAll + 1536; // 128qt x 2ks x 64
  int* degi   = (int*)(Lpart + 16384);
  int* rowptr = degi + NN;        // NN+1
  int* cursor = rowptr + NN + 8;
  int* esrc   = cursor + NN;      // NE
  float* ewt  = (float*)(esrc + NE);  // NE

  dim3 B(256);

  // ---- setup: CSR + dinv + weight prep (deterministic; recomputed per call)
  zero_setup<<<32, B, 0, stream>>>(statsAll, degi);
  deg_kernel<<<NE / 256, B, 0, stream>>>(dst, degi);
  prefix_kernel<<<1, B, 0, stream>>>(degi, rowptr, cursor);
  dinv_kernel<<<NN / 256, B, 0, stream>>>(degi, dinv);
  fill_kernel<<<NE / 256, B, 0, stream>>>(src, dst, dinv, cursor, esrc, ewt);
  prep_weights<<<576, B, 0, stream>>>(Wqkv, Wo, gcnW, W1, W2, Wqp, Wop, Wgp, W1p, W2p);

  gemm_in_kernel<<<NN * C / 256, B, 0, stream>>>(x, W_in, b_in, h, hbb);

  for (int l = 0; l < NL; ++l) {
    float* s1 = statsAll + l * 384;
    float* s2 = s1 + 128;
    float* s3 = s1 + 256;

    // ---- fused projection: gcn gemm + t1 init + QKV + Vt
    proj_mfma<<<NN / 16, 128, 0, stream>>>(hbb, h, Wqp + l * 192 * 64, Wgp + l * 4096,
                                           bqkv + l * 192, gcnB + l * C, dinv,
                                           Qb, Kb, Vtb, t0, t1);

    // ---- fused attention (blocks 0..255) + GCN gather + stats1 (blocks 256..767)
    attn_gather<<<768, 512, 0, stream>>>(Qb, Kb, Vtb, Opart, Lpart,
                                         rowptr, esrc, ewt, t0, dinv, t1, s1);
    // ---- O-projection + residual + stats2
    oproj_mfma<<<NN / 32, B, 0, stream>>>(Opart, Lpart, Wop + l * 4096, bo + l * C, h, t0, s2);

    // ---- combine + MLP (MFMA) -> t4 + fused stats3, then BN3 + LN + ReLU -> h (+hb)
    mlp_mfma<<<NN / 32, B, 0, stream>>>(t1, t0, s1, s2, bn1g + l * C, bn1b + l * C,
                                        bn2g + l * C, bn2b + l * C,
                                        W1p + l * 8192, b1 + l * 2 * C,
                                        W2p + l * 8192, b2 + l * C, t4, s3);
    bn3_ln_relu<<<NN / 4, B, 0, stream>>>(t4, s3, bn3g + l * C, bn3b + l * C,
                                          lng + l * C, lnb + l * C, h, hbb);
  }

  final_kernel<<<NN / 4, B, 0, stream>>>(h, Wout, bout, (float*)d_out);
}

// Round 20
// 464.393 us; speedup vs baseline: 1.7247x; 1.0130x over previous
//
#include <hip/hip_runtime.h>
#include <math.h>

#define NN 8192
#define NE 131072
#define CIN 128
#define C 64
#define NL 4
#define COUT 21
#define EPSV 1e-5f
#define ALPHA 0.18033688011112043f  // 0.125 * log2(e)

typedef unsigned short u16;
typedef __attribute__((ext_vector_type(8))) short short8;
typedef __attribute__((ext_vector_type(4))) float f32x4;
typedef __attribute__((ext_vector_type(4))) unsigned int u32x4;
typedef __attribute__((ext_vector_type(2))) unsigned int u32x2;

__device__ __forceinline__ u16 f2bf(float x) {
  unsigned int u = __float_as_uint(x);
  u += 0x7FFF + ((u >> 16) & 1);
  return (u16)(u >> 16);
}

__device__ __forceinline__ unsigned cvtpk(float a, float b) {
  unsigned r;
  asm("v_cvt_pk_bf16_f32 %0, %1, %2" : "=v"(r) : "v"(a), "v"(b));
  return r;
}

__device__ __forceinline__ int pcmap(int c) {  // k-dim permutation (within 32), c<64
  return (c & 32) | (c & 3) | (((c >> 2) & 3) << 3) | (((c >> 4) & 1) << 2);
}

__device__ __forceinline__ int pc128(int c) {  // same, for c<128
  return (c & 96) | (c & 3) | (((c >> 2) & 3) << 3) | (((c >> 4) & 1) << 2);
}

// ---------------------------------------------------------------- setup
__global__ void zero_setup(float* __restrict__ stats, int* __restrict__ degi) {
  int i = blockIdx.x * 256 + threadIdx.x;
  if (i < 1536) stats[i] = 0.f;
  if (i < NN) degi[i] = 0;
}

__global__ void deg_kernel(const int* __restrict__ dst, int* __restrict__ degi) {
  int e = blockIdx.x * 256 + threadIdx.x;
  if (e < NE) atomicAdd(&degi[dst[e]], 1);
}

// prefix sum + cursor init + dinv (fused)
__global__ __launch_bounds__(256) void prefix_kernel(const int* __restrict__ degi,
                                                     int* __restrict__ rowptr,
                                                     int* __restrict__ cursor,
                                                     float* __restrict__ dinv) {
  __shared__ int part[256];
  int t = threadIdx.x;
  int base = t * 32;
  int loc[32];
  int s = 0;
#pragma unroll
  for (int i = 0; i < 32; ++i) { loc[i] = s; s += degi[base + i]; }
  part[t] = s;
  __syncthreads();
  for (int off = 1; off < 256; off <<= 1) {
    int v = (t >= off) ? part[t - off] : 0;
    __syncthreads();
    part[t] += v;
    __syncthreads();
  }
  int chunkbase = (t == 0) ? 0 : part[t - 1];
#pragma unroll
  for (int i = 0; i < 32; ++i) {
    int v = chunkbase + loc[i];
    rowptr[base + i] = v;
    cursor[base + i] = v;
    dinv[base + i] = rsqrtf((float)degi[base + i] + 1.0f);
  }
  if (t == 255) rowptr[NN] = part[255];
}

__global__ void fill_kernel(const int* __restrict__ src, const int* __restrict__ dst,
                            const float* __restrict__ dinv,
                            int* __restrict__ cursor, int* __restrict__ esrc,
                            float* __restrict__ ewt) {
  int e = blockIdx.x * 256 + threadIdx.x;
  if (e < NE) {
    int d = dst[e];
    int s = src[e];
    int pos = atomicAdd(&cursor[d], 1);
    esrc[pos] = s;
    ewt[pos] = dinv[s];
  }
}

// ------------------------------------- weight prep: bf16 + pc-permute k-dim
__global__ void prep_weights(const float* __restrict__ Wqkv, const float* __restrict__ Wo,
                             const float* __restrict__ Wg,
                             const float* __restrict__ W1, const float* __restrict__ W2,
                             u16* __restrict__ Wqp, u16* __restrict__ Wop,
                             u16* __restrict__ Wgp,
                             u16* __restrict__ W1p, u16* __restrict__ W2p) {
  int idx = blockIdx.x * 256 + threadIdx.x;   // 147456 total
  if (idx < NL * 192 * 64) {
    int l = idx / 12288, rem = idx % 12288;
    int j = rem >> 6, c = rem & 63;
    Wqp[l * 12288 + j * 64 + pcmap(c)] = f2bf(Wqkv[idx]);
  } else if (idx < NL * 192 * 64 + NL * 64 * 64) {
    int i2 = idx - NL * 192 * 64;
    int l = i2 >> 12, m = (i2 >> 6) & 63, k = i2 & 63;
    Wop[l * 4096 + m * 64 + pcmap(k)] = f2bf(Wo[i2]);
  } else if (idx < NL * 192 * 64 + 2 * NL * 64 * 64) {
    int i3 = idx - NL * 192 * 64 - NL * 64 * 64;
    int l = i3 >> 12, k = (i3 >> 6) & 63, c = i3 & 63;
    Wgp[l * 4096 + c * 64 + pcmap(k)] = f2bf(Wg[i3]);  // transpose: row=out ch
  } else if (idx < NL * 192 * 64 + 2 * NL * 64 * 64 + NL * 64 * 128) {
    int i4 = idx - (NL * 192 * 64 + 2 * NL * 64 * 64);  // W1: [L][64k][128m]
    int l = i4 >> 13, i3 = i4 & 8191;
    int k = i3 >> 7, m = i3 & 127;
    W1p[l * 8192 + m * 64 + pcmap(k)] = f2bf(W1[i4]);
  } else if (idx < NL * 192 * 64 + 2 * NL * 64 * 64 + 2 * NL * 64 * 128) {
    int i5 = idx - (NL * 192 * 64 + 2 * NL * 64 * 64 + NL * 64 * 128);  // W2: [L][128k][64m]
    int l = i5 >> 13, i3 = i5 & 8191;
    int k = i3 >> 6, m = i3 & 63;
    W2p[l * 8192 + m * 128 + pc128(k)] = f2bf(W2[i5]);
  }
}

// ------------------------------------------------------------- input GEMM
__global__ __launch_bounds__(256) void gemm_in_kernel(const float* __restrict__ X,
                                                      const float* __restrict__ W,
                                                      const float* __restrict__ b,
                                                      float* __restrict__ Y,
                                                      u16* __restrict__ hb) {
  int idx = blockIdx.x * 256 + threadIdx.x;
  int n = idx >> 6, c = idx & 63;
  const float* xr = X + n * CIN;
  float acc = b[c];
#pragma unroll 16
  for (int k = 0; k < CIN; ++k) acc = fmaf(xr[k], W[k * C + c], acc);
  Y[idx] = acc;
  hb[n * 64 + pcmap(c)] = f2bf(acc);
}

// -------- fused [BN3+LN+ReLU of prev layer] + GCN gemm + t1 init + QKV + Vt
// grid 512 x 128 thr. Block = 16 rows. Phase 0: compute h rows (or stage for
// l==0) into LDS; then w0: gcn + Q, w1: K + V->LDS; then Vt store.
__global__ __launch_bounds__(128) void proj_mfma(const u16* __restrict__ hbin,
                                                 float* __restrict__ h,
                                                 const u16* __restrict__ Wqp,
                                                 const u16* __restrict__ Wgp,
                                                 const float* __restrict__ bq,
                                                 const float* __restrict__ gb,
                                                 const float* __restrict__ dinv,
                                                 u16* __restrict__ Qb,
                                                 u16* __restrict__ Kb,
                                                 u16* __restrict__ Vt,
                                                 float* __restrict__ xw,
                                                 float* __restrict__ t1,
                                                 const float* __restrict__ t4,
                                                 const float* __restrict__ s3g,
                                                 const float* __restrict__ g3,
                                                 const float* __restrict__ b3,
                                                 const float* __restrict__ lg,
                                                 const float* __restrict__ lb,
                                                 int isL0) {
  __shared__ float rowsF[16][68];
  __shared__ u16 xbL[16 * 72];
  __shared__ u16 ldsv[64 * 17];
  const int tid = threadIdx.x;
  const int lane = tid & 63, w = tid >> 6;
  const int r = lane & 15, q = lane >> 4;
  const int n0 = blockIdx.x * 16;
  const int n = n0 + r;

  // ---- Phase 0: produce h rows n0..n0+15 in LDS (+global for l>0)
  {
    int rloc = tid >> 3, cg = tid & 7;
    int nrow = n0 + rloc;
    if (isL0) {
#pragma unroll
      for (int e = 0; e < 8; ++e) {
        int c = cg * 8 + e;
        rowsF[rloc][c] = h[(size_t)nrow * 64 + c];
        xbL[rloc * 72 + c] = hbin[(size_t)nrow * 64 + c];
      }
    } else {
      float xv[8];
      float s = 0.f, ss = 0.f;
#pragma unroll
      for (int e = 0; e < 8; ++e) {
        int c = cg * 8 + e;
        float m3 = s3g[c] * (1.f / NN);
        float v3 = s3g[64 + c] * (1.f / NN) - m3 * m3;
        float x = (t4[(size_t)nrow * 64 + c] - m3) * rsqrtf(v3 + EPSV) * g3[c] + b3[c];
        xv[e] = x;
        s += x; ss += x * x;
      }
      s += __shfl_xor(s, 1); ss += __shfl_xor(ss, 1);
      s += __shfl_xor(s, 2); ss += __shfl_xor(ss, 2);
      s += __shfl_xor(s, 4); ss += __shfl_xor(ss, 4);
      float m = s * (1.f / 64), v = ss * (1.f / 64) - m * m;
      float rs = rsqrtf(v + EPSV);
#pragma unroll
      for (int e = 0; e < 8; ++e) {
        int c = cg * 8 + e;
        float y = (xv[e] - m) * rs * lg[c] + lb[c];
        y = fmaxf(y, 0.f);
        h[(size_t)nrow * 64 + c] = y;
        rowsF[rloc][c] = y;
        xbL[rloc * 72 + pcmap(c)] = f2bf(y);
      }
    }
  }
  __syncthreads();

  short8 hf[2];
#pragma unroll
  for (int s = 0; s < 2; ++s)
    hf[s] = *(const short8*)&xbL[r * 72 + s * 32 + q * 8];

  if (w == 0) {
    float di = dinv[n];
#pragma unroll
    for (int jt = 0; jt < 4; ++jt) {
      f32x4 a = {};
#pragma unroll
      for (int s = 0; s < 2; ++s) {
        short8 wf = *(const short8*)(Wgp + (jt * 16 + r) * 64 + s * 32 + q * 8);
        a = __builtin_amdgcn_mfma_f32_16x16x32_bf16(wf, hf[s], a, 0, 0, 0);
      }
      int j0 = jt * 16 + q * 4;
      f32x4 hres = *(const f32x4*)&rowsF[r][j0];
      f32x4 gbv = *(const f32x4*)&gb[j0];
      *(f32x4*)&xw[(size_t)n * 64 + j0] = a;
      *(f32x4*)&t1[(size_t)n * 64 + j0] = a * di * di + gbv + hres;
    }
#pragma unroll
    for (int jt = 0; jt < 4; ++jt) {
      f32x4 a = {};
#pragma unroll
      for (int s = 0; s < 2; ++s) {
        short8 wf = *(const short8*)(Wqp + (jt * 16 + r) * 64 + s * 32 + q * 8);
        a = __builtin_amdgcn_mfma_f32_16x16x32_bf16(wf, hf[s], a, 0, 0, 0);
      }
      f32x4 v = (a + *(const f32x4*)&bq[jt * 16 + q * 4]) * ALPHA;
      int pb = ((jt & 2) << 4) | (q << 3) | ((jt & 1) << 2);
      *(u32x2*)(Qb + (size_t)n * 64 + pb) = u32x2{cvtpk(v[0], v[1]), cvtpk(v[2], v[3])};
    }
  } else {
#pragma unroll
    for (int jt = 0; jt < 4; ++jt) {
      f32x4 a = {};
#pragma unroll
      for (int s = 0; s < 2; ++s) {
        short8 wf = *(const short8*)(Wqp + (64 + jt * 16 + r) * 64 + s * 32 + q * 8);
        a = __builtin_amdgcn_mfma_f32_16x16x32_bf16(wf, hf[s], a, 0, 0, 0);
      }
      f32x4 v = a + *(const f32x4*)&bq[64 + jt * 16 + q * 4];
      int pb = ((jt & 2) << 4) | (q << 3) | ((jt & 1) << 2);
      *(u32x2*)(Kb + (size_t)n * 64 + pb) = u32x2{cvtpk(v[0], v[1]), cvtpk(v[2], v[3])};
    }
#pragma unroll
    for (int jt = 0; jt < 4; ++jt) {
      f32x4 a = {};
#pragma unroll
      for (int s = 0; s < 2; ++s) {
        short8 wf = *(const short8*)(Wqp + (128 + jt * 16 + r) * 64 + s * 32 + q * 8);
        a = __builtin_amdgcn_mfma_f32_16x16x32_bf16(wf, hf[s], a, 0, 0, 0);
      }
      f32x4 v = a + *(const f32x4*)&bq[128 + jt * 16 + q * 4];
      int j0 = jt * 16 + q * 4;
#pragma unroll
      for (int e = 0; e < 4; ++e) ldsv[(j0 + e) * 17 + r] = f2bf(v[e]);
    }
  }
  __syncthreads();

  const int d = tid >> 1, cp = tid & 1;
  const int grp = n0 & ~31, hh = (n0 >> 4) & 1;
#pragma unroll
  for (int ci = 0; ci < 2; ++ci) {
    int cc = cp * 2 + ci;
    u16 a0 = ldsv[d * 17 + cc * 4 + 0];
    u16 a1 = ldsv[d * 17 + cc * 4 + 1];
    u16 a2 = ldsv[d * 17 + cc * 4 + 2];
    u16 a3 = ldsv[d * 17 + cc * 4 + 3];
    *(u32x2*)(Vt + (size_t)d * NN + grp + cc * 8 + hh * 4) =
        u32x2{(unsigned)a0 | ((unsigned)a1 << 16), (unsigned)a2 | ((unsigned)a3 << 16)};
  }
}

// ------------------------------------------------------------ MFMA flash attention
// fused with GCN gather: grid 768 x 512 thr. Blocks 0..255: attn. 256..767: gather.
__device__ __forceinline__ void loadK(short8 (&kf)[8], const u16* kb, int koff) {
#pragma unroll
  for (int jt = 0; jt < 4; ++jt)
#pragma unroll
    for (int s = 0; s < 2; ++s)
      kf[jt * 2 + s] = *(const short8*)(kb + koff + jt * 1024 + s * 32);
}

__device__ __forceinline__ void loadV(short8 (&vf)[8], const u16* vb, int voff) {
#pragma unroll
  for (int dt = 0; dt < 4; ++dt)
#pragma unroll
    for (int s = 0; s < 2; ++s)
      vf[dt * 2 + s] = *(const short8*)(vb + voff + dt * 16 * NN + s * 32);
}

__device__ __forceinline__ void computeTile(const short8 (&kf)[8], const short8 (&vf)[8],
                                            const short8 (&qf)[4][2],
                                            f32x4 (&o)[4][4], float (&ll)[4]) {
#pragma unroll
  for (int pair = 0; pair < 2; ++pair) {
    f32x4 st[2][4] = {};
#pragma unroll
    for (int s = 0; s < 2; ++s)
#pragma unroll
      for (int jp = 0; jp < 2; ++jp) {
        short8 kfrag = kf[(pair * 2 + jp) * 2 + s];
#pragma unroll
        for (int it = 0; it < 4; ++it)
          st[jp][it] = __builtin_amdgcn_mfma_f32_16x16x32_bf16(kfrag, qf[it][s], st[jp][it], 0, 0, 0);
      }
    short8 pf[4];
#pragma unroll
    for (int it = 0; it < 4; ++it) {
      float p[8];
#pragma unroll
      for (int jp = 0; jp < 2; ++jp)
#pragma unroll
        for (int r = 0; r < 4; ++r) p[jp * 4 + r] = exp2f(st[jp][it][r]);
      ll[it] += ((p[0] + p[1]) + (p[2] + p[3])) + ((p[4] + p[5]) + (p[6] + p[7]));
      u32x4 a;
      a[0] = cvtpk(p[0], p[1]); a[1] = cvtpk(p[2], p[3]);
      a[2] = cvtpk(p[4], p[5]); a[3] = cvtpk(p[6], p[7]);
      pf[it] = __builtin_bit_cast(short8, a);
    }
#pragma unroll
    for (int dt = 0; dt < 4; ++dt) {
      short8 vfrag = vf[dt * 2 + pair];
#pragma unroll
      for (int it = 0; it < 4; ++it)
        o[dt][it] = __builtin_amdgcn_mfma_f32_16x16x32_bf16(vfrag, pf[it], o[dt][it], 0, 0, 0);
    }
  }
}

__global__ __launch_bounds__(512, 2)
void attn_gather(const u16* __restrict__ Qb, const u16* __restrict__ Kb,
                 const u16* __restrict__ Vtb, float* __restrict__ Opart,
                 float* __restrict__ Lpart,
                 const int* __restrict__ rowptr, const int* __restrict__ esrc,
                 const float* __restrict__ ewt, const float* __restrict__ xw,
                 const float* __restrict__ dinv, float* __restrict__ t1,
                 float* __restrict__ stats) {
  __shared__ float fsm[2 * 64 * 68 + 2 * 64];
  const int tid = threadIdx.x;
  const int lane = tid & 63;
  const int w = tid >> 6;

  if (blockIdx.x >= 256) {
    // ================= gather branch: 16 rows/block =================
    const int bid2 = blockIdx.x - 256;
    float* gs = fsm;          // [8][64]
    float* gss = fsm + 512;   // [8][64]
    float s = 0.f, ss = 0.f;
#pragma unroll
    for (int rr = 0; rr < 2; ++rr) {
      int d = bid2 * 16 + w * 2 + rr;
      int beg = rowptr[d], end = rowptr[d + 1];
      float acc = 0.f;
      int i = beg;
      for (; i + 4 <= end; i += 4) {
        int s0 = esrc[i], s1 = esrc[i + 1], s2 = esrc[i + 2], s3 = esrc[i + 3];
        float w0 = ewt[i], w1 = ewt[i + 1], w2 = ewt[i + 2], w3 = ewt[i + 3];
        float x0 = xw[(size_t)s0 * 64 + lane];
        float x1 = xw[(size_t)s1 * 64 + lane];
        float x2 = xw[(size_t)s2 * 64 + lane];
        float x3 = xw[(size_t)s3 * 64 + lane];
        acc = fmaf(x0, w0, acc);
        acc = fmaf(x1, w1, acc);
        acc = fmaf(x2, w2, acc);
        acc = fmaf(x3, w3, acc);
      }
      for (; i < end; ++i) acc = fmaf(xw[(size_t)esrc[i] * 64 + lane], ewt[i], acc);
      size_t idx = (size_t)d * 64 + lane;
      float v = t1[idx] + acc * dinv[d];
      t1[idx] = v;
      s += v; ss += v * v;
    }
    gs[w * 64 + lane] = s; gss[w * 64 + lane] = ss;
    __syncthreads();
    if (tid < 64) {
      float a = 0.f;
#pragma unroll
      for (int j = 0; j < 8; ++j) a += gs[j * 64 + tid];
      atomicAdd(&stats[tid], a);
    } else if (tid < 128) {
      int c = tid - 64;
      float a = 0.f;
#pragma unroll
      for (int j = 0; j < 8; ++j) a += gss[j * 64 + c];
      atomicAdd(&stats[64 + c], a);
    }
    return;
  }

  // ================= attn branch =================
  const int qt = blockIdx.x >> 1, ks = blockIdx.x & 1;
  const int qbase = qt * 64;
  const int kv0 = ks * 4096 + w * 512;
  const int r = lane & 15, q = lane >> 4;

  short8 qf[4][2];
#pragma unroll
  for (int it = 0; it < 4; ++it)
#pragma unroll
    for (int s = 0; s < 2; ++s)
      qf[it][s] = *(const short8*)(Qb + (size_t)(qbase + it * 16 + r) * 64 + s * 32 + q * 8);

  f32x4 o[4][4] = {};
  float ll[4] = {0.f, 0.f, 0.f, 0.f};

  const u16* kb = Kb + (size_t)(kv0 + r) * 64 + q * 8;
  const u16* vb = Vtb + (size_t)r * NN + kv0 + q * 8;

  short8 kA[8], kB[8], vf[8];
  loadK(kA, kb, 0);
#pragma unroll 1
  for (int t = 0; t < 8; t += 2) {
    loadV(vf, vb, t * 64);
    loadK(kB, kb, (t + 1) * 4096);
    computeTile(kA, vf, qf, o, ll);
    loadV(vf, vb, (t + 1) * 64);
    if (t + 2 < 8) loadK(kA, kb, (t + 2) * 4096);
    computeTile(kB, vf, qf, o, ll);
  }

#pragma unroll
  for (int it = 0; it < 4; ++it) {
    ll[it] += __shfl_xor(ll[it], 16);
    ll[it] += __shfl_xor(ll[it], 32);
  }

  // ---- 8-wave merge: 2 LDS bufs, 4 rounds
  float* buf = fsm + (w & 1) * (64 * 68);
  float* lb = fsm + 2 * 64 * 68 + (w & 1) * 64;
  for (int rr = 0; rr < 4; ++rr) {
    if ((w >> 1) == rr) {
      if (rr == 0) {
#pragma unroll
        for (int dt = 0; dt < 4; ++dt)
#pragma unroll
          for (int it = 0; it < 4; ++it)
            *(f32x4*)&buf[(it * 16 + r) * 68 + dt * 16 + q * 4] = o[dt][it];
        if (lane < 16)
#pragma unroll
          for (int it = 0; it < 4; ++it) lb[it * 16 + lane] = ll[it];
      } else {
#pragma unroll
        for (int dt = 0; dt < 4; ++dt)
#pragma unroll
          for (int it = 0; it < 4; ++it) {
            float* p = &buf[(it * 16 + r) * 68 + dt * 16 + q * 4];
            *(f32x4*)p = *(const f32x4*)p + o[dt][it];
          }
        if (lane < 16)
#pragma unroll
          for (int it = 0; it < 4; ++it) lb[it * 16 + lane] += ll[it];
      }
    }
    __syncthreads();
  }

  int row = tid >> 3, d0 = (tid & 7) * 8;
  float* outp = Opart + (size_t)(qt * 2 + ks) * 4096 + row * 64 + d0;
  const float* b0 = fsm + row * 68 + d0;
  const float* b1 = b0 + 64 * 68;
#pragma unroll
  for (int j = 0; j < 8; ++j) outp[j] = b0[j] + b1[j];
  if (tid < 64)
    Lpart[(qt * 2 + ks) * 64 + tid] = fsm[2 * 64 * 68 + tid] + fsm[2 * 64 * 68 + 64 + tid];
}

// ------ O-projection MFMA (+2-way merge +1/l +bias +res) + fused BN stats2
__global__ __launch_bounds__(256) void oproj_mfma(const float* __restrict__ Opart,
                                                  const float* __restrict__ Lpart,
                                                  const u16* __restrict__ Wop,
                                                  const float* __restrict__ bo,
                                                  const float* __restrict__ res,
                                                  float* __restrict__ Y,
                                                  float* __restrict__ stats) {
  __shared__ u16 ldso[32 * 72];
  __shared__ float os[2][64], oss[2][64];
  const int tid = threadIdx.x;
  const int n0 = blockIdx.x * 32;
  const int qtile = n0 >> 6;

  {
    int row = tid >> 3, c0 = (tid & 7) * 8;
    int r64 = (n0 + row) & 63;
    float inv = 1.f / (Lpart[qtile * 128 + r64] + Lpart[qtile * 128 + 64 + r64]);
    const float* O0 = Opart + (size_t)(qtile * 2) * 4096 + r64 * 64;
    const float* O1 = O0 + 4096;
#pragma unroll
    for (int j8 = 0; j8 < 2; ++j8) {
      f32x4 a = *(const f32x4*)&O0[c0 + j8 * 4];
      f32x4 b = *(const f32x4*)&O1[c0 + j8 * 4];
      f32x4 vsum = (a + b) * inv;
#pragma unroll
      for (int e = 0; e < 4; ++e) ldso[row * 72 + pcmap(c0 + j8 * 4 + e)] = f2bf(vsum[e]);
    }
  }
  __syncthreads();

  const int lane = tid & 63, w = tid >> 6;
  const int r = lane & 15, q = lane >> 4;
  const int ntile = w & 1, mhalf = w >> 1;
  short8 hf[2];
#pragma unroll
  for (int s = 0; s < 2; ++s)
    hf[s] = *(const short8*)&ldso[(ntile * 16 + r) * 72 + s * 32 + q * 8];

  const int n = n0 + ntile * 16 + r;
#pragma unroll
  for (int mi = 0; mi < 2; ++mi) {
    int mt = mhalf * 2 + mi;
    f32x4 a = {};
#pragma unroll
    for (int s = 0; s < 2; ++s) {
      short8 wf = *(const short8*)(Wop + (mt * 16 + r) * 64 + s * 32 + q * 8);
      a = __builtin_amdgcn_mfma_f32_16x16x32_bf16(wf, hf[s], a, 0, 0, 0);
    }
    int m0 = mt * 16 + q * 4;
    f32x4 out = a + *(const f32x4*)&bo[m0] + *(const f32x4*)&res[(size_t)n * 64 + m0];
    *(f32x4*)&Y[(size_t)n * 64 + m0] = out;
    f32x4 s_ = out, q_ = out * out;
#pragma unroll
    for (int off = 1; off < 16; off <<= 1) {
#pragma unroll
      for (int e = 0; e < 4; ++e) {
        s_[e] += __shfl_xor(s_[e], off);
        q_[e] += __shfl_xor(q_[e], off);
      }
    }
    if (r == 0) {
#pragma unroll
      for (int e = 0; e < 4; ++e) {
        os[ntile][m0 + e] = s_[e];
        oss[ntile][m0 + e] = q_[e];
      }
    }
  }
  __syncthreads();
  if (tid < 64) atomicAdd(&stats[tid], os[0][tid] + os[1][tid]);
  else if (tid < 128) {
    int c = tid - 64;
    atomicAdd(&stats[64 + c], oss[0][c] + oss[1][c]);
  }
}

// -------- fused combine(bn1+bn2) + MLP via MFMA (+relu +residual) + BN stats3
__global__ __launch_bounds__(256) void mlp_mfma(const float* __restrict__ t1,
                                                const float* __restrict__ t0,
                                                const float* __restrict__ s1,
                                                const float* __restrict__ s2,
                                                const float* __restrict__ g1,
                                                const float* __restrict__ bb1,
                                                const float* __restrict__ g2,
                                                const float* __restrict__ bb2,
                                                const u16* __restrict__ W1p,
                                                const float* __restrict__ b1,
                                                const u16* __restrict__ W2p,
                                                const float* __restrict__ b2,
                                                float* __restrict__ t4,
                                                float* __restrict__ stats) {
  __shared__ float rows[32][68];
  __shared__ u16 xb[32 * 72];
  __shared__ u16 midb[32 * 136];
  __shared__ float os[2][64], oss[2][64];
  int t = threadIdx.x;
  int r0 = blockIdx.x * 32;

  for (int i = t; i < 2048; i += 256) {
    int rr = i >> 6, c = i & 63;
    int idx = (r0 + rr) * 64 + c;
    float m1 = s1[c] * (1.f / NN);
    float v1 = s1[64 + c] * (1.f / NN) - m1 * m1;
    float m2 = s2[c] * (1.f / NN);
    float v2 = s2[64 + c] * (1.f / NN) - m2 * m2;
    float val = (t1[idx] - m1) * rsqrtf(v1 + EPSV) * g1[c] + bb1[c] +
                (t0[idx] - m2) * rsqrtf(v2 + EPSV) * g2[c] + bb2[c];
    rows[rr][c] = val;
    xb[rr * 72 + pcmap(c)] = f2bf(val);
  }
  __syncthreads();

  const int lane = t & 63, w = t >> 6;
  const int r = lane & 15, q = lane >> 4;
  const int ntile = w & 1, mgrp = w >> 1;

  short8 hf[2];
#pragma unroll
  for (int s = 0; s < 2; ++s)
    hf[s] = *(const short8*)&xb[(ntile * 16 + r) * 72 + s * 32 + q * 8];

#pragma unroll
  for (int mi = 0; mi < 4; ++mi) {
    int mt = mgrp * 4 + mi;
    f32x4 a = {};
#pragma unroll
    for (int s = 0; s < 2; ++s) {
      short8 wf = *(const short8*)(W1p + (mt * 16 + r) * 64 + s * 32 + q * 8);
      a = __builtin_amdgcn_mfma_f32_16x16x32_bf16(wf, hf[s], a, 0, 0, 0);
    }
    int m0 = mt * 16 + q * 4;
    f32x4 v = a + *(const f32x4*)&b1[m0];
#pragma unroll
    for (int e = 0; e < 4; ++e)
      midb[(ntile * 16 + r) * 136 + pc128(m0 + e)] = f2bf(fmaxf(v[e], 0.f));
  }
  __syncthreads();

  short8 mf[4];
#pragma unroll
  for (int s = 0; s < 4; ++s)
    mf[s] = *(const short8*)&midb[(ntile * 16 + r) * 136 + s * 32 + q * 8];

  const int n = r0 + ntile * 16 + r;
#pragma unroll
  for (int mi = 0; mi < 2; ++mi) {
    int mt = mgrp * 2 + mi;
    f32x4 a = {};
#pragma unroll
    for (int s = 0; s < 4; ++s) {
      short8 wf = *(const short8*)(W2p + (mt * 16 + r) * 128 + s * 32 + q * 8);
      a = __builtin_amdgcn_mfma_f32_16x16x32_bf16(wf, mf[s], a, 0, 0, 0);
    }
    int m0 = mt * 16 + q * 4;
    f32x4 out = a + *(const f32x4*)&b2[m0] + *(const f32x4*)&rows[ntile * 16 + r][m0];
    *(f32x4*)&t4[(size_t)n * 64 + m0] = out;
    f32x4 s_ = out, q_ = out * out;
#pragma unroll
    for (int off = 1; off < 16; off <<= 1) {
#pragma unroll
      for (int e = 0; e < 4; ++e) {
        s_[e] += __shfl_xor(s_[e], off);
        q_[e] += __shfl_xor(q_[e], off);
      }
    }
    if (r == 0) {
#pragma unroll
      for (int e = 0; e < 4; ++e) {
        os[ntile][m0 + e] = s_[e];
        oss[ntile][m0 + e] = q_[e];
      }
    }
  }
  __syncthreads();
  if (t < 64) atomicAdd(&stats[t], os[0][t] + os[1][t]);
  else if (t < 128) {
    int c = t - 64;
    atomicAdd(&stats[64 + c], oss[0][c] + oss[1][c]);
  }
}

// ------------------------------------------- BN3 + LayerNorm + ReLU (fused; last layer)
__global__ __launch_bounds__(256) void bn3_ln_relu(const float* __restrict__ t4,
                                                   const float* __restrict__ s3,
                                                   const float* __restrict__ g3,
                                                   const float* __restrict__ b3,
                                                   const float* __restrict__ lg,
                                                   const float* __restrict__ lb,
                                                   float* __restrict__ H) {
  int wv = threadIdx.x >> 6, lane = threadIdx.x & 63;
  int n = blockIdx.x * 4 + wv;
  float m3 = s3[lane] * (1.f / NN);
  float v3 = s3[64 + lane] * (1.f / NN) - m3 * m3;
  float x = (t4[n * 64 + lane] - m3) * rsqrtf(v3 + EPSV) * g3[lane] + b3[lane];
  float s = x, ss = x * x;
  for (int o = 32; o > 0; o >>= 1) {
    s += __shfl_xor(s, o, 64);
    ss += __shfl_xor(ss, o, 64);
  }
  float m = s * (1.f / 64), v = ss * (1.f / 64) - m * m;
  float y = (x - m) * rsqrtf(v + EPSV) * lg[lane] + lb[lane];
  H[n * 64 + lane] = fmaxf(y, 0.f);
}

// ------------------------------------------- final GEMM (64x21) + log_softmax
__global__ __launch_bounds__(256) void final_kernel(const float* __restrict__ H,
                                                    const float* __restrict__ Wout,
                                                    const float* __restrict__ bout,
                                                    float* __restrict__ out) {
  int w = threadIdx.x >> 6, lane = threadIdx.x & 63;
  int n = blockIdx.x * 4 + w;
  const float* hr = H + n * 64;
  float acc = (lane < COUT) ? bout[lane] : -INFINITY;
  if (lane < COUT) {
#pragma unroll 16
    for (int k = 0; k < 64; ++k) acc = fmaf(hr[k], Wout[k * COUT + lane], acc);
  }
  float mx = acc;
  for (int o = 32; o > 0; o >>= 1) mx = fmaxf(mx, __shfl_xor(mx, o, 64));
  float e = __expf(acc - mx);
  float se = e;
  for (int o = 32; o > 0; o >>= 1) se += __shfl_xor(se, o, 64);
  float lse = mx + logf(se);
  if (lane < COUT) out[n * COUT + lane] = acc - lse;
}

// ================================================================ launch
extern "C" void kernel_launch(void* const* d_in, const int* in_sizes, int n_in,
                              void* d_out, int out_size, void* d_ws, size_t ws_size,
                              hipStream_t stream) {
  const float* x    = (const float*)d_in[0];
  const int*   ei   = (const int*)d_in[1];
  const float* W_in = (const float*)d_in[2];
  const float* b_in = (const float*)d_in[3];
  const float* gcnW = (const float*)d_in[4];
  const float* gcnB = (const float*)d_in[5];
  const float* Wqkv = (const float*)d_in[6];
  const float* bqkv = (const float*)d_in[7];
  const float* Wo   = (const float*)d_in[8];
  const float* bo   = (const float*)d_in[9];
  const float* bn1g = (const float*)d_in[10];
  const float* bn1b = (const float*)d_in[11];
  const float* bn2g = (const float*)d_in[12];
  const float* bn2b = (const float*)d_in[13];
  const float* bn3g = (const float*)d_in[14];
  const float* bn3b = (const float*)d_in[15];
  const float* W1   = (const float*)d_in[16];
  const float* b1   = (const float*)d_in[17];
  const float* W2   = (const float*)d_in[18];
  const float* b2   = (const float*)d_in[19];
  const float* lng  = (const float*)d_in[20];
  const float* lnb  = (const float*)d_in[21];
  const float* Wout = (const float*)d_in[22];
  const float* bout = (const float*)d_in[23];

  const int* src = ei;
  const int* dst = ei + NE;

  const int NC = NN * C;
  float* ws = (float*)d_ws;
  float* h     = ws + 0 * NC;
  float* t0    = ws + 1 * NC;     // xw (gather input), then oproj output
  float* t1    = ws + 2 * NC;
  float* Opart = ws + 3 * NC;     // 4MB: 128qt x 2ks x 64 x 64
  float* t4    = ws + 5 * NC;
  u16* Qb  = (u16*)(ws + 6 * NC);
  u16* Kb  = Qb + NC;
  u16* Vtb = Kb + NC;
  u16* hbb = Vtb + NC;
  u16* Wqp = hbb + NC;            // NL x 192 x 64
  u16* Wop = Wqp + NL * 192 * 64; // NL x 64 x 64
  u16* Wgp = Wop + NL * 64 * 64;  // NL x 64 x 64
  u16* W1p = Wgp + NL * 64 * 64;  // NL x 128 x 64
  u16* W2p = W1p + NL * 128 * 64; // NL x 64 x 128
  float* dinv = (float*)(W2p + NL * 64 * 128);
  float* statsAll = dinv + NN;    // 12 x 128
  float* Lpart = statsAll + 1536; // 128qt x 2ks x 64
  int* degi   = (int*)(Lpart + 16384);
  int* rowptr = degi + NN;        // NN+1
  int* cursor = rowptr + NN + 8;
  int* esrc   = cursor + NN;      // NE
  float* ewt  = (float*)(esrc + NE);  // NE

  dim3 B(256);

  // ---- setup: CSR + dinv + weight prep (deterministic; recomputed per call)
  zero_setup<<<32, B, 0, stream>>>(statsAll, degi);
  deg_kernel<<<NE / 256, B, 0, stream>>>(dst, degi);
  prefix_kernel<<<1, B, 0, stream>>>(degi, rowptr, cursor, dinv);
  fill_kernel<<<NE / 256, B, 0, stream>>>(src, dst, dinv, cursor, esrc, ewt);
  prep_weights<<<576, B, 0, stream>>>(Wqkv, Wo, gcnW, W1, W2, Wqp, Wop, Wgp, W1p, W2p);

  gemm_in_kernel<<<NN * C / 256, B, 0, stream>>>(x, W_in, b_in, h, hbb);

  for (int l = 0; l < NL; ++l) {
    float* s1 = statsAll + l * 384;
    float* s2 = s1 + 128;
    float* s3 = s1 + 256;
    int lp = (l > 0) ? (l - 1) : 0;
    float* s3prev = statsAll + lp * 384 + 256;

    // ---- fused [bn3+ln+relu of layer l-1] + gcn gemm + t1 init + QKV + Vt
    proj_mfma<<<NN / 16, 128, 0, stream>>>(hbb, h, Wqp + l * 192 * 64, Wgp + l * 4096,
                                           bqkv + l * 192, gcnB + l * C, dinv,
                                           Qb, Kb, Vtb, t0, t1,
                                           t4, s3prev, bn3g + lp * C, bn3b + lp * C,
                                           lng + lp * C, lnb + lp * C, (l == 0) ? 1 : 0);

    // ---- fused attention (blocks 0..255) + GCN gather + stats1 (blocks 256..767)
    attn_gather<<<768, 512, 0, stream>>>(Qb, Kb, Vtb, Opart, Lpart,
                                         rowptr, esrc, ewt, t0, dinv, t1, s1);
    // ---- O-projection + residual + stats2
    oproj_mfma<<<NN / 32, B, 0, stream>>>(Opart, Lpart, Wop + l * 4096, bo + l * C, h, t0, s2);

    // ---- combine + MLP (MFMA) -> t4 + fused stats3
    mlp_mfma<<<NN / 32, B, 0, stream>>>(t1, t0, s1, s2, bn1g + l * C, bn1b + l * C,
                                        bn2g + l * C, bn2b + l * C,
                                        W1p + l * 8192, b1 + l * 2 * C,
                                        W2p + l * 8192, b2 + l * C, t4, s3);
  }

  // ---- last layer's BN3 + LN + ReLU -> h, then output head
  bn3_ln_relu<<<NN / 4, B, 0, stream>>>(t4, statsAll + 3 * 384 + 256,
                                        bn3g + 3 * C, bn3b + 3 * C,
                                        lng + 3 * C, lnb + 3 * C, h);
  final_kernel<<<NN / 4, B, 0, stream>>>(h, Wout, bout, (float*)d_out);
}

// Round 21
// 459.098 us; speedup vs baseline: 1.7445x; 1.0115x over previous
//
#include <hip/hip_runtime.h>
#include <math.h>

#define NN 8192
#define NE 131072
#define CIN 128
#define C 64
#define NL 4
#define COUT 21
#define EPSV 1e-5f
#define ALPHA 0.18033688011112043f  // 0.125 * log2(e)

typedef unsigned short u16;
typedef __attribute__((ext_vector_type(8))) short short8;
typedef __attribute__((ext_vector_type(4))) float f32x4;
typedef __attribute__((ext_vector_type(4))) unsigned int u32x4;
typedef __attribute__((ext_vector_type(2))) unsigned int u32x2;

__device__ __forceinline__ u16 f2bf(float x) {
  unsigned int u = __float_as_uint(x);
  u += 0x7FFF + ((u >> 16) & 1);
  return (u16)(u >> 16);
}

__device__ __forceinline__ unsigned cvtpk(float a, float b) {
  unsigned r;
  asm("v_cvt_pk_bf16_f32 %0, %1, %2" : "=v"(r) : "v"(a), "v"(b));
  return r;
}

__device__ __forceinline__ int pcmap(int c) {  // k-dim permutation (within 32), c<64
  return (c & 32) | (c & 3) | (((c >> 2) & 3) << 3) | (((c >> 4) & 1) << 2);
}

__device__ __forceinline__ int pc128(int c) {  // same, for c<128
  return (c & 96) | (c & 3) | (((c >> 2) & 3) << 3) | (((c >> 4) & 1) << 2);
}

// ---------------------------------------------------------------- setup
__global__ void zero_setup(float* __restrict__ stats, int* __restrict__ degi) {
  int i = blockIdx.x * 256 + threadIdx.x;
  if (i < 1536) stats[i] = 0.f;
  if (i < NN) degi[i] = 0;
}

__global__ void deg_kernel(const int* __restrict__ dst, int* __restrict__ degi) {
  int e = blockIdx.x * 256 + threadIdx.x;
  if (e < NE) atomicAdd(&degi[dst[e]], 1);
}

// prefix sum + cursor init + dinv (fused)
__global__ __launch_bounds__(256) void prefix_kernel(const int* __restrict__ degi,
                                                     int* __restrict__ rowptr,
                                                     int* __restrict__ cursor,
                                                     float* __restrict__ dinv) {
  __shared__ int part[256];
  int t = threadIdx.x;
  int base = t * 32;
  int loc[32];
  int s = 0;
#pragma unroll
  for (int i = 0; i < 32; ++i) { loc[i] = s; s += degi[base + i]; }
  part[t] = s;
  __syncthreads();
  for (int off = 1; off < 256; off <<= 1) {
    int v = (t >= off) ? part[t - off] : 0;
    __syncthreads();
    part[t] += v;
    __syncthreads();
  }
  int chunkbase = (t == 0) ? 0 : part[t - 1];
#pragma unroll
  for (int i = 0; i < 32; ++i) {
    int v = chunkbase + loc[i];
    rowptr[base + i] = v;
    cursor[base + i] = v;
    dinv[base + i] = rsqrtf((float)degi[base + i] + 1.0f);
  }
  if (t == 255) rowptr[NN] = part[255];
}

__global__ void fill_kernel(const int* __restrict__ src, const int* __restrict__ dst,
                            const float* __restrict__ dinv,
                            int* __restrict__ cursor, int* __restrict__ esrc,
                            float* __restrict__ ewt) {
  int e = blockIdx.x * 256 + threadIdx.x;
  if (e < NE) {
    int d = dst[e];
    int s = src[e];
    int pos = atomicAdd(&cursor[d], 1);
    esrc[pos] = s;
    ewt[pos] = dinv[s];
  }
}

// ------------------------------------- weight prep: bf16 + pc-permute k-dim
__global__ void prep_weights(const float* __restrict__ Wqkv, const float* __restrict__ Wo,
                             const float* __restrict__ Wg,
                             const float* __restrict__ W1, const float* __restrict__ W2,
                             u16* __restrict__ Wqp, u16* __restrict__ Wop,
                             u16* __restrict__ Wgp,
                             u16* __restrict__ W1p, u16* __restrict__ W2p) {
  int idx = blockIdx.x * 256 + threadIdx.x;   // 147456 total
  if (idx < NL * 192 * 64) {
    int l = idx / 12288, rem = idx % 12288;
    int j = rem >> 6, c = rem & 63;
    Wqp[l * 12288 + j * 64 + pcmap(c)] = f2bf(Wqkv[idx]);
  } else if (idx < NL * 192 * 64 + NL * 64 * 64) {
    int i2 = idx - NL * 192 * 64;
    int l = i2 >> 12, m = (i2 >> 6) & 63, k = i2 & 63;
    Wop[l * 4096 + m * 64 + pcmap(k)] = f2bf(Wo[i2]);
  } else if (idx < NL * 192 * 64 + 2 * NL * 64 * 64) {
    int i3 = idx - NL * 192 * 64 - NL * 64 * 64;
    int l = i3 >> 12, k = (i3 >> 6) & 63, c = i3 & 63;
    Wgp[l * 4096 + c * 64 + pcmap(k)] = f2bf(Wg[i3]);  // transpose: row=out ch
  } else if (idx < NL * 192 * 64 + 2 * NL * 64 * 64 + NL * 64 * 128) {
    int i4 = idx - (NL * 192 * 64 + 2 * NL * 64 * 64);  // W1: [L][64k][128m]
    int l = i4 >> 13, i3 = i4 & 8191;
    int k = i3 >> 7, m = i3 & 127;
    W1p[l * 8192 + m * 64 + pcmap(k)] = f2bf(W1[i4]);
  } else if (idx < NL * 192 * 64 + 2 * NL * 64 * 64 + 2 * NL * 64 * 128) {
    int i5 = idx - (NL * 192 * 64 + 2 * NL * 64 * 64 + NL * 64 * 128);  // W2: [L][128k][64m]
    int l = i5 >> 13, i3 = i5 & 8191;
    int k = i3 >> 6, m = i3 & 63;
    W2p[l * 8192 + m * 128 + pc128(k)] = f2bf(W2[i5]);
  }
}

// ------------------------------------------------------------- input GEMM
__global__ __launch_bounds__(256) void gemm_in_kernel(const float* __restrict__ X,
                                                      const float* __restrict__ W,
                                                      const float* __restrict__ b,
                                                      float* __restrict__ Y,
                                                      u16* __restrict__ hb) {
  int idx = blockIdx.x * 256 + threadIdx.x;
  int n = idx >> 6, c = idx & 63;
  const float* xr = X + n * CIN;
  float acc = b[c];
#pragma unroll 16
  for (int k = 0; k < CIN; ++k) acc = fmaf(xr[k], W[k * C + c], acc);
  Y[idx] = acc;
  hb[n * 64 + pcmap(c)] = f2bf(acc);
}

// -------- fused [BN3+LN+ReLU of prev layer] + GCN gemm + t1 init + QKV + Vt
// grid 512 x 128 thr. Block = 16 rows. Phase 0: compute h rows (or stage for
// l==0) into LDS; then w0: gcn + Q, w1: K + V->LDS; then Vt store.
__global__ __launch_bounds__(128) void proj_mfma(const u16* __restrict__ hbin,
                                                 float* __restrict__ h,
                                                 const u16* __restrict__ Wqp,
                                                 const u16* __restrict__ Wgp,
                                                 const float* __restrict__ bq,
                                                 const float* __restrict__ gb,
                                                 const float* __restrict__ dinv,
                                                 u16* __restrict__ Qb,
                                                 u16* __restrict__ Kb,
                                                 u16* __restrict__ Vt,
                                                 float* __restrict__ xw,
                                                 float* __restrict__ t1,
                                                 const float* __restrict__ t4,
                                                 const float* __restrict__ s3g,
                                                 const float* __restrict__ g3,
                                                 const float* __restrict__ b3,
                                                 const float* __restrict__ lg,
                                                 const float* __restrict__ lb,
                                                 int isL0) {
  __shared__ float rowsF[16][68];
  __shared__ u16 xbL[16 * 72];
  __shared__ u16 ldsv[64 * 17];
  const int tid = threadIdx.x;
  const int lane = tid & 63, w = tid >> 6;
  const int r = lane & 15, q = lane >> 4;
  const int n0 = blockIdx.x * 16;
  const int n = n0 + r;

  // ---- Phase 0: produce h rows n0..n0+15 in LDS (+global for l>0)
  {
    int rloc = tid >> 3, cg = tid & 7;
    int nrow = n0 + rloc;
    if (isL0) {
#pragma unroll
      for (int e = 0; e < 8; ++e) {
        int c = cg * 8 + e;
        rowsF[rloc][c] = h[(size_t)nrow * 64 + c];
        xbL[rloc * 72 + c] = hbin[(size_t)nrow * 64 + c];
      }
    } else {
      float xv[8];
      float s = 0.f, ss = 0.f;
#pragma unroll
      for (int e = 0; e < 8; ++e) {
        int c = cg * 8 + e;
        float m3 = s3g[c] * (1.f / NN);
        float v3 = s3g[64 + c] * (1.f / NN) - m3 * m3;
        float x = (t4[(size_t)nrow * 64 + c] - m3) * rsqrtf(v3 + EPSV) * g3[c] + b3[c];
        xv[e] = x;
        s += x; ss += x * x;
      }
      s += __shfl_xor(s, 1); ss += __shfl_xor(ss, 1);
      s += __shfl_xor(s, 2); ss += __shfl_xor(ss, 2);
      s += __shfl_xor(s, 4); ss += __shfl_xor(ss, 4);
      float m = s * (1.f / 64), v = ss * (1.f / 64) - m * m;
      float rs = rsqrtf(v + EPSV);
#pragma unroll
      for (int e = 0; e < 8; ++e) {
        int c = cg * 8 + e;
        float y = (xv[e] - m) * rs * lg[c] + lb[c];
        y = fmaxf(y, 0.f);
        h[(size_t)nrow * 64 + c] = y;
        rowsF[rloc][c] = y;
        xbL[rloc * 72 + pcmap(c)] = f2bf(y);
      }
    }
  }
  __syncthreads();

  short8 hf[2];
#pragma unroll
  for (int s = 0; s < 2; ++s)
    hf[s] = *(const short8*)&xbL[r * 72 + s * 32 + q * 8];

  if (w == 0) {
    float di = dinv[n];
#pragma unroll
    for (int jt = 0; jt < 4; ++jt) {
      f32x4 a = {};
#pragma unroll
      for (int s = 0; s < 2; ++s) {
        short8 wf = *(const short8*)(Wgp + (jt * 16 + r) * 64 + s * 32 + q * 8);
        a = __builtin_amdgcn_mfma_f32_16x16x32_bf16(wf, hf[s], a, 0, 0, 0);
      }
      int j0 = jt * 16 + q * 4;
      f32x4 hres = *(const f32x4*)&rowsF[r][j0];
      f32x4 gbv = *(const f32x4*)&gb[j0];
      *(f32x4*)&xw[(size_t)n * 64 + j0] = a;
      *(f32x4*)&t1[(size_t)n * 64 + j0] = a * di * di + gbv + hres;
    }
#pragma unroll
    for (int jt = 0; jt < 4; ++jt) {
      f32x4 a = {};
#pragma unroll
      for (int s = 0; s < 2; ++s) {
        short8 wf = *(const short8*)(Wqp + (jt * 16 + r) * 64 + s * 32 + q * 8);
        a = __builtin_amdgcn_mfma_f32_16x16x32_bf16(wf, hf[s], a, 0, 0, 0);
      }
      f32x4 v = (a + *(const f32x4*)&bq[jt * 16 + q * 4]) * ALPHA;
      int pb = ((jt & 2) << 4) | (q << 3) | ((jt & 1) << 2);
      *(u32x2*)(Qb + (size_t)n * 64 + pb) = u32x2{cvtpk(v[0], v[1]), cvtpk(v[2], v[3])};
    }
  } else {
#pragma unroll
    for (int jt = 0; jt < 4; ++jt) {
      f32x4 a = {};
#pragma unroll
      for (int s = 0; s < 2; ++s) {
        short8 wf = *(const short8*)(Wqp + (64 + jt * 16 + r) * 64 + s * 32 + q * 8);
        a = __builtin_amdgcn_mfma_f32_16x16x32_bf16(wf, hf[s], a, 0, 0, 0);
      }
      f32x4 v = a + *(const f32x4*)&bq[64 + jt * 16 + q * 4];
      int pb = ((jt & 2) << 4) | (q << 3) | ((jt & 1) << 2);
      *(u32x2*)(Kb + (size_t)n * 64 + pb) = u32x2{cvtpk(v[0], v[1]), cvtpk(v[2], v[3])};
    }
#pragma unroll
    for (int jt = 0; jt < 4; ++jt) {
      f32x4 a = {};
#pragma unroll
      for (int s = 0; s < 2; ++s) {
        short8 wf = *(const short8*)(Wqp + (128 + jt * 16 + r) * 64 + s * 32 + q * 8);
        a = __builtin_amdgcn_mfma_f32_16x16x32_bf16(wf, hf[s], a, 0, 0, 0);
      }
      f32x4 v = a + *(const f32x4*)&bq[128 + jt * 16 + q * 4];
      int j0 = jt * 16 + q * 4;
#pragma unroll
      for (int e = 0; e < 4; ++e) ldsv[(j0 + e) * 17 + r] = f2bf(v[e]);
    }
  }
  __syncthreads();

  const int d = tid >> 1, cp = tid & 1;
  const int grp = n0 & ~31, hh = (n0 >> 4) & 1;
#pragma unroll
  for (int ci = 0; ci < 2; ++ci) {
    int cc = cp * 2 + ci;
    u16 a0 = ldsv[d * 17 + cc * 4 + 0];
    u16 a1 = ldsv[d * 17 + cc * 4 + 1];
    u16 a2 = ldsv[d * 17 + cc * 4 + 2];
    u16 a3 = ldsv[d * 17 + cc * 4 + 3];
    *(u32x2*)(Vt + (size_t)d * NN + grp + cc * 8 + hh * 4) =
        u32x2{(unsigned)a0 | ((unsigned)a1 << 16), (unsigned)a2 | ((unsigned)a3 << 16)};
  }
}

// ------------------------------------------------------------ MFMA flash attention
// fused with GCN gather: grid 768 x 512 thr. Blocks 0..255: attn. 256..767: gather.
__device__ __forceinline__ void loadK(short8 (&kf)[8], const u16* kb, int koff) {
#pragma unroll
  for (int jt = 0; jt < 4; ++jt)
#pragma unroll
    for (int s = 0; s < 2; ++s)
      kf[jt * 2 + s] = *(const short8*)(kb + koff + jt * 1024 + s * 32);
}

__device__ __forceinline__ void loadV(short8 (&vf)[8], const u16* vb, int voff) {
#pragma unroll
  for (int dt = 0; dt < 4; ++dt)
#pragma unroll
    for (int s = 0; s < 2; ++s)
      vf[dt * 2 + s] = *(const short8*)(vb + voff + dt * 16 * NN + s * 32);
}

__device__ __forceinline__ void computeTile(const short8 (&kf)[8], const short8 (&vf)[8],
                                            const short8 (&qf)[4][2],
                                            f32x4 (&o)[4][4], float (&ll)[4]) {
#pragma unroll
  for (int pair = 0; pair < 2; ++pair) {
    f32x4 st[2][4] = {};
#pragma unroll
    for (int s = 0; s < 2; ++s)
#pragma unroll
      for (int jp = 0; jp < 2; ++jp) {
        short8 kfrag = kf[(pair * 2 + jp) * 2 + s];
#pragma unroll
        for (int it = 0; it < 4; ++it)
          st[jp][it] = __builtin_amdgcn_mfma_f32_16x16x32_bf16(kfrag, qf[it][s], st[jp][it], 0, 0, 0);
      }
    short8 pf[4];
#pragma unroll
    for (int it = 0; it < 4; ++it) {
      float p[8];
#pragma unroll
      for (int jp = 0; jp < 2; ++jp)
#pragma unroll
        for (int r = 0; r < 4; ++r) p[jp * 4 + r] = exp2f(st[jp][it][r]);
      ll[it] += ((p[0] + p[1]) + (p[2] + p[3])) + ((p[4] + p[5]) + (p[6] + p[7]));
      u32x4 a;
      a[0] = cvtpk(p[0], p[1]); a[1] = cvtpk(p[2], p[3]);
      a[2] = cvtpk(p[4], p[5]); a[3] = cvtpk(p[6], p[7]);
      pf[it] = __builtin_bit_cast(short8, a);
    }
#pragma unroll
    for (int dt = 0; dt < 4; ++dt) {
      short8 vfrag = vf[dt * 2 + pair];
#pragma unroll
      for (int it = 0; it < 4; ++it)
        o[dt][it] = __builtin_amdgcn_mfma_f32_16x16x32_bf16(vfrag, pf[it], o[dt][it], 0, 0, 0);
    }
  }
}

__global__ __launch_bounds__(512, 2)
void attn_gather(const u16* __restrict__ Qb, const u16* __restrict__ Kb,
                 const u16* __restrict__ Vtb, float* __restrict__ Opart,
                 float* __restrict__ Lpart,
                 const int* __restrict__ rowptr, const int* __restrict__ esrc,
                 const float* __restrict__ ewt, const float* __restrict__ xw,
                 const float* __restrict__ dinv, float* __restrict__ t1,
                 float* __restrict__ stats) {
  __shared__ float fsm[2 * 64 * 68 + 2 * 64];
  const int tid = threadIdx.x;
  const int lane = tid & 63;
  const int w = tid >> 6;

  if (blockIdx.x >= 256) {
    // ================= gather branch: 16 rows/block =================
    const int bid2 = blockIdx.x - 256;
    float* gs = fsm;          // [8][64]
    float* gss = fsm + 512;   // [8][64]
    float s = 0.f, ss = 0.f;
#pragma unroll
    for (int rr = 0; rr < 2; ++rr) {
      int d = bid2 * 16 + w * 2 + rr;
      int beg = rowptr[d], end = rowptr[d + 1];
      float acc = 0.f;
      int i = beg;
      for (; i + 4 <= end; i += 4) {
        int s0 = esrc[i], s1 = esrc[i + 1], s2 = esrc[i + 2], s3 = esrc[i + 3];
        float w0 = ewt[i], w1 = ewt[i + 1], w2 = ewt[i + 2], w3 = ewt[i + 3];
        float x0 = xw[(size_t)s0 * 64 + lane];
        float x1 = xw[(size_t)s1 * 64 + lane];
        float x2 = xw[(size_t)s2 * 64 + lane];
        float x3 = xw[(size_t)s3 * 64 + lane];
        acc = fmaf(x0, w0, acc);
        acc = fmaf(x1, w1, acc);
        acc = fmaf(x2, w2, acc);
        acc = fmaf(x3, w3, acc);
      }
      for (; i < end; ++i) acc = fmaf(xw[(size_t)esrc[i] * 64 + lane], ewt[i], acc);
      size_t idx = (size_t)d * 64 + lane;
      float v = t1[idx] + acc * dinv[d];
      t1[idx] = v;
      s += v; ss += v * v;
    }
    gs[w * 64 + lane] = s; gss[w * 64 + lane] = ss;
    __syncthreads();
    if (tid < 64) {
      float a = 0.f;
#pragma unroll
      for (int j = 0; j < 8; ++j) a += gs[j * 64 + tid];
      atomicAdd(&stats[tid], a);
    } else if (tid < 128) {
      int c = tid - 64;
      float a = 0.f;
#pragma unroll
      for (int j = 0; j < 8; ++j) a += gss[j * 64 + c];
      atomicAdd(&stats[64 + c], a);
    }
    return;
  }

  // ================= attn branch =================
  const int qt = blockIdx.x >> 1, ks = blockIdx.x & 1;
  const int qbase = qt * 64;
  const int kv0 = ks * 4096 + w * 512;
  const int r = lane & 15, q = lane >> 4;

  short8 qf[4][2];
#pragma unroll
  for (int it = 0; it < 4; ++it)
#pragma unroll
    for (int s = 0; s < 2; ++s)
      qf[it][s] = *(const short8*)(Qb + (size_t)(qbase + it * 16 + r) * 64 + s * 32 + q * 8);

  f32x4 o[4][4] = {};
  float ll[4] = {0.f, 0.f, 0.f, 0.f};

  const u16* kb = Kb + (size_t)(kv0 + r) * 64 + q * 8;
  const u16* vb = Vtb + (size_t)r * NN + kv0 + q * 8;

  short8 kA[8], kB[8], vf[8];
  loadK(kA, kb, 0);
#pragma unroll 1
  for (int t = 0; t < 8; t += 2) {
    loadV(vf, vb, t * 64);
    loadK(kB, kb, (t + 1) * 4096);
    computeTile(kA, vf, qf, o, ll);
    loadV(vf, vb, (t + 1) * 64);
    if (t + 2 < 8) loadK(kA, kb, (t + 2) * 4096);
    computeTile(kB, vf, qf, o, ll);
  }

#pragma unroll
  for (int it = 0; it < 4; ++it) {
    ll[it] += __shfl_xor(ll[it], 16);
    ll[it] += __shfl_xor(ll[it], 32);
  }

  // ---- 8-wave merge: 2 LDS bufs, 4 rounds
  float* buf = fsm + (w & 1) * (64 * 68);
  float* lb = fsm + 2 * 64 * 68 + (w & 1) * 64;
  for (int rr = 0; rr < 4; ++rr) {
    if ((w >> 1) == rr) {
      if (rr == 0) {
#pragma unroll
        for (int dt = 0; dt < 4; ++dt)
#pragma unroll
          for (int it = 0; it < 4; ++it)
            *(f32x4*)&buf[(it * 16 + r) * 68 + dt * 16 + q * 4] = o[dt][it];
        if (lane < 16)
#pragma unroll
          for (int it = 0; it < 4; ++it) lb[it * 16 + lane] = ll[it];
      } else {
#pragma unroll
        for (int dt = 0; dt < 4; ++dt)
#pragma unroll
          for (int it = 0; it < 4; ++it) {
            float* p = &buf[(it * 16 + r) * 68 + dt * 16 + q * 4];
            *(f32x4*)p = *(const f32x4*)p + o[dt][it];
          }
        if (lane < 16)
#pragma unroll
          for (int it = 0; it < 4; ++it) lb[it * 16 + lane] += ll[it];
      }
    }
    __syncthreads();
  }

  int row = tid >> 3, d0 = (tid & 7) * 8;
  float* outp = Opart + (size_t)(qt * 2 + ks) * 4096 + row * 64 + d0;
  const float* b0 = fsm + row * 68 + d0;
  const float* b1 = b0 + 64 * 68;
#pragma unroll
  for (int j = 0; j < 8; ++j) outp[j] = b0[j] + b1[j];
  if (tid < 64)
    Lpart[(qt * 2 + ks) * 64 + tid] = fsm[2 * 64 * 68 + tid] + fsm[2 * 64 * 68 + 64 + tid];
}

// ------ O-projection MFMA (+2-way merge +1/l +bias +res) + fused BN stats2
__global__ __launch_bounds__(256) void oproj_mfma(const float* __restrict__ Opart,
                                                  const float* __restrict__ Lpart,
                                                  const u16* __restrict__ Wop,
                                                  const float* __restrict__ bo,
                                                  const float* __restrict__ res,
                                                  float* __restrict__ Y,
                                                  float* __restrict__ stats) {
  __shared__ u16 ldso[32 * 72];
  __shared__ float os[2][64], oss[2][64];
  const int tid = threadIdx.x;
  const int n0 = blockIdx.x * 32;
  const int qtile = n0 >> 6;

  {
    int row = tid >> 3, c0 = (tid & 7) * 8;
    int r64 = (n0 + row) & 63;
    float inv = 1.f / (Lpart[qtile * 128 + r64] + Lpart[qtile * 128 + 64 + r64]);
    const float* O0 = Opart + (size_t)(qtile * 2) * 4096 + r64 * 64;
    const float* O1 = O0 + 4096;
#pragma unroll
    for (int j8 = 0; j8 < 2; ++j8) {
      f32x4 a = *(const f32x4*)&O0[c0 + j8 * 4];
      f32x4 b = *(const f32x4*)&O1[c0 + j8 * 4];
      f32x4 vsum = (a + b) * inv;
#pragma unroll
      for (int e = 0; e < 4; ++e) ldso[row * 72 + pcmap(c0 + j8 * 4 + e)] = f2bf(vsum[e]);
    }
  }
  __syncthreads();

  const int lane = tid & 63, w = tid >> 6;
  const int r = lane & 15, q = lane >> 4;
  const int ntile = w & 1, mhalf = w >> 1;
  short8 hf[2];
#pragma unroll
  for (int s = 0; s < 2; ++s)
    hf[s] = *(const short8*)&ldso[(ntile * 16 + r) * 72 + s * 32 + q * 8];

  const int n = n0 + ntile * 16 + r;
#pragma unroll
  for (int mi = 0; mi < 2; ++mi) {
    int mt = mhalf * 2 + mi;
    f32x4 a = {};
#pragma unroll
    for (int s = 0; s < 2; ++s) {
      short8 wf = *(const short8*)(Wop + (mt * 16 + r) * 64 + s * 32 + q * 8);
      a = __builtin_amdgcn_mfma_f32_16x16x32_bf16(wf, hf[s], a, 0, 0, 0);
    }
    int m0 = mt * 16 + q * 4;
    f32x4 out = a + *(const f32x4*)&bo[m0] + *(const f32x4*)&res[(size_t)n * 64 + m0];
    *(f32x4*)&Y[(size_t)n * 64 + m0] = out;
    f32x4 s_ = out, q_ = out * out;
#pragma unroll
    for (int off = 1; off < 16; off <<= 1) {
#pragma unroll
      for (int e = 0; e < 4; ++e) {
        s_[e] += __shfl_xor(s_[e], off);
        q_[e] += __shfl_xor(q_[e], off);
      }
    }
    if (r == 0) {
#pragma unroll
      for (int e = 0; e < 4; ++e) {
        os[ntile][m0 + e] = s_[e];
        oss[ntile][m0 + e] = q_[e];
      }
    }
  }
  __syncthreads();
  if (tid < 64) atomicAdd(&stats[tid], os[0][tid] + os[1][tid]);
  else if (tid < 128) {
    int c = tid - 64;
    atomicAdd(&stats[64 + c], oss[0][c] + oss[1][c]);
  }
}

// -------- fused combine(bn1+bn2) + MLP via MFMA (+relu +residual) + BN stats3
__global__ __launch_bounds__(256) void mlp_mfma(const float* __restrict__ t1,
                                                const float* __restrict__ t0,
                                                const float* __restrict__ s1,
                                                const float* __restrict__ s2,
                                                const float* __restrict__ g1,
                                                const float* __restrict__ bb1,
                                                const float* __restrict__ g2,
                                                const float* __restrict__ bb2,
                                                const u16* __restrict__ W1p,
                                                const float* __restrict__ b1,
                                                const u16* __restrict__ W2p,
                                                const float* __restrict__ b2,
                                                float* __restrict__ t4,
                                                float* __restrict__ stats) {
  __shared__ float rows[32][68];
  __shared__ u16 xb[32 * 72];
  __shared__ u16 midb[32 * 136];
  __shared__ float os[2][64], oss[2][64];
  int t = threadIdx.x;
  int r0 = blockIdx.x * 32;

  for (int i = t; i < 2048; i += 256) {
    int rr = i >> 6, c = i & 63;
    int idx = (r0 + rr) * 64 + c;
    float m1 = s1[c] * (1.f / NN);
    float v1 = s1[64 + c] * (1.f / NN) - m1 * m1;
    float m2 = s2[c] * (1.f / NN);
    float v2 = s2[64 + c] * (1.f / NN) - m2 * m2;
    float val = (t1[idx] - m1) * rsqrtf(v1 + EPSV) * g1[c] + bb1[c] +
                (t0[idx] - m2) * rsqrtf(v2 + EPSV) * g2[c] + bb2[c];
    rows[rr][c] = val;
    xb[rr * 72 + pcmap(c)] = f2bf(val);
  }
  __syncthreads();

  const int lane = t & 63, w = t >> 6;
  const int r = lane & 15, q = lane >> 4;
  const int ntile = w & 1, mgrp = w >> 1;

  short8 hf[2];
#pragma unroll
  for (int s = 0; s < 2; ++s)
    hf[s] = *(const short8*)&xb[(ntile * 16 + r) * 72 + s * 32 + q * 8];

#pragma unroll
  for (int mi = 0; mi < 4; ++mi) {
    int mt = mgrp * 4 + mi;
    f32x4 a = {};
#pragma unroll
    for (int s = 0; s < 2; ++s) {
      short8 wf = *(const short8*)(W1p + (mt * 16 + r) * 64 + s * 32 + q * 8);
      a = __builtin_amdgcn_mfma_f32_16x16x32_bf16(wf, hf[s], a, 0, 0, 0);
    }
    int m0 = mt * 16 + q * 4;
    f32x4 v = a + *(const f32x4*)&b1[m0];
#pragma unroll
    for (int e = 0; e < 4; ++e)
      midb[(ntile * 16 + r) * 136 + pc128(m0 + e)] = f2bf(fmaxf(v[e], 0.f));
  }
  __syncthreads();

  short8 mf[4];
#pragma unroll
  for (int s = 0; s < 4; ++s)
    mf[s] = *(const short8*)&midb[(ntile * 16 + r) * 136 + s * 32 + q * 8];

  const int n = r0 + ntile * 16 + r;
#pragma unroll
  for (int mi = 0; mi < 2; ++mi) {
    int mt = mgrp * 2 + mi;
    f32x4 a = {};
#pragma unroll
    for (int s = 0; s < 4; ++s) {
      short8 wf = *(const short8*)(W2p + (mt * 16 + r) * 128 + s * 32 + q * 8);
      a = __builtin_amdgcn_mfma_f32_16x16x32_bf16(wf, mf[s], a, 0, 0, 0);
    }
    int m0 = mt * 16 + q * 4;
    f32x4 out = a + *(const f32x4*)&b2[m0] + *(const f32x4*)&rows[ntile * 16 + r][m0];
    *(f32x4*)&t4[(size_t)n * 64 + m0] = out;
    f32x4 s_ = out, q_ = out * out;
#pragma unroll
    for (int off = 1; off < 16; off <<= 1) {
#pragma unroll
      for (int e = 0; e < 4; ++e) {
        s_[e] += __shfl_xor(s_[e], off);
        q_[e] += __shfl_xor(q_[e], off);
      }
    }
    if (r == 0) {
#pragma unroll
      for (int e = 0; e < 4; ++e) {
        os[ntile][m0 + e] = s_[e];
        oss[ntile][m0 + e] = q_[e];
      }
    }
  }
  __syncthreads();
  if (t < 64) atomicAdd(&stats[t], os[0][t] + os[1][t]);
  else if (t < 128) {
    int c = t - 64;
    atomicAdd(&stats[64 + c], oss[0][c] + oss[1][c]);
  }
}

// ---- fused [BN3 + LN + ReLU (last layer)] + final GEMM (64x21) + log_softmax
__global__ __launch_bounds__(256) void bn3_ln_final(const float* __restrict__ t4,
                                                    const float* __restrict__ s3,
                                                    const float* __restrict__ g3,
                                                    const float* __restrict__ b3,
                                                    const float* __restrict__ lg,
                                                    const float* __restrict__ lb,
                                                    const float* __restrict__ Wout,
                                                    const float* __restrict__ bout,
                                                    float* __restrict__ out) {
  __shared__ float rows[4][64];
  int wv = threadIdx.x >> 6, lane = threadIdx.x & 63;
  int n = blockIdx.x * 4 + wv;
  float m3 = s3[lane] * (1.f / NN);
  float v3 = s3[64 + lane] * (1.f / NN) - m3 * m3;
  float x = (t4[(size_t)n * 64 + lane] - m3) * rsqrtf(v3 + EPSV) * g3[lane] + b3[lane];
  float s = x, ss = x * x;
  for (int o = 32; o > 0; o >>= 1) {
    s += __shfl_xor(s, o, 64);
    ss += __shfl_xor(ss, o, 64);
  }
  float m = s * (1.f / 64), v = ss * (1.f / 64) - m * m;
  float y = (x - m) * rsqrtf(v + EPSV) * lg[lane] + lb[lane];
  rows[wv][lane] = fmaxf(y, 0.f);
  __syncthreads();

  float acc = (lane < COUT) ? bout[lane] : -INFINITY;
  if (lane < COUT) {
#pragma unroll 16
    for (int k = 0; k < 64; ++k) acc = fmaf(rows[wv][k], Wout[k * COUT + lane], acc);
  }
  float mx = acc;
  for (int o = 32; o > 0; o >>= 1) mx = fmaxf(mx, __shfl_xor(mx, o, 64));
  float e = __expf(acc - mx);
  float se = e;
  for (int o = 32; o > 0; o >>= 1) se += __shfl_xor(se, o, 64);
  float lse = mx + logf(se);
  if (lane < COUT) out[(size_t)n * COUT + lane] = acc - lse;
}

// ================================================================ launch
extern "C" void kernel_launch(void* const* d_in, const int* in_sizes, int n_in,
                              void* d_out, int out_size, void* d_ws, size_t ws_size,
                              hipStream_t stream) {
  const float* x    = (const float*)d_in[0];
  const int*   ei   = (const int*)d_in[1];
  const float* W_in = (const float*)d_in[2];
  const float* b_in = (const float*)d_in[3];
  const float* gcnW = (const float*)d_in[4];
  const float* gcnB = (const float*)d_in[5];
  const float* Wqkv = (const float*)d_in[6];
  const float* bqkv = (const float*)d_in[7];
  const float* Wo   = (const float*)d_in[8];
  const float* bo   = (const float*)d_in[9];
  const float* bn1g = (const float*)d_in[10];
  const float* bn1b = (const float*)d_in[11];
  const float* bn2g = (const float*)d_in[12];
  const float* bn2b = (const float*)d_in[13];
  const float* bn3g = (const float*)d_in[14];
  const float* bn3b = (const float*)d_in[15];
  const float* W1   = (const float*)d_in[16];
  const float* b1   = (const float*)d_in[17];
  const float* W2   = (const float*)d_in[18];
  const float* b2   = (const float*)d_in[19];
  const float* lng  = (const float*)d_in[20];
  const float* lnb  = (const float*)d_in[21];
  const float* Wout = (const float*)d_in[22];
  const float* bout = (const float*)d_in[23];

  const int* src = ei;
  const int* dst = ei + NE;

  const int NC = NN * C;
  float* ws = (float*)d_ws;
  float* h     = ws + 0 * NC;
  float* t0    = ws + 1 * NC;     // xw (gather input), then oproj output
  float* t1    = ws + 2 * NC;
  float* Opart = ws + 3 * NC;     // 4MB: 128qt x 2ks x 64 x 64
  float* t4    = ws + 5 * NC;
  u16* Qb  = (u16*)(ws + 6 * NC);
  u16* Kb  = Qb + NC;
  u16* Vtb = Kb + NC;
  u16* hbb = Vtb + NC;
  u16* Wqp = hbb + NC;            // NL x 192 x 64
  u16* Wop = Wqp + NL * 192 * 64; // NL x 64 x 64
  u16* Wgp = Wop + NL * 64 * 64;  // NL x 64 x 64
  u16* W1p = Wgp + NL * 64 * 64;  // NL x 128 x 64
  u16* W2p = W1p + NL * 128 * 64; // NL x 64 x 128
  float* dinv = (float*)(W2p + NL * 64 * 128);
  float* statsAll = dinv + NN;    // 12 x 128
  float* Lpart = statsAll + 1536; // 128qt x 2ks x 64
  int* degi   = (int*)(Lpart + 16384);
  int* rowptr = degi + NN;        // NN+1
  int* cursor = rowptr + NN + 8;
  int* esrc   = cursor + NN;      // NE
  float* ewt  = (float*)(esrc + NE);  // NE

  dim3 B(256);

  // ---- setup: CSR + dinv + weight prep (deterministic; recomputed per call)
  zero_setup<<<32, B, 0, stream>>>(statsAll, degi);
  deg_kernel<<<NE / 256, B, 0, stream>>>(dst, degi);
  prefix_kernel<<<1, B, 0, stream>>>(degi, rowptr, cursor, dinv);
  fill_kernel<<<NE / 256, B, 0, stream>>>(src, dst, dinv, cursor, esrc, ewt);
  prep_weights<<<576, B, 0, stream>>>(Wqkv, Wo, gcnW, W1, W2, Wqp, Wop, Wgp, W1p, W2p);

  gemm_in_kernel<<<NN * C / 256, B, 0, stream>>>(x, W_in, b_in, h, hbb);

  for (int l = 0; l < NL; ++l) {
    float* s1 = statsAll + l * 384;
    float* s2 = s1 + 128;
    float* s3 = s1 + 256;
    int lp = (l > 0) ? (l - 1) : 0;
    float* s3prev = statsAll + lp * 384 + 256;

    // ---- fused [bn3+ln+relu of layer l-1] + gcn gemm + t1 init + QKV + Vt
    proj_mfma<<<NN / 16, 128, 0, stream>>>(hbb, h, Wqp + l * 192 * 64, Wgp + l * 4096,
                                           bqkv + l * 192, gcnB + l * C, dinv,
                                           Qb, Kb, Vtb, t0, t1,
                                           t4, s3prev, bn3g + lp * C, bn3b + lp * C,
                                           lng + lp * C, lnb + lp * C, (l == 0) ? 1 : 0);

    // ---- fused attention (blocks 0..255) + GCN gather + stats1 (blocks 256..767)
    attn_gather<<<768, 512, 0, stream>>>(Qb, Kb, Vtb, Opart, Lpart,
                                         rowptr, esrc, ewt, t0, dinv, t1, s1);
    // ---- O-projection + residual + stats2
    oproj_mfma<<<NN / 32, B, 0, stream>>>(Opart, Lpart, Wop + l * 4096, bo + l * C, h, t0, s2);

    // ---- combine + MLP (MFMA) -> t4 + fused stats3
    mlp_mfma<<<NN / 32, B, 0, stream>>>(t1, t0, s1, s2, bn1g + l * C, bn1b + l * C,
                                        bn2g + l * C, bn2b + l * C,
                                        W1p + l * 8192, b1 + l * 2 * C,
                                        W2p + l * 8192, b2 + l * C, t4, s3);
  }

  // ---- fused last-layer BN3 + LN + ReLU + output head + log_softmax
  bn3_ln_final<<<NN / 4, B, 0, stream>>>(t4, statsAll + 3 * 384 + 256,
                                         bn3g + 3 * C, bn3b + 3 * C,
                                         lng + 3 * C, lnb + 3 * C,
                                         Wout, bout, (float*)d_out);
}